// Round 9
// baseline (1813.873 us; speedup 1.0000x reference)
//
#include <hip/hip_runtime.h>
#include <hip/hip_bf16.h>
#include <math.h>

#define Bn 128
#define Pn 196
#define ENCn 2048
#define Dn 512
#define An 512
#define EDn 512
#define Vn 10000
#define Ln 20
#define Tn 19

typedef short v8s __attribute__((ext_vector_type(8)));
typedef float v4f __attribute__((ext_vector_type(4)));

__device__ __forceinline__ float sigf(float x){ return 1.f/(1.f+__expf(-x)); }
__device__ __forceinline__ unsigned short f2bf(float f){
  unsigned u = __float_as_uint(f);
  return (unsigned short)((u + 0x7FFFu + ((u>>16)&1u)) >> 16);
}
__device__ __forceinline__ float bf2f(unsigned short h){
  return __uint_as_float(((unsigned)h)<<16);
}

// ---------------- setup kernels ----------------

__global__ void k_order(const int* __restrict__ caption_len,
                        const int* __restrict__ captions,
                        int* __restrict__ order_i, int* __restrict__ declen_i,
                        int* __restrict__ caps_s,
                        float* __restrict__ out_caps, float* __restrict__ out_declen,
                        float* __restrict__ out_order)
{
  __shared__ int lens[Bn];
  int b = threadIdx.x;
  lens[b] = caption_len[b];
  __syncthreads();
  int lb = lens[b];
  int r = 0;
  for (int j = 0; j < Bn; ++j) {
    int lj = lens[j];
    r += (int)((lj > lb) || (lj == lb && j < b));
  }
  order_i[r] = b;
  declen_i[r] = lb - 1;
  out_order[r] = (float)b;
  out_declen[r] = (float)(lb - 1);
  for (int t = 0; t < Ln; ++t) {
    int cv = captions[b*Ln + t];
    caps_s[r*Ln + t] = cv;
    out_caps[r*Ln + t] = (float)cv;
  }
}

// bsum reordered to (d*4+g); dg_b / hc_b plain concat
__global__ void k_setup_bias(const float* __restrict__ bih, const float* __restrict__ bhh,
                             const float* __restrict__ da_b, const float* __restrict__ gate_b,
                             const float* __restrict__ h0_b, const float* __restrict__ c0_b,
                             float* __restrict__ bsum_r, float* __restrict__ dg_b,
                             float* __restrict__ hc_b)
{
  int i = blockIdx.x*256 + threadIdx.x;
  if (i < 2048) {
    int d = i >> 2, g = i & 3;
    bsum_r[i] = bih[g*512+d] + bhh[g*512+d];
  }
  if (i < 2560) dg_b[i] = (i < 512) ? da_b[i] : gate_b[i-512];
  if (i < 1024) hc_b[i] = (i < 512) ? h0_b[i] : c0_b[i-512];
}

__global__ void k_cvt(const float* __restrict__ src, unsigned short* __restrict__ dst, int n)
{
  int i = (blockIdx.x*256 + threadIdx.x)*4;
  if (i < n) {
    float4 v = *(const float4*)(src + i);
    dst[i+0]=f2bf(v.x); dst[i+1]=f2bf(v.y); dst[i+2]=f2bf(v.z); dst[i+3]=f2bf(v.w);
  }
}

// dgT8[(kb*512 + n)*8 + j] = bf16(da_w[n][kb*8+j])  — k-blocked transpose
__global__ void k_dgT(const float* __restrict__ da_w, unsigned short* __restrict__ dgT8)
{
  int i = blockIdx.x*256 + threadIdx.x;   // 0..32767: kb = i>>9, n = i&511
  int kb = i >> 9, n = i & 511;
  const float* src = da_w + (size_t)n*512 + kb*8;
  float4 v0 = *(const float4*)src, v1 = *(const float4*)(src+4);
  unsigned short* d = dgT8 + (size_t)i*8;
  d[0]=f2bf(v0.x); d[1]=f2bf(v0.y); d[2]=f2bf(v0.z); d[3]=f2bf(v0.w);
  d[4]=f2bf(v1.x); d[5]=f2bf(v1.y); d[6]=f2bf(v1.z); d[7]=f2bf(v1.w);
}

// wcat_r[d*4+g][3072] = [Wih | Whh][g*512+d][:] in bf16 (gate-interleaved rows)
__global__ void k_wcat(const float* __restrict__ Wih, const float* __restrict__ Whh,
                       unsigned short* __restrict__ dst)
{
  int i = (blockIdx.x*256 + threadIdx.x)*4;
  if (i >= 2048*3072) return;
  int rp = i/3072, j = i - rp*3072;
  int d = rp >> 2, g = rp & 3;
  int r = g*512 + d;
  const float* s = (j < 2560) ? (Wih + (size_t)r*2560 + j) : (Whh + (size_t)r*512 + (j-2560));
  float4 v = *(const float4*)s;
  dst[i+0]=f2bf(v.x); dst[i+1]=f2bf(v.y); dst[i+2]=f2bf(v.z); dst[i+3]=f2bf(v.w);
}

__global__ void k_cvt_enc(const float* __restrict__ enc, const int* __restrict__ order_i,
                          unsigned short* __restrict__ dst)
{
  int id = blockIdx.x;               // b*196+p
  int b = id / Pn, p = id - b*Pn;
  const float* src = enc + ((size_t)order_i[b]*Pn + p)*ENCn;
  unsigned short* d = dst + (size_t)id*ENCn;
  int i = threadIdx.x*8;
  float4 v0 = *(const float4*)(src+i), v1 = *(const float4*)(src+i+4);
  d[i+0]=f2bf(v0.x); d[i+1]=f2bf(v0.y); d[i+2]=f2bf(v0.z); d[i+3]=f2bf(v0.w);
  d[i+4]=f2bf(v1.x); d[i+5]=f2bf(v1.y); d[i+6]=f2bf(v1.z); d[i+7]=f2bf(v1.w);
}

__global__ void k_mean(const unsigned short* __restrict__ enc_bf,
                       unsigned short* __restrict__ mean_bf)
{
  int b = blockIdx.x;
  const unsigned short* eb = enc_bf + (size_t)b*Pn*ENCn;
  for (int e = threadIdx.x; e < ENCn; e += 256) {
    float s = 0.f;
    for (int p = 0; p < Pn; ++p) s += bf2f(eb[(size_t)p*ENCn + e]);
    mean_bf[b*ENCn + e] = f2bf(s * (1.f/196.f));
  }
}

__global__ void k_zero(uint4* __restrict__ p, int n)
{
  int i = blockIdx.x*256 + threadIdx.x;
  if (i < n) p[i] = uint4{0,0,0,0};
}

__global__ void k_emb_all(const int* __restrict__ caps_s, const float* __restrict__ emb_w,
                          unsigned short* __restrict__ xh_all)
{
  int id = blockIdx.x; int t = id >> 7, b = id & 127;
  int tok = caps_s[b*Ln + t];
  const float* src = emb_w + (size_t)tok*EDn;
  unsigned short* d = xh_all + ((size_t)t*Bn + b)*3072;
  int i = threadIdx.x*2;
  float2 v = *(const float2*)(src+i);
  d[i] = f2bf(v.x); d[i+1] = f2bf(v.y);
}

__global__ void k_h2bf(const float* __restrict__ hc, float* __restrict__ c,
                       unsigned short* __restrict__ h_bf, unsigned short* __restrict__ xh_all)
{
  int b = blockIdx.x, d = threadIdx.x;
  float hv = hc[b*1024 + d];
  float cv = hc[b*1024 + 512 + d];
  c[b*Dn + d] = cv;
  unsigned short hb = f2bf(hv);
  h_bf[b*Dn + d] = hb;
  xh_all[(size_t)b*3072 + 2560 + d] = hb;
}

// ---------------- bf16 MFMA GEMM 64x64 (h0c0 only) ----------------
__global__ __launch_bounds__(256) void k_mfma_gemm(
    const unsigned short* __restrict__ Aw, const unsigned short* __restrict__ Bw,
    const float* __restrict__ bias, float* __restrict__ Cp,
    int N, int K, size_t ldc)
{
  __shared__ unsigned short smA[2][4096];
  __shared__ unsigned short smB[2][4096];
  const int tid = threadIdx.x;
  const int bm0 = blockIdx.y*64, bn0 = blockIdx.x*64;

  const int lane = tid & 63, w = tid >> 6;
  const int wr = w >> 1, wc = w & 1;
  const int lrow = lane & 15, kq = lane >> 4;

  v4f acc[2][2];
  #pragma unroll
  for (int i=0;i<2;++i)
    #pragma unroll
    for (int j=0;j<2;++j) acc[i][j] = (v4f)0.f;

  const int nt = K >> 6;

  auto stage = [&](int buf, int k0) {
    #pragma unroll
    for (int it = 0; it < 2; ++it) {
      int s = it*256 + tid;
      int row = s >> 3;
      int kb  = (s & 7) ^ (row & 7);
      *(v8s*)&smA[buf][s*8] = *(const v8s*)(Aw + (size_t)(bm0+row)*K + k0 + kb*8);
      *(v8s*)&smB[buf][s*8] = *(const v8s*)(Bw + (size_t)(bn0+row)*K + k0 + kb*8);
    }
  };
  auto compute = [&](int buf) {
    #pragma unroll
    for (int kc = 0; kc < 2; ++kc) {
      v8s aF[2], bF[2];
      #pragma unroll
      for (int mi = 0; mi < 2; ++mi) {
        int row = wr*32 + mi*16 + lrow;
        int kb = kc*4 + kq;
        aF[mi] = *(const v8s*)&smA[buf][row*64 + ((kb ^ (row&7))<<3)];
      }
      #pragma unroll
      for (int ni = 0; ni < 2; ++ni) {
        int row = wc*32 + ni*16 + lrow;
        int kb = kc*4 + kq;
        bF[ni] = *(const v8s*)&smB[buf][row*64 + ((kb ^ (row&7))<<3)];
      }
      #pragma unroll
      for (int mi = 0; mi < 2; ++mi)
        #pragma unroll
        for (int ni = 0; ni < 2; ++ni)
          acc[mi][ni] = __builtin_amdgcn_mfma_f32_16x16x32_bf16(aF[mi], bF[ni], acc[mi][ni], 0, 0, 0);
    }
  };

  stage(0, 0);
  __syncthreads();
  for (int tk = 0; tk < nt; ++tk) {
    if (tk + 1 < nt) stage((tk+1)&1, (tk+1)<<6);
    compute(tk&1);
    __syncthreads();
  }

  #pragma unroll
  for (int mi=0; mi<2; ++mi)
    #pragma unroll
    for (int ni=0; ni<2; ++ni)
      #pragma unroll
      for (int r=0; r<4; ++r) {
        int m = bm0 + wr*32 + mi*16 + kq*4 + r;
        int n = bn0 + wc*32 + ni*16 + lrow;
        Cp[(size_t)m*ldc + n] = acc[mi][ni][r] + bias[n];
      }
}

// ---------------- att1 GEMM: 128x64 tile, XCD-contiguous ----------------
__global__ __launch_bounds__(256) void k_att1(
    const unsigned short* __restrict__ Aw, const unsigned short* __restrict__ Bw,
    const float* __restrict__ bias, unsigned short* __restrict__ Cp)
{
  __shared__ unsigned short smA[2][8192];
  __shared__ unsigned short smB[2][4096];
  const int tid = threadIdx.x;
  const int id = blockIdx.x;
  const int g = (id & 7)*196 + (id >> 3);   // XCD-contiguous panel walk
  const int bm0 = (g >> 3) * 128, bn0 = (g & 7) * 64;
  const int K = ENCn;

  const int lane = tid & 63, w = tid >> 6;
  const int wr = w >> 1, wc = w & 1;
  const int lrow = lane & 15, kq = lane >> 4;

  v4f acc[4][2];
  #pragma unroll
  for (int i=0;i<4;++i)
    #pragma unroll
    for (int j=0;j<2;++j) acc[i][j] = (v4f)0.f;

  auto stage = [&](int buf, int k0) {
    #pragma unroll
    for (int it = 0; it < 4; ++it) {
      int s = it*256 + tid;
      int row = s >> 3;
      int kb  = (s & 7) ^ (row & 7);
      *(v8s*)&smA[buf][s*8] = *(const v8s*)(Aw + (size_t)(bm0+row)*K + k0 + kb*8);
    }
    #pragma unroll
    for (int it = 0; it < 2; ++it) {
      int s = it*256 + tid;
      int row = s >> 3;
      int kb  = (s & 7) ^ (row & 7);
      *(v8s*)&smB[buf][s*8] = *(const v8s*)(Bw + (size_t)(bn0+row)*K + k0 + kb*8);
    }
  };
  auto compute = [&](int buf) {
    #pragma unroll
    for (int kc = 0; kc < 2; ++kc) {
      v8s aF[4], bF[2];
      #pragma unroll
      for (int mi = 0; mi < 4; ++mi) {
        int row = wr*64 + mi*16 + lrow;
        int kb = kc*4 + kq;
        aF[mi] = *(const v8s*)&smA[buf][row*64 + ((kb ^ (row&7))<<3)];
      }
      #pragma unroll
      for (int ni = 0; ni < 2; ++ni) {
        int row = wc*32 + ni*16 + lrow;
        int kb = kc*4 + kq;
        bF[ni] = *(const v8s*)&smB[buf][row*64 + ((kb ^ (row&7))<<3)];
      }
      #pragma unroll
      for (int mi = 0; mi < 4; ++mi)
        #pragma unroll
        for (int ni = 0; ni < 2; ++ni)
          acc[mi][ni] = __builtin_amdgcn_mfma_f32_16x16x32_bf16(aF[mi], bF[ni], acc[mi][ni], 0, 0, 0);
    }
  };

  stage(0, 0);
  __syncthreads();
  const int nt = K >> 6;
  for (int tk = 0; tk < nt; ++tk) {
    if (tk + 1 < nt) stage((tk+1)&1, (tk+1)<<6);
    compute(tk&1);
    __syncthreads();
  }

  #pragma unroll
  for (int mi=0; mi<4; ++mi)
    #pragma unroll
    for (int ni=0; ni<2; ++ni)
      #pragma unroll
      for (int r=0; r<4; ++r) {
        int m = bm0 + wr*64 + mi*16 + kq*4 + r;
        int n = bn0 + wc*32 + ni*16 + lrow;
        Cp[(size_t)m*An + n] = f2bf(acc[mi][ni][r] + bias[n]);
      }
}

// ---------------- fused: esm (att2-GEMV + e-dot + softmax) || gpre GEMM ----------------
// grid (192): blocks 0..127 = esm for batch row b; blocks 128..191 = gpre GEMM
// tiles (M=128,N=2048,K=512), sigmoid fused -> gbuf f32 [128][2048].
__global__ __launch_bounds__(256) void k_esm_gpre(
    const unsigned short* __restrict__ att1, const unsigned short* __restrict__ dgT8,
    const unsigned short* __restrict__ dg_bf, const float* __restrict__ dg_b,
    const unsigned short* __restrict__ h_bf,
    const float* __restrict__ fa_w, const float* __restrict__ fa_b,
    float* __restrict__ alpha, float* __restrict__ out_alph,
    float* __restrict__ gbuf,
    const int* __restrict__ declen_i, int t)
{
  __shared__ __align__(16) char smraw[32768];
  const int tid = threadIdx.x;

  if (blockIdx.x >= 128) {
    // ---- gpre GEMM tile ----
    unsigned short (*smA)[4096] = (unsigned short(*)[4096])smraw;
    unsigned short (*smB)[4096] = (unsigned short(*)[4096])(smraw + 16384);
    const int id = blockIdx.x - 128;         // 0..63
    const int bm0 = (id >> 5) * 64, bn0 = (id & 31) * 64;
    if (declen_i[bm0] <= t) return;
    const unsigned short* Bw = dg_bf + (size_t)512*Dn;   // gate_w rows
    const int K = Dn;

    const int lane = tid & 63, w = tid >> 6;
    const int wr = w >> 1, wc = w & 1;
    const int lrow = lane & 15, kq = lane >> 4;

    v4f acc[2][2];
    #pragma unroll
    for (int i=0;i<2;++i)
      #pragma unroll
      for (int j=0;j<2;++j) acc[i][j] = (v4f)0.f;

    auto stage = [&](int buf, int k0) {
      #pragma unroll
      for (int it = 0; it < 2; ++it) {
        int s = it*256 + tid;
        int row = s >> 3;
        int kb  = (s & 7) ^ (row & 7);
        *(v8s*)&smA[buf][s*8] = *(const v8s*)(h_bf + (size_t)(bm0+row)*K + k0 + kb*8);
        *(v8s*)&smB[buf][s*8] = *(const v8s*)(Bw + (size_t)(bn0+row)*K + k0 + kb*8);
      }
    };
    auto compute = [&](int buf) {
      #pragma unroll
      for (int kc = 0; kc < 2; ++kc) {
        v8s aF[2], bF[2];
        #pragma unroll
        for (int mi = 0; mi < 2; ++mi) {
          int row = wr*32 + mi*16 + lrow;
          int kb = kc*4 + kq;
          aF[mi] = *(const v8s*)&smA[buf][row*64 + ((kb ^ (row&7))<<3)];
        }
        #pragma unroll
        for (int ni = 0; ni < 2; ++ni) {
          int row = wc*32 + ni*16 + lrow;
          int kb = kc*4 + kq;
          bF[ni] = *(const v8s*)&smB[buf][row*64 + ((kb ^ (row&7))<<3)];
        }
        #pragma unroll
        for (int mi = 0; mi < 2; ++mi)
          #pragma unroll
          for (int ni = 0; ni < 2; ++ni)
            acc[mi][ni] = __builtin_amdgcn_mfma_f32_16x16x32_bf16(aF[mi], bF[ni], acc[mi][ni], 0, 0, 0);
      }
    };

    stage(0, 0);
    __syncthreads();
    const int nt = K >> 6;
    for (int tk = 0; tk < nt; ++tk) {
      if (tk + 1 < nt) stage((tk+1)&1, (tk+1)<<6);
      compute(tk&1);
      __syncthreads();
    }

    #pragma unroll
    for (int mi=0; mi<2; ++mi)
      #pragma unroll
      for (int ni=0; ni<2; ++ni)
        #pragma unroll
        for (int r=0; r<4; ++r) {
          int m = bm0 + wr*32 + mi*16 + kq*4 + r;
          int n = bn0 + wc*32 + ni*16 + lrow;
          gbuf[(size_t)m*2048 + n] = sigf(acc[mi][ni][r] + dg_b[512 + n]);
        }
    return;
  }

  // ---- esm for batch row b ----
  int b = blockIdx.x;
  if (t >= declen_i[b]) {
    if (tid < Pn)
      out_alph[(size_t)b*Tn*Pn + (size_t)t*Pn + tid] = 0.f;
    return;
  }
  float* h_l  = (float*)smraw;         // 512
  float* a2s  = h_l + 512;             // 512
  float* fws  = a2s + 512;             // 512
  float* es   = fws + 512;             // 200 (196 used)
  float* wred = es + 200;              // 4
  float* wsum = wred + 4;              // 4

  for (int i = tid; i < Dn; i += 256) h_l[i] = bf2f(h_bf[b*Dn + i]);
  for (int i = tid; i < An; i += 256) fws[i] = fa_w[i];
  __syncthreads();
  // att2 GEMV: n = tid, tid+256; k-blocked transposed weights (coalesced)
  #pragma unroll
  for (int half = 0; half < 2; ++half) {
    int n = tid + half*256;
    float s = 0.f;
    #pragma unroll 4
    for (int kb = 0; kb < 64; ++kb) {
      v8s wv = *(const v8s*)(dgT8 + ((size_t)kb*512 + n)*8);
      #pragma unroll
      for (int j = 0; j < 8; ++j) s += bf2f((unsigned short)wv[j]) * h_l[kb*8 + j];
    }
    a2s[n] = s + dg_b[n];
  }
  __syncthreads();
  int lane = tid & 63, w = tid >> 6;
  if (tid < Pn) {
    const unsigned short* row = att1 + ((size_t)b*Pn + tid)*An;
    float s = 0.f;
    #pragma unroll 4
    for (int kb = 0; kb < 64; ++kb) {
      const v8s vv = *(const v8s*)(row + kb*8);
      #pragma unroll
      for (int j = 0; j < 8; ++j) {
        int a = kb*8 + j;
        float v = bf2f((unsigned short)vv[j]) + a2s[a];
        s += fmaxf(v, 0.f) * fws[a];
      }
    }
    es[tid] = s + fa_b[0];
  }
  __syncthreads();
  float m = -1e30f;
  for (int p = tid; p < Pn; p += 256) m = fmaxf(m, es[p]);
  for (int off = 32; off; off >>= 1) m = fmaxf(m, __shfl_down(m, off));
  if (lane == 0) wred[w] = m;
  __syncthreads();
  m = fmaxf(fmaxf(wred[0], wred[1]), fmaxf(wred[2], wred[3]));
  float s = 0.f;
  for (int p = tid; p < Pn; p += 256) { float ev = __expf(es[p] - m); es[p] = ev; s += ev; }
  for (int off = 32; off; off >>= 1) s += __shfl_down(s, off);
  if (lane == 0) wsum[w] = s;
  __syncthreads();
  s = wsum[0] + wsum[1] + wsum[2] + wsum[3];
  float inv = 1.f / s;
  for (int p = tid; p < Pn; p += 256) {
    float al = es[p] * inv;
    alpha[b*Pn + p] = al;
    out_alph[(size_t)b*Tn*Pn + (size_t)t*Pn + p] = al;
  }
}

// ---------------- awe + gate ----------------
// grid (8, 128): block (ei, b) handles 256-e slice; g pre-sigmoided in gbuf.
__global__ __launch_bounds__(256) void k_awe_gate(
    const unsigned short* __restrict__ enc_bf,
    const float* __restrict__ alpha, const float* __restrict__ gbuf,
    unsigned short* __restrict__ xh_t, const int* __restrict__ declen_i, int t)
{
  int b = blockIdx.y;
  if (t >= declen_i[b]) return;
  __shared__ float als[Pn];
  __shared__ float red[8][256];
  int tid = threadIdx.x;
  if (tid < Pn) als[tid] = alpha[b*Pn + tid];
  __syncthreads();
  int e0 = blockIdx.x*256;
  int ec = tid & 31, ps = tid >> 5;
  const unsigned short* eb = enc_bf + (size_t)b*Pn*ENCn + e0 + ec*8;
  float s[8] = {};
  for (int p = ps; p < Pn; p += 8) {
    v8s v = *(const v8s*)(eb + (size_t)p*ENCn);
    float a = als[p];
    #pragma unroll
    for (int j = 0; j < 8; ++j) s[j] += a * bf2f((unsigned short)v[j]);
  }
  #pragma unroll
  for (int j = 0; j < 8; ++j) red[ps][ec*8+j] = s[j];
  __syncthreads();
  {
    int eg = e0 + tid;
    float tsum = 0.f;
    #pragma unroll
    for (int k = 0; k < 8; ++k) tsum += red[k][tid];
    float g = gbuf[(size_t)b*2048 + eg];
    xh_t[(size_t)b*3072 + 512 + eg] = f2bf(g*tsum);
  }
}

// ---------------- gates GEMM + LSTM epilogue ----------------
__global__ __launch_bounds__(256) void k_gates_lstm(
    const unsigned short* __restrict__ Aw, const unsigned short* __restrict__ Bw,
    const float* __restrict__ bias,
    float* __restrict__ c, unsigned short* __restrict__ h_bf,
    unsigned short* __restrict__ h_all, unsigned short* __restrict__ xh_all,
    const int* __restrict__ declen_i, int t)
{
  __shared__ unsigned short smA[2][4096];
  __shared__ unsigned short smB[2][4096];
  __shared__ float smC[64][65];
  const int tid = threadIdx.x;
  const int bm0 = blockIdx.y*64, bn0 = blockIdx.x*64;
  if (declen_i[bm0] <= t) return;

  const int lane = tid & 63, w = tid >> 6;
  const int wr = w >> 1, wc = w & 1;
  const int lrow = lane & 15, kq = lane >> 4;
  const int K = 3072;

  v4f acc[2][2];
  #pragma unroll
  for (int i=0;i<2;++i)
    #pragma unroll
    for (int j=0;j<2;++j) acc[i][j] = (v4f)0.f;

  auto stage = [&](int buf, int k0) {
    #pragma unroll
    for (int it = 0; it < 2; ++it) {
      int s = it*256 + tid;
      int row = s >> 3;
      int kb  = (s & 7) ^ (row & 7);
      *(v8s*)&smA[buf][s*8] = *(const v8s*)(Aw + (size_t)(bm0+row)*K + k0 + kb*8);
      *(v8s*)&smB[buf][s*8] = *(const v8s*)(Bw + (size_t)(bn0+row)*K + k0 + kb*8);
    }
  };
  auto compute = [&](int buf) {
    #pragma unroll
    for (int kc = 0; kc < 2; ++kc) {
      v8s aF[2], bF[2];
      #pragma unroll
      for (int mi = 0; mi < 2; ++mi) {
        int row = wr*32 + mi*16 + lrow;
        int kb = kc*4 + kq;
        aF[mi] = *(const v8s*)&smA[buf][row*64 + ((kb ^ (row&7))<<3)];
      }
      #pragma unroll
      for (int ni = 0; ni < 2; ++ni) {
        int row = wc*32 + ni*16 + lrow;
        int kb = kc*4 + kq;
        bF[ni] = *(const v8s*)&smB[buf][row*64 + ((kb ^ (row&7))<<3)];
      }
      #pragma unroll
      for (int mi = 0; mi < 2; ++mi)
        #pragma unroll
        for (int ni = 0; ni < 2; ++ni)
          acc[mi][ni] = __builtin_amdgcn_mfma_f32_16x16x32_bf16(aF[mi], bF[ni], acc[mi][ni], 0, 0, 0);
    }
  };

  stage(0, 0);
  __syncthreads();
  const int nt = K >> 6;
  for (int tk = 0; tk < nt; ++tk) {
    if (tk + 1 < nt) stage((tk+1)&1, (tk+1)<<6);
    compute(tk&1);
    __syncthreads();
  }

  #pragma unroll
  for (int mi=0; mi<2; ++mi)
    #pragma unroll
    for (int ni=0; ni<2; ++ni)
      #pragma unroll
      for (int r=0; r<4; ++r) {
        int ml = wr*32 + mi*16 + kq*4 + r;
        int nl = wc*32 + ni*16 + lrow;
        smC[ml][nl] = acc[mi][ni][r] + bias[bn0 + nl];
      }
  __syncthreads();

  for (int idx = tid; idx < 1024; idx += 256) {
    int ml = idx >> 4, dl = idx & 15;
    int b = bm0 + ml;
    if (t < declen_i[b]) {
      int dg = (bn0 >> 2) + dl;
      float gi = smC[ml][dl*4+0];
      float gf = smC[ml][dl*4+1];
      float gg = smC[ml][dl*4+2];
      float go = smC[ml][dl*4+3];
      float cv = c[b*Dn + dg];
      float cn = sigf(gf)*cv + sigf(gi)*tanhf(gg);
      float hn = sigf(go)*tanhf(cn);
      c[b*Dn + dg] = cn;
      unsigned short hb = f2bf(hn);
      h_bf[b*Dn + dg] = hb;
      h_all[((size_t)t*Bn + b)*Dn + dg] = hb;
      if (t + 1 < Tn)
        xh_all[((size_t)(t+1)*Bn + b)*3072 + 2560 + dg] = hb;
    }
  }
}

// ---------------- batched pred GEMM: 128x64 tiles (one t per m-tile) ----------------
__global__ __launch_bounds__(256) void k_pred(
    const unsigned short* __restrict__ Aw, const unsigned short* __restrict__ Bw,
    const float* __restrict__ bias, float* __restrict__ out_pred,
    const int* __restrict__ declen_i)
{
  __shared__ unsigned short smA[2][8192];
  __shared__ unsigned short smB[2][4096];
  const int tid = threadIdx.x;
  const int t0 = blockIdx.y;
  const int bm0 = t0*128, bn0 = blockIdx.x*64;
  const int K = Dn;

  const int lane = tid & 63, w = tid >> 6;
  const int wr = w >> 1, wc = w & 1;
  const int lrow = lane & 15, kq = lane >> 4;

  v4f acc[4][2];
  #pragma unroll
  for (int i=0;i<4;++i)
    #pragma unroll
    for (int j=0;j<2;++j) acc[i][j] = (v4f)0.f;

  auto stage = [&](int buf, int k0) {
    #pragma unroll
    for (int it = 0; it < 4; ++it) {
      int s = it*256 + tid;
      int row = s >> 3;
      int kb  = (s & 7) ^ (row & 7);
      *(v8s*)&smA[buf][s*8] = *(const v8s*)(Aw + (size_t)(bm0+row)*K + k0 + kb*8);
    }
    #pragma unroll
    for (int it = 0; it < 2; ++it) {
      int s = it*256 + tid;
      int row = s >> 3;
      int kb  = (s & 7) ^ (row & 7);
      int gn = bn0 + row; if (gn >= Vn) gn = Vn-1;
      *(v8s*)&smB[buf][s*8] = *(const v8s*)(Bw + (size_t)gn*K + k0 + kb*8);
    }
  };
  auto compute = [&](int buf) {
    #pragma unroll
    for (int kc = 0; kc < 2; ++kc) {
      v8s aF[4], bF[2];
      #pragma unroll
      for (int mi = 0; mi < 4; ++mi) {
        int row = wr*64 + mi*16 + lrow;
        int kb = kc*4 + kq;
        aF[mi] = *(const v8s*)&smA[buf][row*64 + ((kb ^ (row&7))<<3)];
      }
      #pragma unroll
      for (int ni = 0; ni < 2; ++ni) {
        int row = wc*32 + ni*16 + lrow;
        int kb = kc*4 + kq;
        bF[ni] = *(const v8s*)&smB[buf][row*64 + ((kb ^ (row&7))<<3)];
      }
      #pragma unroll
      for (int mi = 0; mi < 4; ++mi)
        #pragma unroll
        for (int ni = 0; ni < 2; ++ni)
          acc[mi][ni] = __builtin_amdgcn_mfma_f32_16x16x32_bf16(aF[mi], bF[ni], acc[mi][ni], 0, 0, 0);
    }
  };

  stage(0, 0);
  __syncthreads();
  const int nt = K >> 6;
  for (int tk = 0; tk < nt; ++tk) {
    if (tk + 1 < nt) stage((tk+1)&1, (tk+1)<<6);
    compute(tk&1);
    __syncthreads();
  }

  #pragma unroll
  for (int mi=0; mi<4; ++mi)
    #pragma unroll
    for (int ni=0; ni<2; ++ni)
      #pragma unroll
      for (int r=0; r<4; ++r) {
        int b = wr*64 + mi*16 + kq*4 + r;      // 0..127 within tile = batch row
        int n = bn0 + wc*32 + ni*16 + lrow;
        if (n < Vn) {
          float v = (t0 < declen_i[b]) ? (acc[mi][ni][r] + bias[n]) : 0.f;
          out_pred[((size_t)b*Tn + t0)*Vn + n] = v;
        }
      }
}

// ---------------- launch ----------------

extern "C" void kernel_launch(void* const* d_in, const int* in_sizes, int n_in,
                              void* d_out, int out_size, void* d_ws, size_t ws_size,
                              hipStream_t stream)
{
  const float* enc     = (const float*)d_in[0];
  const int*   captions= (const int*)d_in[1];
  const int*   cap_len = (const int*)d_in[2];
  const float* emb_w   = (const float*)d_in[3];
  const float* Wih     = (const float*)d_in[4];
  const float* Whh     = (const float*)d_in[5];
  const float* bih     = (const float*)d_in[6];
  const float* bhh     = (const float*)d_in[7];
  const float* h0_w    = (const float*)d_in[8];
  const float* h0_b    = (const float*)d_in[9];
  const float* c0_w    = (const float*)d_in[10];
  const float* c0_b    = (const float*)d_in[11];
  const float* gate_w  = (const float*)d_in[12];
  const float* gate_b  = (const float*)d_in[13];
  const float* lin_w   = (const float*)d_in[14];
  const float* lin_b   = (const float*)d_in[15];
  const float* ea_w    = (const float*)d_in[16];
  const float* ea_b    = (const float*)d_in[17];
  const float* da_w    = (const float*)d_in[18];
  const float* da_b    = (const float*)d_in[19];
  const float* fa_w    = (const float*)d_in[20];
  const float* fa_b    = (const float*)d_in[21];

  float* out = (float*)d_out;
  float* out_pred   = out;                               // [128][19][10000]
  float* out_caps   = out + (size_t)Bn*Tn*Vn;            // [128][20]
  float* out_declen = out_caps + Bn*Ln;                  // [128]
  float* out_alph   = out_declen + Bn;                   // [128][19][196]
  float* out_order  = out_alph + (size_t)Bn*Tn*Pn;       // [128]

  char* wp = (char*)d_ws;
  auto alloc = [&](size_t bytes)->void* {
    void* p = (void*)wp; wp += (bytes + 255) & ~(size_t)255; return p;
  };
  int*   order_i  = (int*)alloc(Bn*4);
  int*   declen_i = (int*)alloc(Bn*4);
  int*   caps_s   = (int*)alloc(Bn*Ln*4);
  unsigned short* enc_bf  = (unsigned short*)alloc((size_t)Bn*Pn*ENCn*2);  // 102.8 MB
  unsigned short* mean_bf = (unsigned short*)alloc((size_t)Bn*ENCn*2);
  float* hc       = (float*)alloc((size_t)Bn*1024*4);
  float* c        = (float*)alloc((size_t)Bn*Dn*4);
  unsigned short* h_bf   = (unsigned short*)alloc((size_t)Bn*Dn*2);
  unsigned short* h_all  = (unsigned short*)alloc((size_t)Tn*Bn*Dn*2);     // 2.5 MB
  unsigned short* xh_all = (unsigned short*)alloc((size_t)Tn*Bn*3072*2);   // 14.9 MB
  unsigned short* att1   = (unsigned short*)alloc((size_t)Bn*Pn*An*2);     // 25.7 MB
  float* gbuf     = (float*)alloc((size_t)Bn*2048*4);                      // 1 MB
  float* alpha    = (float*)alloc((size_t)Bn*Pn*4);
  unsigned short* ea_bf   = (unsigned short*)alloc((size_t)An*ENCn*2);
  unsigned short* lin_bf  = (unsigned short*)alloc((size_t)Vn*Dn*2);
  unsigned short* h0c0_bf = (unsigned short*)alloc((size_t)1024*ENCn*2);
  unsigned short* dg_bf   = (unsigned short*)alloc((size_t)2560*Dn*2);
  unsigned short* dgT8    = (unsigned short*)alloc((size_t)512*512*2);
  unsigned short* wcat_bf = (unsigned short*)alloc((size_t)2048*3072*2);
  float* bsum = (float*)alloc(2048*4);
  float* dg_b = (float*)alloc(2560*4);
  float* hc_b = (float*)alloc(1024*4);

  // ---- setup ----
  k_order<<<1,128,0,stream>>>(cap_len, captions, order_i, declen_i, caps_s,
                              out_caps, out_declen, out_order);
  k_setup_bias<<<10,256,0,stream>>>(bih, bhh, da_b, gate_b, h0_b, c0_b, bsum, dg_b, hc_b);
  k_cvt<<<(An*ENCn/4+255)/256,256,0,stream>>>(ea_w, ea_bf, An*ENCn);
  k_cvt<<<(Vn*Dn/4+255)/256,256,0,stream>>>(lin_w, lin_bf, Vn*Dn);
  k_cvt<<<(Dn*ENCn/4+255)/256,256,0,stream>>>(h0_w, h0c0_bf, Dn*ENCn);
  k_cvt<<<(Dn*ENCn/4+255)/256,256,0,stream>>>(c0_w, h0c0_bf + (size_t)512*ENCn, Dn*ENCn);
  k_cvt<<<(An*Dn/4+255)/256,256,0,stream>>>(da_w, dg_bf, An*Dn);
  k_cvt<<<(ENCn*Dn/4+255)/256,256,0,stream>>>(gate_w, dg_bf + (size_t)512*Dn, ENCn*Dn);
  k_dgT<<<128,256,0,stream>>>(da_w, dgT8);
  k_wcat<<<(2048*3072/4+255)/256,256,0,stream>>>(Wih, Whh, wcat_bf);
  k_cvt_enc<<<Bn*Pn,256,0,stream>>>(enc, order_i, enc_bf);
  k_mean<<<Bn,256,0,stream>>>(enc_bf, mean_bf);
  k_zero<<<((int)((size_t)Tn*Bn*3072*2/16)+255)/256,256,0,stream>>>(
      (uint4*)xh_all, (int)((size_t)Tn*Bn*3072*2/16));
  k_emb_all<<<Tn*Bn,256,0,stream>>>(caps_s, emb_w, xh_all);

  // h0/c0
  k_mfma_gemm<<<dim3(16,2),256,0,stream>>>(
      mean_bf, h0c0_bf, hc_b, hc, 1024, ENCn, 1024);
  k_h2bf<<<Bn,512,0,stream>>>(hc, c, h_bf, xh_all);

  // att1 = enc_bf @ ea_w^T (bf16 out), 128x64 tiles, XCD-contiguous
  k_att1<<<dim3(196*8),256,0,stream>>>(enc_bf, ea_bf, ea_b, att1);

  for (int t = 0; t < Tn; ++t) {
    unsigned short* xh_t = xh_all + (size_t)t*Bn*3072;
    // fused: esm (att2-GEMV + e-dot + softmax) || gpre GEMM
    k_esm_gpre<<<192,256,0,stream>>>(att1, dgT8, dg_bf, dg_b, h_bf, fa_w, fa_b,
                                     alpha, out_alph, gbuf, declen_i, t);
    // awe + gate
    k_awe_gate<<<dim3(8,Bn),256,0,stream>>>(enc_bf, alpha, gbuf, xh_t, declen_i, t);
    // gates GEMM + LSTM epilogue
    k_gates_lstm<<<dim3(32,2),256,0,stream>>>(
        xh_t, wcat_bf, bsum, c, h_bf, h_all, xh_all, declen_i, t);
  }

  // batched pred over all t: 128x64 tiles
  k_pred<<<dim3((Vn+63)/64, Tn),256,0,stream>>>(
      h_all, lin_bf, lin_b, out_pred, declen_i);
}

// Round 10
// 1702.578 us; speedup vs baseline: 1.0654x; 1.0654x over previous
//
#include <hip/hip_runtime.h>
#include <hip/hip_bf16.h>
#include <math.h>

#define Bn 128
#define Pn 196
#define ENCn 2048
#define Dn 512
#define An 512
#define EDn 512
#define Vn 10000
#define Ln 20
#define Tn 19

typedef short v8s __attribute__((ext_vector_type(8)));
typedef float v4f __attribute__((ext_vector_type(4)));

__device__ __forceinline__ float sigf(float x){ return 1.f/(1.f+__expf(-x)); }
__device__ __forceinline__ unsigned short f2bf(float f){
  unsigned u = __float_as_uint(f);
  return (unsigned short)((u + 0x7FFFu + ((u>>16)&1u)) >> 16);
}
__device__ __forceinline__ float bf2f(unsigned short h){
  return __uint_as_float(((unsigned)h)<<16);
}

// ---------------- setup kernels ----------------

__global__ void k_order(const int* __restrict__ caption_len,
                        const int* __restrict__ captions,
                        int* __restrict__ order_i, int* __restrict__ declen_i,
                        int* __restrict__ caps_s,
                        float* __restrict__ out_caps, float* __restrict__ out_declen,
                        float* __restrict__ out_order)
{
  __shared__ int lens[Bn];
  int b = threadIdx.x;
  lens[b] = caption_len[b];
  __syncthreads();
  int lb = lens[b];
  int r = 0;
  for (int j = 0; j < Bn; ++j) {
    int lj = lens[j];
    r += (int)((lj > lb) || (lj == lb && j < b));
  }
  order_i[r] = b;
  declen_i[r] = lb - 1;
  out_order[r] = (float)b;
  out_declen[r] = (float)(lb - 1);
  for (int t = 0; t < Ln; ++t) {
    int cv = captions[b*Ln + t];
    caps_s[r*Ln + t] = cv;
    out_caps[r*Ln + t] = (float)cv;
  }
}

// bsum reordered to (d*4+g); dg_b / hc_b plain concat
__global__ void k_setup_bias(const float* __restrict__ bih, const float* __restrict__ bhh,
                             const float* __restrict__ da_b, const float* __restrict__ gate_b,
                             const float* __restrict__ h0_b, const float* __restrict__ c0_b,
                             float* __restrict__ bsum_r, float* __restrict__ dg_b,
                             float* __restrict__ hc_b)
{
  int i = blockIdx.x*256 + threadIdx.x;
  if (i < 2048) {
    int d = i >> 2, g = i & 3;
    bsum_r[i] = bih[g*512+d] + bhh[g*512+d];
  }
  if (i < 2560) dg_b[i] = (i < 512) ? da_b[i] : gate_b[i-512];
  if (i < 1024) hc_b[i] = (i < 512) ? h0_b[i] : c0_b[i-512];
}

// merged f32->bf16 conversion of all 6 weight matrices, one dispatch
#define C_EA  (512*2048)
#define C_LIN (10000*512)
#define C_H0  (512*2048)
#define C_C0  (512*2048)
#define C_DA  (512*512)
#define C_GW  (2048*512)
#define CUM1  (C_EA)
#define CUM2  (CUM1 + C_LIN)
#define CUM3  (CUM2 + C_H0)
#define CUM4  (CUM3 + C_C0)
#define CUM5  (CUM4 + C_DA)
#define CUM6  (CUM5 + C_GW)          // 9576448 total, = 9352 blocks * 1024

__global__ void k_cvt6(const float* __restrict__ ea_w, const float* __restrict__ lin_w,
                       const float* __restrict__ h0_w, const float* __restrict__ c0_w,
                       const float* __restrict__ da_w, const float* __restrict__ gate_w,
                       unsigned short* __restrict__ ea_bf, unsigned short* __restrict__ lin_bf,
                       unsigned short* __restrict__ h0c0_bf, unsigned short* __restrict__ dg_bf)
{
  int i = (blockIdx.x*256 + threadIdx.x)*4;
  const float* src; unsigned short* dst; int off;
  if      (i < CUM1) { src = ea_w;   dst = ea_bf;                    off = i; }
  else if (i < CUM2) { src = lin_w;  dst = lin_bf;                   off = i - CUM1; }
  else if (i < CUM3) { src = h0_w;   dst = h0c0_bf;                  off = i - CUM2; }
  else if (i < CUM4) { src = c0_w;   dst = h0c0_bf + (size_t)C_H0;   off = i - CUM3; }
  else if (i < CUM5) { src = da_w;   dst = dg_bf;                    off = i - CUM4; }
  else               { src = gate_w; dst = dg_bf + (size_t)C_DA;     off = i - CUM5; }
  float4 v = *(const float4*)(src + off);
  dst[off+0]=f2bf(v.x); dst[off+1]=f2bf(v.y); dst[off+2]=f2bf(v.z); dst[off+3]=f2bf(v.w);
}

// wcat_r[d*4+g][3072] = [Wih | Whh][g*512+d][:] in bf16 (gate-interleaved rows)
__global__ void k_wcat(const float* __restrict__ Wih, const float* __restrict__ Whh,
                       unsigned short* __restrict__ dst)
{
  int i = (blockIdx.x*256 + threadIdx.x)*4;
  if (i >= 2048*3072) return;
  int rp = i/3072, j = i - rp*3072;
  int d = rp >> 2, g = rp & 3;
  int r = g*512 + d;
  const float* s = (j < 2560) ? (Wih + (size_t)r*2560 + j) : (Whh + (size_t)r*512 + (j-2560));
  float4 v = *(const float4*)s;
  dst[i+0]=f2bf(v.x); dst[i+1]=f2bf(v.y); dst[i+2]=f2bf(v.z); dst[i+3]=f2bf(v.w);
}

__global__ void k_cvt_enc(const float* __restrict__ enc, const int* __restrict__ order_i,
                          unsigned short* __restrict__ dst)
{
  int id = blockIdx.x;               // b*196+p
  int b = id / Pn, p = id - b*Pn;
  const float* src = enc + ((size_t)order_i[b]*Pn + p)*ENCn;
  unsigned short* d = dst + (size_t)id*ENCn;
  int i = threadIdx.x*8;
  float4 v0 = *(const float4*)(src+i), v1 = *(const float4*)(src+i+4);
  d[i+0]=f2bf(v0.x); d[i+1]=f2bf(v0.y); d[i+2]=f2bf(v0.z); d[i+3]=f2bf(v0.w);
  d[i+4]=f2bf(v1.x); d[i+5]=f2bf(v1.y); d[i+6]=f2bf(v1.z); d[i+7]=f2bf(v1.w);
}

__global__ void k_mean(const unsigned short* __restrict__ enc_bf,
                       unsigned short* __restrict__ mean_bf)
{
  int b = blockIdx.x;
  const unsigned short* eb = enc_bf + (size_t)b*Pn*ENCn;
  for (int e = threadIdx.x; e < ENCn; e += 256) {
    float s = 0.f;
    for (int p = 0; p < Pn; ++p) s += bf2f(eb[(size_t)p*ENCn + e]);
    mean_bf[b*ENCn + e] = f2bf(s * (1.f/196.f));
  }
}

__global__ void k_emb_all(const int* __restrict__ caps_s, const float* __restrict__ emb_w,
                          unsigned short* __restrict__ xh_all)
{
  int id = blockIdx.x; int t = id >> 7, b = id & 127;
  int tok = caps_s[b*Ln + t];
  const float* src = emb_w + (size_t)tok*EDn;
  unsigned short* d = xh_all + ((size_t)t*Bn + b)*3072;
  int i = threadIdx.x*2;
  float2 v = *(const float2*)(src+i);
  d[i] = f2bf(v.x); d[i+1] = f2bf(v.y);
}

__global__ void k_h2bf(const float* __restrict__ hc, float* __restrict__ c,
                       unsigned short* __restrict__ h_bf, unsigned short* __restrict__ xh_all)
{
  int b = blockIdx.x, d = threadIdx.x;
  float hv = hc[b*1024 + d];
  float cv = hc[b*1024 + 512 + d];
  c[b*Dn + d] = cv;
  unsigned short hb = f2bf(hv);
  h_bf[b*Dn + d] = hb;
  xh_all[(size_t)b*3072 + 2560 + d] = hb;
}

// ---------------- bf16 MFMA GEMM 64x64: C[M,N] = A @ B^T (+bias) ----------------
// grid (N/64, M/64); actlen tile-skip (sorted declen, prefix-active).
__global__ __launch_bounds__(256) void k_mfma_gemm(
    const unsigned short* __restrict__ Aw, const unsigned short* __restrict__ Bw,
    const float* __restrict__ bias, float* __restrict__ Cp,
    int N, int K, size_t ldc,
    const int* __restrict__ actlen, int t)
{
  __shared__ unsigned short smA[2][4096];
  __shared__ unsigned short smB[2][4096];
  const int tid = threadIdx.x;
  const int bm0 = blockIdx.y*64, bn0 = blockIdx.x*64;
  if (actlen && actlen[bm0] <= t) return;

  const int lane = tid & 63, w = tid >> 6;
  const int wr = w >> 1, wc = w & 1;
  const int lrow = lane & 15, kq = lane >> 4;

  v4f acc[2][2];
  #pragma unroll
  for (int i=0;i<2;++i)
    #pragma unroll
    for (int j=0;j<2;++j) acc[i][j] = (v4f)0.f;

  const int nt = K >> 6;

  auto stage = [&](int buf, int k0) {
    #pragma unroll
    for (int it = 0; it < 2; ++it) {
      int s = it*256 + tid;
      int row = s >> 3;
      int kb  = (s & 7) ^ (row & 7);
      *(v8s*)&smA[buf][s*8] = *(const v8s*)(Aw + (size_t)(bm0+row)*K + k0 + kb*8);
      *(v8s*)&smB[buf][s*8] = *(const v8s*)(Bw + (size_t)(bn0+row)*K + k0 + kb*8);
    }
  };
  auto compute = [&](int buf) {
    #pragma unroll
    for (int kc = 0; kc < 2; ++kc) {
      v8s aF[2], bF[2];
      #pragma unroll
      for (int mi = 0; mi < 2; ++mi) {
        int row = wr*32 + mi*16 + lrow;
        int kb = kc*4 + kq;
        aF[mi] = *(const v8s*)&smA[buf][row*64 + ((kb ^ (row&7))<<3)];
      }
      #pragma unroll
      for (int ni = 0; ni < 2; ++ni) {
        int row = wc*32 + ni*16 + lrow;
        int kb = kc*4 + kq;
        bF[ni] = *(const v8s*)&smB[buf][row*64 + ((kb ^ (row&7))<<3)];
      }
      #pragma unroll
      for (int mi = 0; mi < 2; ++mi)
        #pragma unroll
        for (int ni = 0; ni < 2; ++ni)
          acc[mi][ni] = __builtin_amdgcn_mfma_f32_16x16x32_bf16(aF[mi], bF[ni], acc[mi][ni], 0, 0, 0);
    }
  };

  stage(0, 0);
  __syncthreads();
  for (int tk = 0; tk < nt; ++tk) {
    if (tk + 1 < nt) stage((tk+1)&1, (tk+1)<<6);
    compute(tk&1);
    __syncthreads();
  }

  #pragma unroll
  for (int mi=0; mi<2; ++mi)
    #pragma unroll
    for (int ni=0; ni<2; ++ni)
      #pragma unroll
      for (int r=0; r<4; ++r) {
        int m = bm0 + wr*32 + mi*16 + kq*4 + r;
        int n = bn0 + wc*32 + ni*16 + lrow;
        Cp[(size_t)m*ldc + n] = acc[mi][ni][r] + bias[n];
      }
}

// ---------------- att1 GEMM: 128x64 tile, XCD-contiguous ----------------
__global__ __launch_bounds__(256) void k_att1(
    const unsigned short* __restrict__ Aw, const unsigned short* __restrict__ Bw,
    const float* __restrict__ bias, unsigned short* __restrict__ Cp)
{
  __shared__ unsigned short smA[2][8192];
  __shared__ unsigned short smB[2][4096];
  const int tid = threadIdx.x;
  const int id = blockIdx.x;
  const int g = (id & 7)*196 + (id >> 3);   // XCD-contiguous panel walk
  const int bm0 = (g >> 3) * 128, bn0 = (g & 7) * 64;
  const int K = ENCn;

  const int lane = tid & 63, w = tid >> 6;
  const int wr = w >> 1, wc = w & 1;
  const int lrow = lane & 15, kq = lane >> 4;

  v4f acc[4][2];
  #pragma unroll
  for (int i=0;i<4;++i)
    #pragma unroll
    for (int j=0;j<2;++j) acc[i][j] = (v4f)0.f;

  auto stage = [&](int buf, int k0) {
    #pragma unroll
    for (int it = 0; it < 4; ++it) {
      int s = it*256 + tid;
      int row = s >> 3;
      int kb  = (s & 7) ^ (row & 7);
      *(v8s*)&smA[buf][s*8] = *(const v8s*)(Aw + (size_t)(bm0+row)*K + k0 + kb*8);
    }
    #pragma unroll
    for (int it = 0; it < 2; ++it) {
      int s = it*256 + tid;
      int row = s >> 3;
      int kb  = (s & 7) ^ (row & 7);
      *(v8s*)&smB[buf][s*8] = *(const v8s*)(Bw + (size_t)(bn0+row)*K + k0 + kb*8);
    }
  };
  auto compute = [&](int buf) {
    #pragma unroll
    for (int kc = 0; kc < 2; ++kc) {
      v8s aF[4], bF[2];
      #pragma unroll
      for (int mi = 0; mi < 4; ++mi) {
        int row = wr*64 + mi*16 + lrow;
        int kb = kc*4 + kq;
        aF[mi] = *(const v8s*)&smA[buf][row*64 + ((kb ^ (row&7))<<3)];
      }
      #pragma unroll
      for (int ni = 0; ni < 2; ++ni) {
        int row = wc*32 + ni*16 + lrow;
        int kb = kc*4 + kq;
        bF[ni] = *(const v8s*)&smB[buf][row*64 + ((kb ^ (row&7))<<3)];
      }
      #pragma unroll
      for (int mi = 0; mi < 4; ++mi)
        #pragma unroll
        for (int ni = 0; ni < 2; ++ni)
          acc[mi][ni] = __builtin_amdgcn_mfma_f32_16x16x32_bf16(aF[mi], bF[ni], acc[mi][ni], 0, 0, 0);
    }
  };

  stage(0, 0);
  __syncthreads();
  const int nt = K >> 6;
  for (int tk = 0; tk < nt; ++tk) {
    if (tk + 1 < nt) stage((tk+1)&1, (tk+1)<<6);
    compute(tk&1);
    __syncthreads();
  }

  #pragma unroll
  for (int mi=0; mi<4; ++mi)
    #pragma unroll
    for (int ni=0; ni<2; ++ni)
      #pragma unroll
      for (int r=0; r<4; ++r) {
        int m = bm0 + wr*64 + mi*16 + kq*4 + r;
        int n = bn0 + wc*32 + ni*16 + lrow;
        Cp[(size_t)m*An + n] = f2bf(acc[mi][ni][r] + bias[n]);
      }
}

// ---------------- gates GEMM + LSTM epilogue ----------------
__global__ __launch_bounds__(256) void k_gates_lstm(
    const unsigned short* __restrict__ Aw, const unsigned short* __restrict__ Bw,
    const float* __restrict__ bias,
    float* __restrict__ c, unsigned short* __restrict__ h_bf,
    unsigned short* __restrict__ h_all, unsigned short* __restrict__ xh_all,
    const int* __restrict__ declen_i, int t)
{
  __shared__ unsigned short smA[2][4096];
  __shared__ unsigned short smB[2][4096];
  __shared__ float smC[64][65];
  const int tid = threadIdx.x;
  const int bm0 = blockIdx.y*64, bn0 = blockIdx.x*64;
  if (declen_i[bm0] <= t) return;

  const int lane = tid & 63, w = tid >> 6;
  const int wr = w >> 1, wc = w & 1;
  const int lrow = lane & 15, kq = lane >> 4;
  const int K = 3072;

  v4f acc[2][2];
  #pragma unroll
  for (int i=0;i<2;++i)
    #pragma unroll
    for (int j=0;j<2;++j) acc[i][j] = (v4f)0.f;

  auto stage = [&](int buf, int k0) {
    #pragma unroll
    for (int it = 0; it < 2; ++it) {
      int s = it*256 + tid;
      int row = s >> 3;
      int kb  = (s & 7) ^ (row & 7);
      *(v8s*)&smA[buf][s*8] = *(const v8s*)(Aw + (size_t)(bm0+row)*K + k0 + kb*8);
      *(v8s*)&smB[buf][s*8] = *(const v8s*)(Bw + (size_t)(bn0+row)*K + k0 + kb*8);
    }
  };
  auto compute = [&](int buf) {
    #pragma unroll
    for (int kc = 0; kc < 2; ++kc) {
      v8s aF[2], bF[2];
      #pragma unroll
      for (int mi = 0; mi < 2; ++mi) {
        int row = wr*32 + mi*16 + lrow;
        int kb = kc*4 + kq;
        aF[mi] = *(const v8s*)&smA[buf][row*64 + ((kb ^ (row&7))<<3)];
      }
      #pragma unroll
      for (int ni = 0; ni < 2; ++ni) {
        int row = wc*32 + ni*16 + lrow;
        int kb = kc*4 + kq;
        bF[ni] = *(const v8s*)&smB[buf][row*64 + ((kb ^ (row&7))<<3)];
      }
      #pragma unroll
      for (int mi = 0; mi < 2; ++mi)
        #pragma unroll
        for (int ni = 0; ni < 2; ++ni)
          acc[mi][ni] = __builtin_amdgcn_mfma_f32_16x16x32_bf16(aF[mi], bF[ni], acc[mi][ni], 0, 0, 0);
    }
  };

  stage(0, 0);
  __syncthreads();
  const int nt = K >> 6;
  for (int tk = 0; tk < nt; ++tk) {
    if (tk + 1 < nt) stage((tk+1)&1, (tk+1)<<6);
    compute(tk&1);
    __syncthreads();
  }

  #pragma unroll
  for (int mi=0; mi<2; ++mi)
    #pragma unroll
    for (int ni=0; ni<2; ++ni)
      #pragma unroll
      for (int r=0; r<4; ++r) {
        int ml = wr*32 + mi*16 + kq*4 + r;
        int nl = wc*32 + ni*16 + lrow;
        smC[ml][nl] = acc[mi][ni][r] + bias[bn0 + nl];
      }
  __syncthreads();

  for (int idx = tid; idx < 1024; idx += 256) {
    int ml = idx >> 4, dl = idx & 15;
    int b = bm0 + ml;
    if (t < declen_i[b]) {
      int dg = (bn0 >> 2) + dl;
      float gi = smC[ml][dl*4+0];
      float gf = smC[ml][dl*4+1];
      float gg = smC[ml][dl*4+2];
      float go = smC[ml][dl*4+3];
      float cv = c[b*Dn + dg];
      float cn = sigf(gf)*cv + sigf(gi)*tanhf(gg);
      float hn = sigf(go)*tanhf(cn);
      c[b*Dn + dg] = cn;
      unsigned short hb = f2bf(hn);
      h_bf[b*Dn + dg] = hb;
      h_all[((size_t)t*Bn + b)*Dn + dg] = hb;
      if (t + 1 < Tn)
        xh_all[((size_t)(t+1)*Bn + b)*3072 + 2560 + dg] = hb;
    }
  }
}

// ---------------- batched pred GEMM: 128x64 tiles (one t per m-tile) ----------------
__global__ __launch_bounds__(256) void k_pred(
    const unsigned short* __restrict__ Aw, const unsigned short* __restrict__ Bw,
    const float* __restrict__ bias, float* __restrict__ out_pred,
    const int* __restrict__ declen_i)
{
  __shared__ unsigned short smA[2][8192];
  __shared__ unsigned short smB[2][4096];
  const int tid = threadIdx.x;
  const int t0 = blockIdx.y;
  const int bm0 = t0*128, bn0 = blockIdx.x*64;
  const int K = Dn;

  const int lane = tid & 63, w = tid >> 6;
  const int wr = w >> 1, wc = w & 1;
  const int lrow = lane & 15, kq = lane >> 4;

  v4f acc[4][2];
  #pragma unroll
  for (int i=0;i<4;++i)
    #pragma unroll
    for (int j=0;j<2;++j) acc[i][j] = (v4f)0.f;

  auto stage = [&](int buf, int k0) {
    #pragma unroll
    for (int it = 0; it < 4; ++it) {
      int s = it*256 + tid;
      int row = s >> 3;
      int kb  = (s & 7) ^ (row & 7);
      *(v8s*)&smA[buf][s*8] = *(const v8s*)(Aw + (size_t)(bm0+row)*K + k0 + kb*8);
    }
    #pragma unroll
    for (int it = 0; it < 2; ++it) {
      int s = it*256 + tid;
      int row = s >> 3;
      int kb  = (s & 7) ^ (row & 7);
      int gn = bn0 + row; if (gn >= Vn) gn = Vn-1;
      *(v8s*)&smB[buf][s*8] = *(const v8s*)(Bw + (size_t)gn*K + k0 + kb*8);
    }
  };
  auto compute = [&](int buf) {
    #pragma unroll
    for (int kc = 0; kc < 2; ++kc) {
      v8s aF[4], bF[2];
      #pragma unroll
      for (int mi = 0; mi < 4; ++mi) {
        int row = wr*64 + mi*16 + lrow;
        int kb = kc*4 + kq;
        aF[mi] = *(const v8s*)&smA[buf][row*64 + ((kb ^ (row&7))<<3)];
      }
      #pragma unroll
      for (int ni = 0; ni < 2; ++ni) {
        int row = wc*32 + ni*16 + lrow;
        int kb = kc*4 + kq;
        bF[ni] = *(const v8s*)&smB[buf][row*64 + ((kb ^ (row&7))<<3)];
      }
      #pragma unroll
      for (int mi = 0; mi < 4; ++mi)
        #pragma unroll
        for (int ni = 0; ni < 2; ++ni)
          acc[mi][ni] = __builtin_amdgcn_mfma_f32_16x16x32_bf16(aF[mi], bF[ni], acc[mi][ni], 0, 0, 0);
    }
  };

  stage(0, 0);
  __syncthreads();
  const int nt = K >> 6;
  for (int tk = 0; tk < nt; ++tk) {
    if (tk + 1 < nt) stage((tk+1)&1, (tk+1)<<6);
    compute(tk&1);
    __syncthreads();
  }

  #pragma unroll
  for (int mi=0; mi<4; ++mi)
    #pragma unroll
    for (int ni=0; ni<2; ++ni)
      #pragma unroll
      for (int r=0; r<4; ++r) {
        int b = wr*64 + mi*16 + kq*4 + r;      // 0..127 within tile = batch row
        int n = bn0 + wc*32 + ni*16 + lrow;
        if (n < Vn) {
          float v = (t0 < declen_i[b]) ? (acc[mi][ni][r] + bias[n]) : 0.f;
          out_pred[((size_t)b*Tn + t0)*Vn + n] = v;
        }
      }
}

// ---------------- e-dot + softmax (thread-per-p) ----------------
__global__ __launch_bounds__(256) void k_esm(
    const unsigned short* __restrict__ att1, const float* __restrict__ att2g,
    const float* __restrict__ fa_w, const float* __restrict__ fa_b,
    float* __restrict__ alpha, float* __restrict__ out_alph,
    const int* __restrict__ declen_i, int t)
{
  int b = blockIdx.x;
  int tid = threadIdx.x;
  if (t >= declen_i[b]) {
    if (tid < Pn)
      out_alph[(size_t)b*Tn*Pn + (size_t)t*Pn + tid] = 0.f;
    return;
  }
  __shared__ float a2s[An];
  __shared__ float fws[An];
  __shared__ float es[Pn];
  __shared__ float wred[4];
  __shared__ float wsum[4];
  for (int i = tid; i < An; i += 256) { a2s[i] = att2g[(size_t)b*2560 + i]; fws[i] = fa_w[i]; }
  __syncthreads();
  int lane = tid & 63, w = tid >> 6;
  if (tid < Pn) {
    const unsigned short* row = att1 + ((size_t)b*Pn + tid)*An;
    float s = 0.f;
    #pragma unroll 4
    for (int kb = 0; kb < 64; ++kb) {
      const v8s vv = *(const v8s*)(row + kb*8);
      #pragma unroll
      for (int j = 0; j < 8; ++j) {
        int a = kb*8 + j;
        float v = bf2f((unsigned short)vv[j]) + a2s[a];
        s += fmaxf(v, 0.f) * fws[a];
      }
    }
    es[tid] = s + fa_b[0];
  }
  __syncthreads();
  float m = -1e30f;
  for (int p = tid; p < Pn; p += 256) m = fmaxf(m, es[p]);
  for (int off = 32; off; off >>= 1) m = fmaxf(m, __shfl_down(m, off));
  if (lane == 0) wred[w] = m;
  __syncthreads();
  m = fmaxf(fmaxf(wred[0], wred[1]), fmaxf(wred[2], wred[3]));
  float s = 0.f;
  for (int p = tid; p < Pn; p += 256) { float ev = __expf(es[p] - m); es[p] = ev; s += ev; }
  for (int off = 32; off; off >>= 1) s += __shfl_down(s, off);
  if (lane == 0) wsum[w] = s;
  __syncthreads();
  s = wsum[0] + wsum[1] + wsum[2] + wsum[3];
  float inv = 1.f / s;
  for (int p = tid; p < Pn; p += 256) {
    float al = es[p] * inv;
    alpha[b*Pn + p] = al;
    out_alph[(size_t)b*Tn*Pn + (size_t)t*Pn + p] = al;
  }
}

// ---------------- awe + gate ----------------
// grid (8, 128): block (ei, b) handles 256-e slice.
__global__ __launch_bounds__(256) void k_awe_gate(
    const unsigned short* __restrict__ enc_bf,
    const float* __restrict__ alpha, const float* __restrict__ att2g,
    unsigned short* __restrict__ xh_t, const int* __restrict__ declen_i, int t)
{
  int b = blockIdx.y;
  if (t >= declen_i[b]) return;
  __shared__ float als[Pn];
  __shared__ float red[8][256];
  int tid = threadIdx.x;
  if (tid < Pn) als[tid] = alpha[b*Pn + tid];
  __syncthreads();
  int e0 = blockIdx.x*256;
  int ec = tid & 31, ps = tid >> 5;
  const unsigned short* eb = enc_bf + (size_t)b*Pn*ENCn + e0 + ec*8;
  float s[8] = {};
  for (int p = ps; p < Pn; p += 8) {
    v8s v = *(const v8s*)(eb + (size_t)p*ENCn);
    float a = als[p];
    #pragma unroll
    for (int j = 0; j < 8; ++j) s[j] += a * bf2f((unsigned short)v[j]);
  }
  #pragma unroll
  for (int j = 0; j < 8; ++j) red[ps][ec*8+j] = s[j];
  __syncthreads();
  {
    int e = tid;
    float tsum = 0.f;
    #pragma unroll
    for (int k = 0; k < 8; ++k) tsum += red[k][e];
    int eg = e0 + e;
    float g = sigf(att2g[(size_t)b*2560 + 512 + eg]);
    xh_t[(size_t)b*3072 + 512 + eg] = f2bf(g*tsum);
  }
}

// ---------------- launch ----------------

extern "C" void kernel_launch(void* const* d_in, const int* in_sizes, int n_in,
                              void* d_out, int out_size, void* d_ws, size_t ws_size,
                              hipStream_t stream)
{
  const float* enc     = (const float*)d_in[0];
  const int*   captions= (const int*)d_in[1];
  const int*   cap_len = (const int*)d_in[2];
  const float* emb_w   = (const float*)d_in[3];
  const float* Wih     = (const float*)d_in[4];
  const float* Whh     = (const float*)d_in[5];
  const float* bih     = (const float*)d_in[6];
  const float* bhh     = (const float*)d_in[7];
  const float* h0_w    = (const float*)d_in[8];
  const float* h0_b    = (const float*)d_in[9];
  const float* c0_w    = (const float*)d_in[10];
  const float* c0_b    = (const float*)d_in[11];
  const float* gate_w  = (const float*)d_in[12];
  const float* gate_b  = (const float*)d_in[13];
  const float* lin_w   = (const float*)d_in[14];
  const float* lin_b   = (const float*)d_in[15];
  const float* ea_w    = (const float*)d_in[16];
  const float* ea_b    = (const float*)d_in[17];
  const float* da_w    = (const float*)d_in[18];
  const float* da_b    = (const float*)d_in[19];
  const float* fa_w    = (const float*)d_in[20];
  const float* fa_b    = (const float*)d_in[21];

  float* out = (float*)d_out;
  float* out_pred   = out;                               // [128][19][10000]
  float* out_caps   = out + (size_t)Bn*Tn*Vn;            // [128][20]
  float* out_declen = out_caps + Bn*Ln;                  // [128]
  float* out_alph   = out_declen + Bn;                   // [128][19][196]
  float* out_order  = out_alph + (size_t)Bn*Tn*Pn;       // [128]

  char* wp = (char*)d_ws;
  auto alloc = [&](size_t bytes)->void* {
    void* p = (void*)wp; wp += (bytes + 255) & ~(size_t)255; return p;
  };
  int*   order_i  = (int*)alloc(Bn*4);
  int*   declen_i = (int*)alloc(Bn*4);
  int*   caps_s   = (int*)alloc(Bn*Ln*4);
  unsigned short* enc_bf  = (unsigned short*)alloc((size_t)Bn*Pn*ENCn*2);  // 102.8 MB
  unsigned short* mean_bf = (unsigned short*)alloc((size_t)Bn*ENCn*2);
  float* hc       = (float*)alloc((size_t)Bn*1024*4);
  float* c        = (float*)alloc((size_t)Bn*Dn*4);
  unsigned short* h_bf   = (unsigned short*)alloc((size_t)Bn*Dn*2);
  unsigned short* h_all  = (unsigned short*)alloc((size_t)Tn*Bn*Dn*2);     // 2.5 MB
  unsigned short* xh_all = (unsigned short*)alloc((size_t)Tn*Bn*3072*2);   // 14.9 MB
  unsigned short* att1   = (unsigned short*)alloc((size_t)Bn*Pn*An*2);     // 25.7 MB
  float* att2g    = (float*)alloc((size_t)Bn*2560*4);
  float* alpha    = (float*)alloc((size_t)Bn*Pn*4);
  unsigned short* ea_bf   = (unsigned short*)alloc((size_t)An*ENCn*2);
  unsigned short* lin_bf  = (unsigned short*)alloc((size_t)Vn*Dn*2);
  unsigned short* h0c0_bf = (unsigned short*)alloc((size_t)1024*ENCn*2);
  unsigned short* dg_bf   = (unsigned short*)alloc((size_t)2560*Dn*2);
  unsigned short* wcat_bf = (unsigned short*)alloc((size_t)2048*3072*2);
  float* bsum = (float*)alloc(2048*4);
  float* dg_b = (float*)alloc(2560*4);
  float* hc_b = (float*)alloc(1024*4);

  // ---- setup ----
  k_order<<<1,128,0,stream>>>(cap_len, captions, order_i, declen_i, caps_s,
                              out_caps, out_declen, out_order);
  k_setup_bias<<<10,256,0,stream>>>(bih, bhh, da_b, gate_b, h0_b, c0_b, bsum, dg_b, hc_b);
  k_cvt6<<<9352,256,0,stream>>>(ea_w, lin_w, h0_w, c0_w, da_w, gate_w,
                                ea_bf, lin_bf, h0c0_bf, dg_bf);
  k_wcat<<<(2048*3072/4+255)/256,256,0,stream>>>(Wih, Whh, wcat_bf);
  k_cvt_enc<<<Bn*Pn,256,0,stream>>>(enc, order_i, enc_bf);
  k_mean<<<Bn,256,0,stream>>>(enc_bf, mean_bf);
  k_emb_all<<<Tn*Bn,256,0,stream>>>(caps_s, emb_w, xh_all);

  // h0/c0
  k_mfma_gemm<<<dim3(16,2),256,0,stream>>>(
      mean_bf, h0c0_bf, hc_b, hc, 1024, ENCn, 1024, nullptr, 0);
  k_h2bf<<<Bn,512,0,stream>>>(hc, c, h_bf, xh_all);

  // att1 = enc_bf @ ea_w^T (bf16 out), 128x64 tiles, XCD-contiguous
  k_att1<<<dim3(196*8),256,0,stream>>>(enc_bf, ea_bf, ea_b, att1);

  for (int t = 0; t < Tn; ++t) {
    unsigned short* xh_t = xh_all + (size_t)t*Bn*3072;
    // att2|gpre = h @ [da_w;gate_w]^T : [128,2560]
    k_mfma_gemm<<<dim3(40,2),256,0,stream>>>(
        h_bf, dg_bf, dg_b, att2g, 2560, Dn, 2560, declen_i, t);
    // e-dot + softmax (thread-per-p)
    k_esm<<<Bn,256,0,stream>>>(att1, att2g, fa_w, fa_b, alpha, out_alph, declen_i, t);
    // awe + gate (1024 blocks)
    k_awe_gate<<<dim3(8,Bn),256,0,stream>>>(enc_bf, alpha, att2g, xh_t, declen_i, t);
    // gates GEMM + LSTM epilogue
    k_gates_lstm<<<dim3(32,2),256,0,stream>>>(
        xh_t, wcat_bf, bsum, c, h_bf, h_all, xh_all, declen_i, t);
  }

  // batched pred over all t: 128x64 tiles
  k_pred<<<dim3((Vn+63)/64, Tn),256,0,stream>>>(
      h_all, lin_bf, lin_b, out_pred, declen_i);
}

// Round 11
// 1700.453 us; speedup vs baseline: 1.0667x; 1.0012x over previous
//
#include <hip/hip_runtime.h>
#include <hip/hip_bf16.h>
#include <math.h>

#define Bn 128
#define Pn 196
#define ENCn 2048
#define Dn 512
#define An 512
#define EDn 512
#define Vn 10000
#define Ln 20
#define Tn 19

typedef short v8s __attribute__((ext_vector_type(8)));
typedef float v4f __attribute__((ext_vector_type(4)));

__device__ __forceinline__ float sigf(float x){ return 1.f/(1.f+__expf(-x)); }
__device__ __forceinline__ unsigned short f2bf(float f){
  unsigned u = __float_as_uint(f);
  return (unsigned short)((u + 0x7FFFu + ((u>>16)&1u)) >> 16);
}
__device__ __forceinline__ float bf2f(unsigned short h){
  return __uint_as_float(((unsigned)h)<<16);
}

// ---------------- setup kernels ----------------

__global__ void k_order(const int* __restrict__ caption_len,
                        const int* __restrict__ captions,
                        int* __restrict__ order_i, int* __restrict__ declen_i,
                        int* __restrict__ caps_s,
                        float* __restrict__ out_caps, float* __restrict__ out_declen,
                        float* __restrict__ out_order)
{
  __shared__ int lens[Bn];
  int b = threadIdx.x;
  lens[b] = caption_len[b];
  __syncthreads();
  int lb = lens[b];
  int r = 0;
  for (int j = 0; j < Bn; ++j) {
    int lj = lens[j];
    r += (int)((lj > lb) || (lj == lb && j < b));
  }
  order_i[r] = b;
  declen_i[r] = lb - 1;
  out_order[r] = (float)b;
  out_declen[r] = (float)(lb - 1);
  for (int t = 0; t < Ln; ++t) {
    int cv = captions[b*Ln + t];
    caps_s[r*Ln + t] = cv;
    out_caps[r*Ln + t] = (float)cv;
  }
}

// bsum reordered to (d*4+g); dg_b / hc_b plain concat
__global__ void k_setup_bias(const float* __restrict__ bih, const float* __restrict__ bhh,
                             const float* __restrict__ da_b, const float* __restrict__ gate_b,
                             const float* __restrict__ h0_b, const float* __restrict__ c0_b,
                             float* __restrict__ bsum_r, float* __restrict__ dg_b,
                             float* __restrict__ hc_b)
{
  int i = blockIdx.x*256 + threadIdx.x;
  if (i < 2048) {
    int d = i >> 2, g = i & 3;
    bsum_r[i] = bih[g*512+d] + bhh[g*512+d];
  }
  if (i < 2560) dg_b[i] = (i < 512) ? da_b[i] : gate_b[i-512];
  if (i < 1024) hc_b[i] = (i < 512) ? h0_b[i] : c0_b[i-512];
}

// merged f32->bf16 conversion of all 6 weight matrices, one dispatch
#define C_EA  (512*2048)
#define C_LIN (10000*512)
#define C_H0  (512*2048)
#define C_C0  (512*2048)
#define C_DA  (512*512)
#define C_GW  (2048*512)
#define CUM1  (C_EA)
#define CUM2  (CUM1 + C_LIN)
#define CUM3  (CUM2 + C_H0)
#define CUM4  (CUM3 + C_C0)
#define CUM5  (CUM4 + C_DA)
#define CUM6  (CUM5 + C_GW)          // 9576448 total, = 9352 blocks * 1024

__global__ void k_cvt6(const float* __restrict__ ea_w, const float* __restrict__ lin_w,
                       const float* __restrict__ h0_w, const float* __restrict__ c0_w,
                       const float* __restrict__ da_w, const float* __restrict__ gate_w,
                       unsigned short* __restrict__ ea_bf, unsigned short* __restrict__ lin_bf,
                       unsigned short* __restrict__ h0c0_bf, unsigned short* __restrict__ dg_bf)
{
  int i = (blockIdx.x*256 + threadIdx.x)*4;
  const float* src; unsigned short* dst; int off;
  if      (i < CUM1) { src = ea_w;   dst = ea_bf;                    off = i; }
  else if (i < CUM2) { src = lin_w;  dst = lin_bf;                   off = i - CUM1; }
  else if (i < CUM3) { src = h0_w;   dst = h0c0_bf;                  off = i - CUM2; }
  else if (i < CUM4) { src = c0_w;   dst = h0c0_bf + (size_t)C_H0;   off = i - CUM3; }
  else if (i < CUM5) { src = da_w;   dst = dg_bf;                    off = i - CUM4; }
  else               { src = gate_w; dst = dg_bf + (size_t)C_DA;     off = i - CUM5; }
  float4 v = *(const float4*)(src + off);
  dst[off+0]=f2bf(v.x); dst[off+1]=f2bf(v.y); dst[off+2]=f2bf(v.z); dst[off+3]=f2bf(v.w);
}

// wcat_r[d*4+g][3072] = [Wih | Whh][g*512+d][:] in bf16 (gate-interleaved rows)
__global__ void k_wcat(const float* __restrict__ Wih, const float* __restrict__ Whh,
                       unsigned short* __restrict__ dst)
{
  int i = (blockIdx.x*256 + threadIdx.x)*4;
  if (i >= 2048*3072) return;
  int rp = i/3072, j = i - rp*3072;
  int d = rp >> 2, g = rp & 3;
  int r = g*512 + d;
  const float* s = (j < 2560) ? (Wih + (size_t)r*2560 + j) : (Whh + (size_t)r*512 + (j-2560));
  float4 v = *(const float4*)s;
  dst[i+0]=f2bf(v.x); dst[i+1]=f2bf(v.y); dst[i+2]=f2bf(v.z); dst[i+3]=f2bf(v.w);
}

__global__ void k_cvt_enc(const float* __restrict__ enc, const int* __restrict__ order_i,
                          unsigned short* __restrict__ dst)
{
  int id = blockIdx.x;               // b*196+p
  int b = id / Pn, p = id - b*Pn;
  const float* src = enc + ((size_t)order_i[b]*Pn + p)*ENCn;
  unsigned short* d = dst + (size_t)id*ENCn;
  int i = threadIdx.x*8;
  float4 v0 = *(const float4*)(src+i), v1 = *(const float4*)(src+i+4);
  d[i+0]=f2bf(v0.x); d[i+1]=f2bf(v0.y); d[i+2]=f2bf(v0.z); d[i+3]=f2bf(v0.w);
  d[i+4]=f2bf(v1.x); d[i+5]=f2bf(v1.y); d[i+6]=f2bf(v1.z); d[i+7]=f2bf(v1.w);
}

__global__ void k_mean(const unsigned short* __restrict__ enc_bf,
                       unsigned short* __restrict__ mean_bf)
{
  int b = blockIdx.x;
  const unsigned short* eb = enc_bf + (size_t)b*Pn*ENCn;
  for (int e = threadIdx.x; e < ENCn; e += 256) {
    float s = 0.f;
    for (int p = 0; p < Pn; ++p) s += bf2f(eb[(size_t)p*ENCn + e]);
    mean_bf[b*ENCn + e] = f2bf(s * (1.f/196.f));
  }
}

__global__ void k_emb_all(const int* __restrict__ caps_s, const float* __restrict__ emb_w,
                          unsigned short* __restrict__ xh_all)
{
  int id = blockIdx.x; int t = id >> 7, b = id & 127;
  int tok = caps_s[b*Ln + t];
  const float* src = emb_w + (size_t)tok*EDn;
  unsigned short* d = xh_all + ((size_t)t*Bn + b)*3072;
  int i = threadIdx.x*2;
  float2 v = *(const float2*)(src+i);
  d[i] = f2bf(v.x); d[i+1] = f2bf(v.y);
}

__global__ void k_h2bf(const float* __restrict__ hc, float* __restrict__ c,
                       unsigned short* __restrict__ h_bf, unsigned short* __restrict__ xh_all)
{
  int b = blockIdx.x, d = threadIdx.x;
  float hv = hc[b*1024 + d];
  float cv = hc[b*1024 + 512 + d];
  c[b*Dn + d] = cv;
  unsigned short hb = f2bf(hv);
  h_bf[b*Dn + d] = hb;
  xh_all[(size_t)b*3072 + 2560 + d] = hb;
}

// ---------------- bf16 MFMA GEMM 64x64: C[M,N] = A @ B^T (+bias) ----------------
// grid (N/64, M/64); actlen tile-skip (sorted declen, prefix-active).
__global__ __launch_bounds__(256) void k_mfma_gemm(
    const unsigned short* __restrict__ Aw, const unsigned short* __restrict__ Bw,
    const float* __restrict__ bias, float* __restrict__ Cp,
    int N, int K, size_t ldc,
    const int* __restrict__ actlen, int t)
{
  __shared__ unsigned short smA[2][4096];
  __shared__ unsigned short smB[2][4096];
  const int tid = threadIdx.x;
  const int bm0 = blockIdx.y*64, bn0 = blockIdx.x*64;
  if (actlen && actlen[bm0] <= t) return;

  const int lane = tid & 63, w = tid >> 6;
  const int wr = w >> 1, wc = w & 1;
  const int lrow = lane & 15, kq = lane >> 4;

  v4f acc[2][2];
  #pragma unroll
  for (int i=0;i<2;++i)
    #pragma unroll
    for (int j=0;j<2;++j) acc[i][j] = (v4f)0.f;

  const int nt = K >> 6;

  auto stage = [&](int buf, int k0) {
    #pragma unroll
    for (int it = 0; it < 2; ++it) {
      int s = it*256 + tid;
      int row = s >> 3;
      int kb  = (s & 7) ^ (row & 7);
      *(v8s*)&smA[buf][s*8] = *(const v8s*)(Aw + (size_t)(bm0+row)*K + k0 + kb*8);
      *(v8s*)&smB[buf][s*8] = *(const v8s*)(Bw + (size_t)(bn0+row)*K + k0 + kb*8);
    }
  };
  auto compute = [&](int buf) {
    #pragma unroll
    for (int kc = 0; kc < 2; ++kc) {
      v8s aF[2], bF[2];
      #pragma unroll
      for (int mi = 0; mi < 2; ++mi) {
        int row = wr*32 + mi*16 + lrow;
        int kb = kc*4 + kq;
        aF[mi] = *(const v8s*)&smA[buf][row*64 + ((kb ^ (row&7))<<3)];
      }
      #pragma unroll
      for (int ni = 0; ni < 2; ++ni) {
        int row = wc*32 + ni*16 + lrow;
        int kb = kc*4 + kq;
        bF[ni] = *(const v8s*)&smB[buf][row*64 + ((kb ^ (row&7))<<3)];
      }
      #pragma unroll
      for (int mi = 0; mi < 2; ++mi)
        #pragma unroll
        for (int ni = 0; ni < 2; ++ni)
          acc[mi][ni] = __builtin_amdgcn_mfma_f32_16x16x32_bf16(aF[mi], bF[ni], acc[mi][ni], 0, 0, 0);
    }
  };

  stage(0, 0);
  __syncthreads();
  for (int tk = 0; tk < nt; ++tk) {
    if (tk + 1 < nt) stage((tk+1)&1, (tk+1)<<6);
    compute(tk&1);
    __syncthreads();
  }

  #pragma unroll
  for (int mi=0; mi<2; ++mi)
    #pragma unroll
    for (int ni=0; ni<2; ++ni)
      #pragma unroll
      for (int r=0; r<4; ++r) {
        int m = bm0 + wr*32 + mi*16 + kq*4 + r;
        int n = bn0 + wc*32 + ni*16 + lrow;
        Cp[(size_t)m*ldc + n] = acc[mi][ni][r] + bias[n];
      }
}

// ---------------- att1 GEMM: 128x64 tile, XCD-contiguous ----------------
__global__ __launch_bounds__(256) void k_att1(
    const unsigned short* __restrict__ Aw, const unsigned short* __restrict__ Bw,
    const float* __restrict__ bias, unsigned short* __restrict__ Cp)
{
  __shared__ unsigned short smA[2][8192];
  __shared__ unsigned short smB[2][4096];
  const int tid = threadIdx.x;
  const int id = blockIdx.x;
  const int g = (id & 7)*196 + (id >> 3);   // XCD-contiguous panel walk
  const int bm0 = (g >> 3) * 128, bn0 = (g & 7) * 64;
  const int K = ENCn;

  const int lane = tid & 63, w = tid >> 6;
  const int wr = w >> 1, wc = w & 1;
  const int lrow = lane & 15, kq = lane >> 4;

  v4f acc[4][2];
  #pragma unroll
  for (int i=0;i<4;++i)
    #pragma unroll
    for (int j=0;j<2;++j) acc[i][j] = (v4f)0.f;

  auto stage = [&](int buf, int k0) {
    #pragma unroll
    for (int it = 0; it < 4; ++it) {
      int s = it*256 + tid;
      int row = s >> 3;
      int kb  = (s & 7) ^ (row & 7);
      *(v8s*)&smA[buf][s*8] = *(const v8s*)(Aw + (size_t)(bm0+row)*K + k0 + kb*8);
    }
    #pragma unroll
    for (int it = 0; it < 2; ++it) {
      int s = it*256 + tid;
      int row = s >> 3;
      int kb  = (s & 7) ^ (row & 7);
      *(v8s*)&smB[buf][s*8] = *(const v8s*)(Bw + (size_t)(bn0+row)*K + k0 + kb*8);
    }
  };
  auto compute = [&](int buf) {
    #pragma unroll
    for (int kc = 0; kc < 2; ++kc) {
      v8s aF[4], bF[2];
      #pragma unroll
      for (int mi = 0; mi < 4; ++mi) {
        int row = wr*64 + mi*16 + lrow;
        int kb = kc*4 + kq;
        aF[mi] = *(const v8s*)&smA[buf][row*64 + ((kb ^ (row&7))<<3)];
      }
      #pragma unroll
      for (int ni = 0; ni < 2; ++ni) {
        int row = wc*32 + ni*16 + lrow;
        int kb = kc*4 + kq;
        bF[ni] = *(const v8s*)&smB[buf][row*64 + ((kb ^ (row&7))<<3)];
      }
      #pragma unroll
      for (int mi = 0; mi < 4; ++mi)
        #pragma unroll
        for (int ni = 0; ni < 2; ++ni)
          acc[mi][ni] = __builtin_amdgcn_mfma_f32_16x16x32_bf16(aF[mi], bF[ni], acc[mi][ni], 0, 0, 0);
    }
  };

  stage(0, 0);
  __syncthreads();
  const int nt = K >> 6;
  for (int tk = 0; tk < nt; ++tk) {
    if (tk + 1 < nt) stage((tk+1)&1, (tk+1)<<6);
    compute(tk&1);
    __syncthreads();
  }

  #pragma unroll
  for (int mi=0; mi<4; ++mi)
    #pragma unroll
    for (int ni=0; ni<2; ++ni)
      #pragma unroll
      for (int r=0; r<4; ++r) {
        int m = bm0 + wr*64 + mi*16 + kq*4 + r;
        int n = bn0 + wc*32 + ni*16 + lrow;
        Cp[(size_t)m*An + n] = f2bf(acc[mi][ni][r] + bias[n]);
      }
}

// ---------------- gates GEMM + LSTM epilogue ----------------
__global__ __launch_bounds__(256) void k_gates_lstm(
    const unsigned short* __restrict__ Aw, const unsigned short* __restrict__ Bw,
    const float* __restrict__ bias,
    float* __restrict__ c, unsigned short* __restrict__ h_bf,
    unsigned short* __restrict__ h_all, unsigned short* __restrict__ xh_all,
    const int* __restrict__ declen_i, int t)
{
  __shared__ unsigned short smA[2][4096];
  __shared__ unsigned short smB[2][4096];
  __shared__ float smC[64][65];
  const int tid = threadIdx.x;
  const int bm0 = blockIdx.y*64, bn0 = blockIdx.x*64;
  if (declen_i[bm0] <= t) return;

  const int lane = tid & 63, w = tid >> 6;
  const int wr = w >> 1, wc = w & 1;
  const int lrow = lane & 15, kq = lane >> 4;
  const int K = 3072;

  v4f acc[2][2];
  #pragma unroll
  for (int i=0;i<2;++i)
    #pragma unroll
    for (int j=0;j<2;++j) acc[i][j] = (v4f)0.f;

  auto stage = [&](int buf, int k0) {
    #pragma unroll
    for (int it = 0; it < 2; ++it) {
      int s = it*256 + tid;
      int row = s >> 3;
      int kb  = (s & 7) ^ (row & 7);
      *(v8s*)&smA[buf][s*8] = *(const v8s*)(Aw + (size_t)(bm0+row)*K + k0 + kb*8);
      *(v8s*)&smB[buf][s*8] = *(const v8s*)(Bw + (size_t)(bn0+row)*K + k0 + kb*8);
    }
  };
  auto compute = [&](int buf) {
    #pragma unroll
    for (int kc = 0; kc < 2; ++kc) {
      v8s aF[2], bF[2];
      #pragma unroll
      for (int mi = 0; mi < 2; ++mi) {
        int row = wr*32 + mi*16 + lrow;
        int kb = kc*4 + kq;
        aF[mi] = *(const v8s*)&smA[buf][row*64 + ((kb ^ (row&7))<<3)];
      }
      #pragma unroll
      for (int ni = 0; ni < 2; ++ni) {
        int row = wc*32 + ni*16 + lrow;
        int kb = kc*4 + kq;
        bF[ni] = *(const v8s*)&smB[buf][row*64 + ((kb ^ (row&7))<<3)];
      }
      #pragma unroll
      for (int mi = 0; mi < 2; ++mi)
        #pragma unroll
        for (int ni = 0; ni < 2; ++ni)
          acc[mi][ni] = __builtin_amdgcn_mfma_f32_16x16x32_bf16(aF[mi], bF[ni], acc[mi][ni], 0, 0, 0);
    }
  };

  stage(0, 0);
  __syncthreads();
  const int nt = K >> 6;
  for (int tk = 0; tk < nt; ++tk) {
    if (tk + 1 < nt) stage((tk+1)&1, (tk+1)<<6);
    compute(tk&1);
    __syncthreads();
  }

  #pragma unroll
  for (int mi=0; mi<2; ++mi)
    #pragma unroll
    for (int ni=0; ni<2; ++ni)
      #pragma unroll
      for (int r=0; r<4; ++r) {
        int ml = wr*32 + mi*16 + kq*4 + r;
        int nl = wc*32 + ni*16 + lrow;
        smC[ml][nl] = acc[mi][ni][r] + bias[bn0 + nl];
      }
  __syncthreads();

  for (int idx = tid; idx < 1024; idx += 256) {
    int ml = idx >> 4, dl = idx & 15;
    int b = bm0 + ml;
    if (t < declen_i[b]) {
      int dg = (bn0 >> 2) + dl;
      float gi = smC[ml][dl*4+0];
      float gf = smC[ml][dl*4+1];
      float gg = smC[ml][dl*4+2];
      float go = smC[ml][dl*4+3];
      float cv = c[b*Dn + dg];
      float cn = sigf(gf)*cv + sigf(gi)*tanhf(gg);
      float hn = sigf(go)*tanhf(cn);
      c[b*Dn + dg] = cn;
      unsigned short hb = f2bf(hn);
      h_bf[b*Dn + dg] = hb;
      h_all[((size_t)t*Bn + b)*Dn + dg] = hb;
      if (t + 1 < Tn)
        xh_all[((size_t)(t+1)*Bn + b)*3072 + 2560 + dg] = hb;
    }
  }
}

// ---------------- batched pred GEMM (all t, 64x64 tiles with inactive-tile skip) ----------------
__global__ __launch_bounds__(256) void k_pred(
    const unsigned short* __restrict__ Aw, const unsigned short* __restrict__ Bw,
    const float* __restrict__ bias, float* __restrict__ out_pred,
    const int* __restrict__ declen_i)
{
  __shared__ unsigned short smA[2][4096];
  __shared__ unsigned short smB[2][4096];
  const int tid = threadIdx.x;
  const int bm0 = blockIdx.y*64, bn0 = blockIdx.x*64;
  const int t0 = bm0 >> 7, b0 = bm0 & 127;

  if (declen_i[b0] <= t0) {
    for (int i = tid; i < 4096; i += 256) {
      int ml = i >> 6, nl = i & 63;
      int n = bn0 + nl;
      if (n < Vn) {
        int m = bm0 + ml;
        out_pred[((size_t)(m & 127)*Tn + (m >> 7))*Vn + n] = 0.f;
      }
    }
    return;
  }

  const int lane = tid & 63, w = tid >> 6;
  const int wr = w >> 1, wc = w & 1;
  const int lrow = lane & 15, kq = lane >> 4;
  const int K = 512;

  v4f acc[2][2];
  #pragma unroll
  for (int i=0;i<2;++i)
    #pragma unroll
    for (int j=0;j<2;++j) acc[i][j] = (v4f)0.f;

  auto stage = [&](int buf, int k0) {
    #pragma unroll
    for (int it = 0; it < 2; ++it) {
      int s = it*256 + tid;
      int row = s >> 3;
      int kb  = (s & 7) ^ (row & 7);
      *(v8s*)&smA[buf][s*8] = *(const v8s*)(Aw + (size_t)(bm0+row)*K + k0 + kb*8);
      {
        int gn = bn0 + row; if (gn >= Vn) gn = Vn-1;
        *(v8s*)&smB[buf][s*8] = *(const v8s*)(Bw + (size_t)gn*K + k0 + kb*8);
      }
    }
  };
  auto compute = [&](int buf) {
    #pragma unroll
    for (int kc = 0; kc < 2; ++kc) {
      v8s aF[2], bF[2];
      #pragma unroll
      for (int mi = 0; mi < 2; ++mi) {
        int row = wr*32 + mi*16 + lrow;
        int kb = kc*4 + kq;
        aF[mi] = *(const v8s*)&smA[buf][row*64 + ((kb ^ (row&7))<<3)];
      }
      #pragma unroll
      for (int ni = 0; ni < 2; ++ni) {
        int row = wc*32 + ni*16 + lrow;
        int kb = kc*4 + kq;
        bF[ni] = *(const v8s*)&smB[buf][row*64 + ((kb ^ (row&7))<<3)];
      }
      #pragma unroll
      for (int mi = 0; mi < 2; ++mi)
        #pragma unroll
        for (int ni = 0; ni < 2; ++ni)
          acc[mi][ni] = __builtin_amdgcn_mfma_f32_16x16x32_bf16(aF[mi], bF[ni], acc[mi][ni], 0, 0, 0);
    }
  };

  stage(0, 0);
  __syncthreads();
  const int nt = K >> 6;
  for (int tk = 0; tk < nt; ++tk) {
    if (tk + 1 < nt) stage((tk+1)&1, (tk+1)<<6);
    compute(tk&1);
    __syncthreads();
  }

  #pragma unroll
  for (int mi=0; mi<2; ++mi)
    #pragma unroll
    for (int ni=0; ni<2; ++ni)
      #pragma unroll
      for (int r=0; r<4; ++r) {
        int m = bm0 + wr*32 + mi*16 + kq*4 + r;
        int n = bn0 + wc*32 + ni*16 + lrow;
        if (n < Vn) {
          int b = m & 127, tt = m >> 7;
          float v = (tt < declen_i[b]) ? (acc[mi][ni][r] + bias[n]) : 0.f;
          out_pred[((size_t)b*Tn + tt)*Vn + n] = v;
        }
      }
}

// ---------------- e-dot + softmax (thread-per-p) ----------------
__global__ __launch_bounds__(256) void k_esm(
    const unsigned short* __restrict__ att1, const float* __restrict__ att2g,
    const float* __restrict__ fa_w, const float* __restrict__ fa_b,
    float* __restrict__ alpha, float* __restrict__ out_alph,
    const int* __restrict__ declen_i, int t)
{
  int b = blockIdx.x;
  int tid = threadIdx.x;
  if (t >= declen_i[b]) {
    if (tid < Pn)
      out_alph[(size_t)b*Tn*Pn + (size_t)t*Pn + tid] = 0.f;
    return;
  }
  __shared__ float a2s[An];
  __shared__ float fws[An];
  __shared__ float es[Pn];
  __shared__ float wred[4];
  __shared__ float wsum[4];
  for (int i = tid; i < An; i += 256) { a2s[i] = att2g[(size_t)b*2560 + i]; fws[i] = fa_w[i]; }
  __syncthreads();
  int lane = tid & 63, w = tid >> 6;
  if (tid < Pn) {
    const unsigned short* row = att1 + ((size_t)b*Pn + tid)*An;
    float s = 0.f;
    #pragma unroll 4
    for (int kb = 0; kb < 64; ++kb) {
      const v8s vv = *(const v8s*)(row + kb*8);
      #pragma unroll
      for (int j = 0; j < 8; ++j) {
        int a = kb*8 + j;
        float v = bf2f((unsigned short)vv[j]) + a2s[a];
        s += fmaxf(v, 0.f) * fws[a];
      }
    }
    es[tid] = s + fa_b[0];
  }
  __syncthreads();
  float m = -1e30f;
  for (int p = tid; p < Pn; p += 256) m = fmaxf(m, es[p]);
  for (int off = 32; off; off >>= 1) m = fmaxf(m, __shfl_down(m, off));
  if (lane == 0) wred[w] = m;
  __syncthreads();
  m = fmaxf(fmaxf(wred[0], wred[1]), fmaxf(wred[2], wred[3]));
  float s = 0.f;
  for (int p = tid; p < Pn; p += 256) { float ev = __expf(es[p] - m); es[p] = ev; s += ev; }
  for (int off = 32; off; off >>= 1) s += __shfl_down(s, off);
  if (lane == 0) wsum[w] = s;
  __syncthreads();
  s = wsum[0] + wsum[1] + wsum[2] + wsum[3];
  float inv = 1.f / s;
  for (int p = tid; p < Pn; p += 256) {
    float al = es[p] * inv;
    alpha[b*Pn + p] = al;
    out_alph[(size_t)b*Tn*Pn + (size_t)t*Pn + p] = al;
  }
}

// ---------------- awe + gate ----------------
// grid (8, 128): block (ei, b) handles 256-e slice.
__global__ __launch_bounds__(256) void k_awe_gate(
    const unsigned short* __restrict__ enc_bf,
    const float* __restrict__ alpha, const float* __restrict__ att2g,
    unsigned short* __restrict__ xh_t, const int* __restrict__ declen_i, int t)
{
  int b = blockIdx.y;
  if (t >= declen_i[b]) return;
  __shared__ float als[Pn];
  __shared__ float red[8][256];
  int tid = threadIdx.x;
  if (tid < Pn) als[tid] = alpha[b*Pn + tid];
  __syncthreads();
  int e0 = blockIdx.x*256;
  int ec = tid & 31, ps = tid >> 5;
  const unsigned short* eb = enc_bf + (size_t)b*Pn*ENCn + e0 + ec*8;
  float s[8] = {};
  for (int p = ps; p < Pn; p += 8) {
    v8s v = *(const v8s*)(eb + (size_t)p*ENCn);
    float a = als[p];
    #pragma unroll
    for (int j = 0; j < 8; ++j) s[j] += a * bf2f((unsigned short)v[j]);
  }
  #pragma unroll
  for (int j = 0; j < 8; ++j) red[ps][ec*8+j] = s[j];
  __syncthreads();
  {
    int e = tid;
    float tsum = 0.f;
    #pragma unroll
    for (int k = 0; k < 8; ++k) tsum += red[k][e];
    int eg = e0 + e;
    float g = sigf(att2g[(size_t)b*2560 + 512 + eg]);
    xh_t[(size_t)b*3072 + 512 + eg] = f2bf(g*tsum);
  }
}

// ---------------- launch ----------------

extern "C" void kernel_launch(void* const* d_in, const int* in_sizes, int n_in,
                              void* d_out, int out_size, void* d_ws, size_t ws_size,
                              hipStream_t stream)
{
  const float* enc     = (const float*)d_in[0];
  const int*   captions= (const int*)d_in[1];
  const int*   cap_len = (const int*)d_in[2];
  const float* emb_w   = (const float*)d_in[3];
  const float* Wih     = (const float*)d_in[4];
  const float* Whh     = (const float*)d_in[5];
  const float* bih     = (const float*)d_in[6];
  const float* bhh     = (const float*)d_in[7];
  const float* h0_w    = (const float*)d_in[8];
  const float* h0_b    = (const float*)d_in[9];
  const float* c0_w    = (const float*)d_in[10];
  const float* c0_b    = (const float*)d_in[11];
  const float* gate_w  = (const float*)d_in[12];
  const float* gate_b  = (const float*)d_in[13];
  const float* lin_w   = (const float*)d_in[14];
  const float* lin_b   = (const float*)d_in[15];
  const float* ea_w    = (const float*)d_in[16];
  const float* ea_b    = (const float*)d_in[17];
  const float* da_w    = (const float*)d_in[18];
  const float* da_b    = (const float*)d_in[19];
  const float* fa_w    = (const float*)d_in[20];
  const float* fa_b    = (const float*)d_in[21];

  float* out = (float*)d_out;
  float* out_pred   = out;                               // [128][19][10000]
  float* out_caps   = out + (size_t)Bn*Tn*Vn;            // [128][20]
  float* out_declen = out_caps + Bn*Ln;                  // [128]
  float* out_alph   = out_declen + Bn;                   // [128][19][196]
  float* out_order  = out_alph + (size_t)Bn*Tn*Pn;       // [128]

  char* wp = (char*)d_ws;
  auto alloc = [&](size_t bytes)->void* {
    void* p = (void*)wp; wp += (bytes + 255) & ~(size_t)255; return p;
  };
  int*   order_i  = (int*)alloc(Bn*4);
  int*   declen_i = (int*)alloc(Bn*4);
  int*   caps_s   = (int*)alloc(Bn*Ln*4);
  unsigned short* enc_bf  = (unsigned short*)alloc((size_t)Bn*Pn*ENCn*2);  // 102.8 MB
  unsigned short* mean_bf = (unsigned short*)alloc((size_t)Bn*ENCn*2);
  float* hc       = (float*)alloc((size_t)Bn*1024*4);
  float* c        = (float*)alloc((size_t)Bn*Dn*4);
  unsigned short* h_bf   = (unsigned short*)alloc((size_t)Bn*Dn*2);
  unsigned short* h_all  = (unsigned short*)alloc((size_t)Tn*Bn*Dn*2);     // 2.5 MB
  unsigned short* xh_all = (unsigned short*)alloc((size_t)Tn*Bn*3072*2);   // 14.9 MB
  unsigned short* att1   = (unsigned short*)alloc((size_t)Bn*Pn*An*2);     // 25.7 MB
  float* att2g    = (float*)alloc((size_t)Bn*2560*4);
  float* alpha    = (float*)alloc((size_t)Bn*Pn*4);
  unsigned short* ea_bf   = (unsigned short*)alloc((size_t)An*ENCn*2);
  unsigned short* lin_bf  = (unsigned short*)alloc((size_t)Vn*Dn*2);
  unsigned short* h0c0_bf = (unsigned short*)alloc((size_t)1024*ENCn*2);
  unsigned short* dg_bf   = (unsigned short*)alloc((size_t)2560*Dn*2);
  unsigned short* wcat_bf = (unsigned short*)alloc((size_t)2048*3072*2);
  float* bsum = (float*)alloc(2048*4);
  float* dg_b = (float*)alloc(2560*4);
  float* hc_b = (float*)alloc(1024*4);

  // ---- setup ----
  k_order<<<1,128,0,stream>>>(cap_len, captions, order_i, declen_i, caps_s,
                              out_caps, out_declen, out_order);
  k_setup_bias<<<10,256,0,stream>>>(bih, bhh, da_b, gate_b, h0_b, c0_b, bsum, dg_b, hc_b);
  k_cvt6<<<9352,256,0,stream>>>(ea_w, lin_w, h0_w, c0_w, da_w, gate_w,
                                ea_bf, lin_bf, h0c0_bf, dg_bf);
  k_wcat<<<(2048*3072/4+255)/256,256,0,stream>>>(Wih, Whh, wcat_bf);
  k_cvt_enc<<<Bn*Pn,256,0,stream>>>(enc, order_i, enc_bf);
  k_mean<<<Bn,256,0,stream>>>(enc_bf, mean_bf);
  k_emb_all<<<Tn*Bn,256,0,stream>>>(caps_s, emb_w, xh_all);

  // h0/c0
  k_mfma_gemm<<<dim3(16,2),256,0,stream>>>(
      mean_bf, h0c0_bf, hc_b, hc, 1024, ENCn, 1024, nullptr, 0);
  k_h2bf<<<Bn,512,0,stream>>>(hc, c, h_bf, xh_all);

  // att1 = enc_bf @ ea_w^T (bf16 out), 128x64 tiles, XCD-contiguous
  k_att1<<<dim3(196*8),256,0,stream>>>(enc_bf, ea_bf, ea_b, att1);

  for (int t = 0; t < Tn; ++t) {
    unsigned short* xh_t = xh_all + (size_t)t*Bn*3072;
    // att2|gpre = h @ [da_w;gate_w]^T : [128,2560]
    k_mfma_gemm<<<dim3(40,2),256,0,stream>>>(
        h_bf, dg_bf, dg_b, att2g, 2560, Dn, 2560, declen_i, t);
    // e-dot + softmax (thread-per-p)
    k_esm<<<Bn,256,0,stream>>>(att1, att2g, fa_w, fa_b, alpha, out_alph, declen_i, t);
    // awe + gate (1024 blocks)
    k_awe_gate<<<dim3(8,Bn),256,0,stream>>>(enc_bf, alpha, att2g, xh_t, declen_i, t);
    // gates GEMM + LSTM epilogue
    k_gates_lstm<<<dim3(32,2),256,0,stream>>>(
        xh_t, wcat_bf, bsum, c, h_bf, h_all, xh_all, declen_i, t);
  }

  // batched pred over all t: 64x64 tiles with inactive-tile skip
  k_pred<<<dim3((Vn+63)/64, (Tn*Bn)/64),256,0,stream>>>(
      h_all, lin_bf, lin_b, out_pred, declen_i);
}

// Round 12
// 1470.366 us; speedup vs baseline: 1.2336x; 1.1565x over previous
//
#include <hip/hip_runtime.h>
#include <hip/hip_bf16.h>
#include <math.h>

#define Bn 128
#define Pn 196
#define ENCn 2048
#define Dn 512
#define An 512
#define EDn 512
#define Vn 10000
#define Ln 20
#define Tn 19

typedef short v8s __attribute__((ext_vector_type(8)));
typedef float v4f __attribute__((ext_vector_type(4)));

__device__ __forceinline__ float sigf(float x){ return 1.f/(1.f+__expf(-x)); }
__device__ __forceinline__ unsigned short f2bf(float f){
  unsigned u = __float_as_uint(f);
  return (unsigned short)((u + 0x7FFFu + ((u>>16)&1u)) >> 16);
}
__device__ __forceinline__ float bf2f(unsigned short h){
  return __uint_as_float(((unsigned)h)<<16);
}

// ---------------- setup kernels ----------------

__global__ void k_order(const int* __restrict__ caption_len,
                        const int* __restrict__ captions,
                        int* __restrict__ order_i, int* __restrict__ declen_i,
                        int* __restrict__ caps_s,
                        float* __restrict__ out_caps, float* __restrict__ out_declen,
                        float* __restrict__ out_order)
{
  __shared__ int lens[Bn];
  int b = threadIdx.x;
  lens[b] = caption_len[b];
  __syncthreads();
  int lb = lens[b];
  int r = 0;
  for (int j = 0; j < Bn; ++j) {
    int lj = lens[j];
    r += (int)((lj > lb) || (lj == lb && j < b));
  }
  order_i[r] = b;
  declen_i[r] = lb - 1;
  out_order[r] = (float)b;
  out_declen[r] = (float)(lb - 1);
  for (int t = 0; t < Ln; ++t) {
    int cv = captions[b*Ln + t];
    caps_s[r*Ln + t] = cv;
    out_caps[r*Ln + t] = (float)cv;
  }
}

// bsum reordered to (d*4+g); dg_b / hc_b plain concat
__global__ void k_setup_bias(const float* __restrict__ bih, const float* __restrict__ bhh,
                             const float* __restrict__ da_b, const float* __restrict__ gate_b,
                             const float* __restrict__ h0_b, const float* __restrict__ c0_b,
                             float* __restrict__ bsum_r, float* __restrict__ dg_b,
                             float* __restrict__ hc_b)
{
  int i = blockIdx.x*256 + threadIdx.x;
  if (i < 2048) {
    int d = i >> 2, g = i & 3;
    bsum_r[i] = bih[g*512+d] + bhh[g*512+d];
  }
  if (i < 2560) dg_b[i] = (i < 512) ? da_b[i] : gate_b[i-512];
  if (i < 1024) hc_b[i] = (i < 512) ? h0_b[i] : c0_b[i-512];
}

// merged f32->bf16 conversion of all 6 weight matrices, one dispatch
#define C_EA  (512*2048)
#define C_LIN (10000*512)
#define C_H0  (512*2048)
#define C_C0  (512*2048)
#define C_DA  (512*512)
#define C_GW  (2048*512)
#define CUM1  (C_EA)
#define CUM2  (CUM1 + C_LIN)
#define CUM3  (CUM2 + C_H0)
#define CUM4  (CUM3 + C_C0)
#define CUM5  (CUM4 + C_DA)
#define CUM6  (CUM5 + C_GW)          // 9576448 total, = 9352 blocks * 1024

__global__ void k_cvt6(const float* __restrict__ ea_w, const float* __restrict__ lin_w,
                       const float* __restrict__ h0_w, const float* __restrict__ c0_w,
                       const float* __restrict__ da_w, const float* __restrict__ gate_w,
                       unsigned short* __restrict__ ea_bf, unsigned short* __restrict__ lin_bf,
                       unsigned short* __restrict__ h0c0_bf, unsigned short* __restrict__ dg_bf)
{
  int i = (blockIdx.x*256 + threadIdx.x)*4;
  const float* src; unsigned short* dst; int off;
  if      (i < CUM1) { src = ea_w;   dst = ea_bf;                    off = i; }
  else if (i < CUM2) { src = lin_w;  dst = lin_bf;                   off = i - CUM1; }
  else if (i < CUM3) { src = h0_w;   dst = h0c0_bf;                  off = i - CUM2; }
  else if (i < CUM4) { src = c0_w;   dst = h0c0_bf + (size_t)C_H0;   off = i - CUM3; }
  else if (i < CUM5) { src = da_w;   dst = dg_bf;                    off = i - CUM4; }
  else               { src = gate_w; dst = dg_bf + (size_t)C_DA;     off = i - CUM5; }
  float4 v = *(const float4*)(src + off);
  dst[off+0]=f2bf(v.x); dst[off+1]=f2bf(v.y); dst[off+2]=f2bf(v.z); dst[off+3]=f2bf(v.w);
}

// wcat_r[d*4+g][3072] = [Wih | Whh][g*512+d][:] in bf16 (gate-interleaved rows)
__global__ void k_wcat(const float* __restrict__ Wih, const float* __restrict__ Whh,
                       unsigned short* __restrict__ dst)
{
  int i = (blockIdx.x*256 + threadIdx.x)*4;
  if (i >= 2048*3072) return;
  int rp = i/3072, j = i - rp*3072;
  int d = rp >> 2, g = rp & 3;
  int r = g*512 + d;
  const float* s = (j < 2560) ? (Wih + (size_t)r*2560 + j) : (Whh + (size_t)r*512 + (j-2560));
  float4 v = *(const float4*)s;
  dst[i+0]=f2bf(v.x); dst[i+1]=f2bf(v.y); dst[i+2]=f2bf(v.z); dst[i+3]=f2bf(v.w);
}

__global__ void k_cvt_enc(const float* __restrict__ enc, const int* __restrict__ order_i,
                          unsigned short* __restrict__ dst)
{
  int id = blockIdx.x;               // b*196+p
  int b = id / Pn, p = id - b*Pn;
  const float* src = enc + ((size_t)order_i[b]*Pn + p)*ENCn;
  unsigned short* d = dst + (size_t)id*ENCn;
  int i = threadIdx.x*8;
  float4 v0 = *(const float4*)(src+i), v1 = *(const float4*)(src+i+4);
  d[i+0]=f2bf(v0.x); d[i+1]=f2bf(v0.y); d[i+2]=f2bf(v0.z); d[i+3]=f2bf(v0.w);
  d[i+4]=f2bf(v1.x); d[i+5]=f2bf(v1.y); d[i+6]=f2bf(v1.z); d[i+7]=f2bf(v1.w);
}

__global__ void k_mean(const unsigned short* __restrict__ enc_bf,
                       unsigned short* __restrict__ mean_bf)
{
  int b = blockIdx.x;
  const unsigned short* eb = enc_bf + (size_t)b*Pn*ENCn;
  for (int e = threadIdx.x; e < ENCn; e += 256) {
    float s = 0.f;
    for (int p = 0; p < Pn; ++p) s += bf2f(eb[(size_t)p*ENCn + e]);
    mean_bf[b*ENCn + e] = f2bf(s * (1.f/196.f));
  }
}

__global__ void k_emb_all(const int* __restrict__ caps_s, const float* __restrict__ emb_w,
                          unsigned short* __restrict__ xh_all)
{
  int id = blockIdx.x; int t = id >> 7, b = id & 127;
  int tok = caps_s[b*Ln + t];
  const float* src = emb_w + (size_t)tok*EDn;
  unsigned short* d = xh_all + ((size_t)t*Bn + b)*3072;
  int i = threadIdx.x*2;
  float2 v = *(const float2*)(src+i);
  d[i] = f2bf(v.x); d[i+1] = f2bf(v.y);
}

__global__ void k_h2bf(const float* __restrict__ hc, float* __restrict__ c,
                       unsigned short* __restrict__ h_bf, unsigned short* __restrict__ xh_all)
{
  int b = blockIdx.x, d = threadIdx.x;
  float hv = hc[b*1024 + d];
  float cv = hc[b*1024 + 512 + d];
  c[b*Dn + d] = cv;
  unsigned short hb = f2bf(hv);
  h_bf[b*Dn + d] = hb;
  xh_all[(size_t)b*3072 + 2560 + d] = hb;
}

// ---------------- bf16 MFMA GEMM 64x64, BK=128: C = A @ B^T (+bias) ----------------
// grid (N/64, M/64); actlen tile-skip. 4 K-phases at K=512 (vs 8 at BK=64).
__global__ __launch_bounds__(256) void k_mfma_gemm(
    const unsigned short* __restrict__ Aw, const unsigned short* __restrict__ Bw,
    const float* __restrict__ bias, float* __restrict__ Cp,
    int N, int K, size_t ldc,
    const int* __restrict__ actlen, int t)
{
  __shared__ unsigned short smA[2][8192];   // 64 rows x 128 k
  __shared__ unsigned short smB[2][8192];
  const int tid = threadIdx.x;
  const int bm0 = blockIdx.y*64, bn0 = blockIdx.x*64;
  if (actlen && actlen[bm0] <= t) return;

  const int lane = tid & 63, w = tid >> 6;
  const int wr = w >> 1, wc = w & 1;
  const int lrow = lane & 15, kq = lane >> 4;

  v4f acc[2][2];
  #pragma unroll
  for (int i=0;i<2;++i)
    #pragma unroll
    for (int j=0;j<2;++j) acc[i][j] = (v4f)0.f;

  const int nt = K >> 7;

  auto stage = [&](int buf, int k0) {
    #pragma unroll
    for (int it = 0; it < 4; ++it) {
      int s = it*256 + tid;            // (row, kbl): row = s>>4, kbl = s&15
      int row = s >> 4;
      int kbs = (s & 15) ^ (row & 7);  // swizzled source k-block
      *(v8s*)&smA[buf][s*8] = *(const v8s*)(Aw + (size_t)(bm0+row)*K + k0 + kbs*8);
      *(v8s*)&smB[buf][s*8] = *(const v8s*)(Bw + (size_t)(bn0+row)*K + k0 + kbs*8);
    }
  };
  auto compute = [&](int buf) {
    #pragma unroll
    for (int kc = 0; kc < 4; ++kc) {
      v8s aF[2], bF[2];
      #pragma unroll
      for (int mi = 0; mi < 2; ++mi) {
        int row = wr*32 + mi*16 + lrow;
        int kb = kc*4 + kq;
        aF[mi] = *(const v8s*)&smA[buf][row*128 + ((kb ^ (row&7))<<3)];
      }
      #pragma unroll
      for (int ni = 0; ni < 2; ++ni) {
        int row = wc*32 + ni*16 + lrow;
        int kb = kc*4 + kq;
        bF[ni] = *(const v8s*)&smB[buf][row*128 + ((kb ^ (row&7))<<3)];
      }
      #pragma unroll
      for (int mi = 0; mi < 2; ++mi)
        #pragma unroll
        for (int ni = 0; ni < 2; ++ni)
          acc[mi][ni] = __builtin_amdgcn_mfma_f32_16x16x32_bf16(aF[mi], bF[ni], acc[mi][ni], 0, 0, 0);
    }
  };

  stage(0, 0);
  __syncthreads();
  for (int tk = 0; tk < nt; ++tk) {
    if (tk + 1 < nt) stage((tk+1)&1, (tk+1)<<7);
    compute(tk&1);
    __syncthreads();
  }

  #pragma unroll
  for (int mi=0; mi<2; ++mi)
    #pragma unroll
    for (int ni=0; ni<2; ++ni)
      #pragma unroll
      for (int r=0; r<4; ++r) {
        int m = bm0 + wr*32 + mi*16 + kq*4 + r;
        int n = bn0 + wc*32 + ni*16 + lrow;
        Cp[(size_t)m*ldc + n] = acc[mi][ni][r] + bias[n];
      }
}

// ---------------- att1 GEMM: 128x64 tile, XCD-contiguous (BK=64) ----------------
__global__ __launch_bounds__(256) void k_att1(
    const unsigned short* __restrict__ Aw, const unsigned short* __restrict__ Bw,
    const float* __restrict__ bias, unsigned short* __restrict__ Cp)
{
  __shared__ unsigned short smA[2][8192];
  __shared__ unsigned short smB[2][4096];
  const int tid = threadIdx.x;
  const int id = blockIdx.x;
  const int g = (id & 7)*196 + (id >> 3);   // XCD-contiguous panel walk
  const int bm0 = (g >> 3) * 128, bn0 = (g & 7) * 64;
  const int K = ENCn;

  const int lane = tid & 63, w = tid >> 6;
  const int wr = w >> 1, wc = w & 1;
  const int lrow = lane & 15, kq = lane >> 4;

  v4f acc[4][2];
  #pragma unroll
  for (int i=0;i<4;++i)
    #pragma unroll
    for (int j=0;j<2;++j) acc[i][j] = (v4f)0.f;

  auto stage = [&](int buf, int k0) {
    #pragma unroll
    for (int it = 0; it < 4; ++it) {
      int s = it*256 + tid;
      int row = s >> 3;
      int kb  = (s & 7) ^ (row & 7);
      *(v8s*)&smA[buf][s*8] = *(const v8s*)(Aw + (size_t)(bm0+row)*K + k0 + kb*8);
    }
    #pragma unroll
    for (int it = 0; it < 2; ++it) {
      int s = it*256 + tid;
      int row = s >> 3;
      int kb  = (s & 7) ^ (row & 7);
      *(v8s*)&smB[buf][s*8] = *(const v8s*)(Bw + (size_t)(bn0+row)*K + k0 + kb*8);
    }
  };
  auto compute = [&](int buf) {
    #pragma unroll
    for (int kc = 0; kc < 2; ++kc) {
      v8s aF[4], bF[2];
      #pragma unroll
      for (int mi = 0; mi < 4; ++mi) {
        int row = wr*64 + mi*16 + lrow;
        int kb = kc*4 + kq;
        aF[mi] = *(const v8s*)&smA[buf][row*64 + ((kb ^ (row&7))<<3)];
      }
      #pragma unroll
      for (int ni = 0; ni < 2; ++ni) {
        int row = wc*32 + ni*16 + lrow;
        int kb = kc*4 + kq;
        bF[ni] = *(const v8s*)&smB[buf][row*64 + ((kb ^ (row&7))<<3)];
      }
      #pragma unroll
      for (int mi = 0; mi < 4; ++mi)
        #pragma unroll
        for (int ni = 0; ni < 2; ++ni)
          acc[mi][ni] = __builtin_amdgcn_mfma_f32_16x16x32_bf16(aF[mi], bF[ni], acc[mi][ni], 0, 0, 0);
    }
  };

  stage(0, 0);
  __syncthreads();
  const int nt = K >> 6;
  for (int tk = 0; tk < nt; ++tk) {
    if (tk + 1 < nt) stage((tk+1)&1, (tk+1)<<6);
    compute(tk&1);
    __syncthreads();
  }

  #pragma unroll
  for (int mi=0; mi<4; ++mi)
    #pragma unroll
    for (int ni=0; ni<2; ++ni)
      #pragma unroll
      for (int r=0; r<4; ++r) {
        int m = bm0 + wr*64 + mi*16 + kq*4 + r;
        int n = bn0 + wc*32 + ni*16 + lrow;
        Cp[(size_t)m*An + n] = f2bf(acc[mi][ni][r] + bias[n]);
      }
}

// ---------------- gates GEMM (BK=128) + LSTM epilogue ----------------
__global__ __launch_bounds__(256) void k_gates_lstm(
    const unsigned short* __restrict__ Aw, const unsigned short* __restrict__ Bw,
    const float* __restrict__ bias,
    float* __restrict__ c, unsigned short* __restrict__ h_bf,
    unsigned short* __restrict__ h_all, unsigned short* __restrict__ xh_all,
    const int* __restrict__ declen_i, int t)
{
  __shared__ __align__(16) char smraw[65536];
  unsigned short (*smA)[8192] = (unsigned short(*)[8192])smraw;            // 32KB
  unsigned short (*smB)[8192] = (unsigned short(*)[8192])(smraw + 32768);  // 32KB
  float (*smC)[65] = (float(*)[65])smraw;  // aliases smA after K-loop
  const int tid = threadIdx.x;
  const int bm0 = blockIdx.y*64, bn0 = blockIdx.x*64;
  if (declen_i[bm0] <= t) return;

  const int lane = tid & 63, w = tid >> 6;
  const int wr = w >> 1, wc = w & 1;
  const int lrow = lane & 15, kq = lane >> 4;
  const int K = 3072;

  v4f acc[2][2];
  #pragma unroll
  for (int i=0;i<2;++i)
    #pragma unroll
    for (int j=0;j<2;++j) acc[i][j] = (v4f)0.f;

  auto stage = [&](int buf, int k0) {
    #pragma unroll
    for (int it = 0; it < 4; ++it) {
      int s = it*256 + tid;
      int row = s >> 4;
      int kbs = (s & 15) ^ (row & 7);
      *(v8s*)&smA[buf][s*8] = *(const v8s*)(Aw + (size_t)(bm0+row)*K + k0 + kbs*8);
      *(v8s*)&smB[buf][s*8] = *(const v8s*)(Bw + (size_t)(bn0+row)*K + k0 + kbs*8);
    }
  };
  auto compute = [&](int buf) {
    #pragma unroll
    for (int kc = 0; kc < 4; ++kc) {
      v8s aF[2], bF[2];
      #pragma unroll
      for (int mi = 0; mi < 2; ++mi) {
        int row = wr*32 + mi*16 + lrow;
        int kb = kc*4 + kq;
        aF[mi] = *(const v8s*)&smA[buf][row*128 + ((kb ^ (row&7))<<3)];
      }
      #pragma unroll
      for (int ni = 0; ni < 2; ++ni) {
        int row = wc*32 + ni*16 + lrow;
        int kb = kc*4 + kq;
        bF[ni] = *(const v8s*)&smB[buf][row*128 + ((kb ^ (row&7))<<3)];
      }
      #pragma unroll
      for (int mi = 0; mi < 2; ++mi)
        #pragma unroll
        for (int ni = 0; ni < 2; ++ni)
          acc[mi][ni] = __builtin_amdgcn_mfma_f32_16x16x32_bf16(aF[mi], bF[ni], acc[mi][ni], 0, 0, 0);
    }
  };

  stage(0, 0);
  __syncthreads();
  const int nt = K >> 7;   // 24
  for (int tk = 0; tk < nt; ++tk) {
    if (tk + 1 < nt) stage((tk+1)&1, (tk+1)<<7);
    compute(tk&1);
    __syncthreads();
  }
  // loop ends with barrier: safe to overwrite smA region with smC

  #pragma unroll
  for (int mi=0; mi<2; ++mi)
    #pragma unroll
    for (int ni=0; ni<2; ++ni)
      #pragma unroll
      for (int r=0; r<4; ++r) {
        int ml = wr*32 + mi*16 + kq*4 + r;
        int nl = wc*32 + ni*16 + lrow;
        smC[ml][nl] = acc[mi][ni][r] + bias[bn0 + nl];
      }
  __syncthreads();

  for (int idx = tid; idx < 1024; idx += 256) {
    int ml = idx >> 4, dl = idx & 15;
    int b = bm0 + ml;
    if (t < declen_i[b]) {
      int dg = (bn0 >> 2) + dl;
      float gi = smC[ml][dl*4+0];
      float gf = smC[ml][dl*4+1];
      float gg = smC[ml][dl*4+2];
      float go = smC[ml][dl*4+3];
      float cv = c[b*Dn + dg];
      float cn = sigf(gf)*cv + sigf(gi)*tanhf(gg);
      float hn = sigf(go)*tanhf(cn);
      c[b*Dn + dg] = cn;
      unsigned short hb = f2bf(hn);
      h_bf[b*Dn + dg] = hb;
      h_all[((size_t)t*Bn + b)*Dn + dg] = hb;
      if (t + 1 < Tn)
        xh_all[((size_t)(t+1)*Bn + b)*3072 + 2560 + dg] = hb;
    }
  }
}

// ---------------- batched pred GEMM (all t, 64x64 tiles with inactive-tile skip) ----------------
__global__ __launch_bounds__(256) void k_pred(
    const unsigned short* __restrict__ Aw, const unsigned short* __restrict__ Bw,
    const float* __restrict__ bias, float* __restrict__ out_pred,
    const int* __restrict__ declen_i)
{
  __shared__ unsigned short smA[2][4096];
  __shared__ unsigned short smB[2][4096];
  const int tid = threadIdx.x;
  const int bm0 = blockIdx.y*64, bn0 = blockIdx.x*64;
  const int t0 = bm0 >> 7, b0 = bm0 & 127;

  if (declen_i[b0] <= t0) {
    for (int i = tid; i < 4096; i += 256) {
      int ml = i >> 6, nl = i & 63;
      int n = bn0 + nl;
      if (n < Vn) {
        int m = bm0 + ml;
        out_pred[((size_t)(m & 127)*Tn + (m >> 7))*Vn + n] = 0.f;
      }
    }
    return;
  }

  const int lane = tid & 63, w = tid >> 6;
  const int wr = w >> 1, wc = w & 1;
  const int lrow = lane & 15, kq = lane >> 4;
  const int K = 512;

  v4f acc[2][2];
  #pragma unroll
  for (int i=0;i<2;++i)
    #pragma unroll
    for (int j=0;j<2;++j) acc[i][j] = (v4f)0.f;

  auto stage = [&](int buf, int k0) {
    #pragma unroll
    for (int it = 0; it < 2; ++it) {
      int s = it*256 + tid;
      int row = s >> 3;
      int kb  = (s & 7) ^ (row & 7);
      *(v8s*)&smA[buf][s*8] = *(const v8s*)(Aw + (size_t)(bm0+row)*K + k0 + kb*8);
      {
        int gn = bn0 + row; if (gn >= Vn) gn = Vn-1;
        *(v8s*)&smB[buf][s*8] = *(const v8s*)(Bw + (size_t)gn*K + k0 + kb*8);
      }
    }
  };
  auto compute = [&](int buf) {
    #pragma unroll
    for (int kc = 0; kc < 2; ++kc) {
      v8s aF[2], bF[2];
      #pragma unroll
      for (int mi = 0; mi < 2; ++mi) {
        int row = wr*32 + mi*16 + lrow;
        int kb = kc*4 + kq;
        aF[mi] = *(const v8s*)&smA[buf][row*64 + ((kb ^ (row&7))<<3)];
      }
      #pragma unroll
      for (int ni = 0; ni < 2; ++ni) {
        int row = wc*32 + ni*16 + lrow;
        int kb = kc*4 + kq;
        bF[ni] = *(const v8s*)&smB[buf][row*64 + ((kb ^ (row&7))<<3)];
      }
      #pragma unroll
      for (int mi = 0; mi < 2; ++mi)
        #pragma unroll
        for (int ni = 0; ni < 2; ++ni)
          acc[mi][ni] = __builtin_amdgcn_mfma_f32_16x16x32_bf16(aF[mi], bF[ni], acc[mi][ni], 0, 0, 0);
    }
  };

  stage(0, 0);
  __syncthreads();
  const int nt = K >> 6;
  for (int tk = 0; tk < nt; ++tk) {
    if (tk + 1 < nt) stage((tk+1)&1, (tk+1)<<6);
    compute(tk&1);
    __syncthreads();
  }

  #pragma unroll
  for (int mi=0; mi<2; ++mi)
    #pragma unroll
    for (int ni=0; ni<2; ++ni)
      #pragma unroll
      for (int r=0; r<4; ++r) {
        int m = bm0 + wr*32 + mi*16 + kq*4 + r;
        int n = bn0 + wc*32 + ni*16 + lrow;
        if (n < Vn) {
          int b = m & 127, tt = m >> 7;
          float v = (tt < declen_i[b]) ? (acc[mi][ni][r] + bias[n]) : 0.f;
          out_pred[((size_t)b*Tn + tt)*Vn + n] = v;
        }
      }
}

// ---------------- e-dot + softmax (thread-per-p) ----------------
__global__ __launch_bounds__(256) void k_esm(
    const unsigned short* __restrict__ att1, const float* __restrict__ att2g,
    const float* __restrict__ fa_w, const float* __restrict__ fa_b,
    float* __restrict__ alpha, float* __restrict__ out_alph,
    const int* __restrict__ declen_i, int t)
{
  int b = blockIdx.x;
  int tid = threadIdx.x;
  if (t >= declen_i[b]) {
    if (tid < Pn)
      out_alph[(size_t)b*Tn*Pn + (size_t)t*Pn + tid] = 0.f;
    return;
  }
  __shared__ float a2s[An];
  __shared__ float fws[An];
  __shared__ float es[Pn];
  __shared__ float wred[4];
  __shared__ float wsum[4];
  for (int i = tid; i < An; i += 256) { a2s[i] = att2g[(size_t)b*2560 + i]; fws[i] = fa_w[i]; }
  __syncthreads();
  int lane = tid & 63, w = tid >> 6;
  if (tid < Pn) {
    const unsigned short* row = att1 + ((size_t)b*Pn + tid)*An;
    float s = 0.f;
    #pragma unroll 4
    for (int kb = 0; kb < 64; ++kb) {
      const v8s vv = *(const v8s*)(row + kb*8);
      #pragma unroll
      for (int j = 0; j < 8; ++j) {
        int a = kb*8 + j;
        float v = bf2f((unsigned short)vv[j]) + a2s[a];
        s += fmaxf(v, 0.f) * fws[a];
      }
    }
    es[tid] = s + fa_b[0];
  }
  __syncthreads();
  float m = -1e30f;
  for (int p = tid; p < Pn; p += 256) m = fmaxf(m, es[p]);
  for (int off = 32; off; off >>= 1) m = fmaxf(m, __shfl_down(m, off));
  if (lane == 0) wred[w] = m;
  __syncthreads();
  m = fmaxf(fmaxf(wred[0], wred[1]), fmaxf(wred[2], wred[3]));
  float s = 0.f;
  for (int p = tid; p < Pn; p += 256) { float ev = __expf(es[p] - m); es[p] = ev; s += ev; }
  for (int off = 32; off; off >>= 1) s += __shfl_down(s, off);
  if (lane == 0) wsum[w] = s;
  __syncthreads();
  s = wsum[0] + wsum[1] + wsum[2] + wsum[3];
  float inv = 1.f / s;
  for (int p = tid; p < Pn; p += 256) {
    float al = es[p] * inv;
    alpha[b*Pn + p] = al;
    out_alph[(size_t)b*Tn*Pn + (size_t)t*Pn + p] = al;
  }
}

// ---------------- awe + gate ----------------
// grid (8, 128): block (ei, b) handles 256-e slice.
__global__ __launch_bounds__(256) void k_awe_gate(
    const unsigned short* __restrict__ enc_bf,
    const float* __restrict__ alpha, const float* __restrict__ att2g,
    unsigned short* __restrict__ xh_t, const int* __restrict__ declen_i, int t)
{
  int b = blockIdx.y;
  if (t >= declen_i[b]) return;
  __shared__ float als[Pn];
  __shared__ float red[8][256];
  int tid = threadIdx.x;
  if (tid < Pn) als[tid] = alpha[b*Pn + tid];
  __syncthreads();
  int e0 = blockIdx.x*256;
  int ec = tid & 31, ps = tid >> 5;
  const unsigned short* eb = enc_bf + (size_t)b*Pn*ENCn + e0 + ec*8;
  float s[8] = {};
  for (int p = ps; p < Pn; p += 8) {
    v8s v = *(const v8s*)(eb + (size_t)p*ENCn);
    float a = als[p];
    #pragma unroll
    for (int j = 0; j < 8; ++j) s[j] += a * bf2f((unsigned short)v[j]);
  }
  #pragma unroll
  for (int j = 0; j < 8; ++j) red[ps][ec*8+j] = s[j];
  __syncthreads();
  {
    int e = tid;
    float tsum = 0.f;
    #pragma unroll
    for (int k = 0; k < 8; ++k) tsum += red[k][e];
    int eg = e0 + e;
    float g = sigf(att2g[(size_t)b*2560 + 512 + eg]);
    xh_t[(size_t)b*3072 + 512 + eg] = f2bf(g*tsum);
  }
}

// ---------------- launch ----------------

extern "C" void kernel_launch(void* const* d_in, const int* in_sizes, int n_in,
                              void* d_out, int out_size, void* d_ws, size_t ws_size,
                              hipStream_t stream)
{
  const float* enc     = (const float*)d_in[0];
  const int*   captions= (const int*)d_in[1];
  const int*   cap_len = (const int*)d_in[2];
  const float* emb_w   = (const float*)d_in[3];
  const float* Wih     = (const float*)d_in[4];
  const float* Whh     = (const float*)d_in[5];
  const float* bih     = (const float*)d_in[6];
  const float* bhh     = (const float*)d_in[7];
  const float* h0_w    = (const float*)d_in[8];
  const float* h0_b    = (const float*)d_in[9];
  const float* c0_w    = (const float*)d_in[10];
  const float* c0_b    = (const float*)d_in[11];
  const float* gate_w  = (const float*)d_in[12];
  const float* gate_b  = (const float*)d_in[13];
  const float* lin_w   = (const float*)d_in[14];
  const float* lin_b   = (const float*)d_in[15];
  const float* ea_w    = (const float*)d_in[16];
  const float* ea_b    = (const float*)d_in[17];
  const float* da_w    = (const float*)d_in[18];
  const float* da_b    = (const float*)d_in[19];
  const float* fa_w    = (const float*)d_in[20];
  const float* fa_b    = (const float*)d_in[21];

  float* out = (float*)d_out;
  float* out_pred   = out;                               // [128][19][10000]
  float* out_caps   = out + (size_t)Bn*Tn*Vn;            // [128][20]
  float* out_declen = out_caps + Bn*Ln;                  // [128]
  float* out_alph   = out_declen + Bn;                   // [128][19][196]
  float* out_order  = out_alph + (size_t)Bn*Tn*Pn;       // [128]

  char* wp = (char*)d_ws;
  auto alloc = [&](size_t bytes)->void* {
    void* p = (void*)wp; wp += (bytes + 255) & ~(size_t)255; return p;
  };
  int*   order_i  = (int*)alloc(Bn*4);
  int*   declen_i = (int*)alloc(Bn*4);
  int*   caps_s   = (int*)alloc(Bn*Ln*4);
  unsigned short* enc_bf  = (unsigned short*)alloc((size_t)Bn*Pn*ENCn*2);  // 102.8 MB
  unsigned short* mean_bf = (unsigned short*)alloc((size_t)Bn*ENCn*2);
  float* hc       = (float*)alloc((size_t)Bn*1024*4);
  float* c        = (float*)alloc((size_t)Bn*Dn*4);
  unsigned short* h_bf   = (unsigned short*)alloc((size_t)Bn*Dn*2);
  unsigned short* h_all  = (unsigned short*)alloc((size_t)Tn*Bn*Dn*2);     // 2.5 MB
  unsigned short* xh_all = (unsigned short*)alloc((size_t)Tn*Bn*3072*2);   // 14.9 MB
  unsigned short* att1   = (unsigned short*)alloc((size_t)Bn*Pn*An*2);     // 25.7 MB
  float* att2g    = (float*)alloc((size_t)Bn*2560*4);
  float* alpha    = (float*)alloc((size_t)Bn*Pn*4);
  unsigned short* ea_bf   = (unsigned short*)alloc((size_t)An*ENCn*2);
  unsigned short* lin_bf  = (unsigned short*)alloc((size_t)Vn*Dn*2);
  unsigned short* h0c0_bf = (unsigned short*)alloc((size_t)1024*ENCn*2);
  unsigned short* dg_bf   = (unsigned short*)alloc((size_t)2560*Dn*2);
  unsigned short* wcat_bf = (unsigned short*)alloc((size_t)2048*3072*2);
  float* bsum = (float*)alloc(2048*4);
  float* dg_b = (float*)alloc(2560*4);
  float* hc_b = (float*)alloc(1024*4);

  // ---- setup ----
  k_order<<<1,128,0,stream>>>(cap_len, captions, order_i, declen_i, caps_s,
                              out_caps, out_declen, out_order);
  k_setup_bias<<<10,256,0,stream>>>(bih, bhh, da_b, gate_b, h0_b, c0_b, bsum, dg_b, hc_b);
  k_cvt6<<<9352,256,0,stream>>>(ea_w, lin_w, h0_w, c0_w, da_w, gate_w,
                                ea_bf, lin_bf, h0c0_bf, dg_bf);
  k_wcat<<<(2048*3072/4+255)/256,256,0,stream>>>(Wih, Whh, wcat_bf);
  k_cvt_enc<<<Bn*Pn,256,0,stream>>>(enc, order_i, enc_bf);
  k_mean<<<Bn,256,0,stream>>>(enc_bf, mean_bf);
  k_emb_all<<<Tn*Bn,256,0,stream>>>(caps_s, emb_w, xh_all);

  // h0/c0 (K=2048, BK=128 -> 16 phases)
  k_mfma_gemm<<<dim3(16,2),256,0,stream>>>(
      mean_bf, h0c0_bf, hc_b, hc, 1024, ENCn, 1024, nullptr, 0);
  k_h2bf<<<Bn,512,0,stream>>>(hc, c, h_bf, xh_all);

  // att1 = enc_bf @ ea_w^T (bf16 out), 128x64 tiles, XCD-contiguous
  k_att1<<<dim3(196*8),256,0,stream>>>(enc_bf, ea_bf, ea_b, att1);

  for (int t = 0; t < Tn; ++t) {
    unsigned short* xh_t = xh_all + (size_t)t*Bn*3072;
    // att2|gpre = h @ [da_w;gate_w]^T : [128,2560], K=512 -> 4 phases
    k_mfma_gemm<<<dim3(40,2),256,0,stream>>>(
        h_bf, dg_bf, dg_b, att2g, 2560, Dn, 2560, declen_i, t);
    // e-dot + softmax (thread-per-p)
    k_esm<<<Bn,256,0,stream>>>(att1, att2g, fa_w, fa_b, alpha, out_alph, declen_i, t);
    // awe + gate (1024 blocks)
    k_awe_gate<<<dim3(8,Bn),256,0,stream>>>(enc_bf, alpha, att2g, xh_t, declen_i, t);
    // gates GEMM (BK=128, 24 phases) + LSTM epilogue
    k_gates_lstm<<<dim3(32,2),256,0,stream>>>(
        xh_t, wcat_bf, bsum, c, h_bf, h_all, xh_all, declen_i, t);
  }

  // batched pred over all t: 64x64 tiles with inactive-tile skip
  k_pred<<<dim3((Vn+63)/64, (Tn*Bn)/64),256,0,stream>>>(
      h_all, lin_bf, lin_b, out_pred, declen_i);
}

// Round 13
// 1384.209 us; speedup vs baseline: 1.3104x; 1.0622x over previous
//
#include <hip/hip_runtime.h>
#include <hip/hip_bf16.h>
#include <math.h>

#define Bn 128
#define Pn 196
#define ENCn 2048
#define Dn 512
#define An 512
#define EDn 512
#define Vn 10000
#define Ln 20
#define Tn 19

typedef short v8s __attribute__((ext_vector_type(8)));
typedef float v4f __attribute__((ext_vector_type(4)));

__device__ __forceinline__ float sigf(float x){ return 1.f/(1.f+__expf(-x)); }
__device__ __forceinline__ unsigned short f2bf(float f){
  unsigned u = __float_as_uint(f);
  return (unsigned short)((u + 0x7FFFu + ((u>>16)&1u)) >> 16);
}
__device__ __forceinline__ float bf2f(unsigned short h){
  return __uint_as_float(((unsigned)h)<<16);
}

// ---------------- setup kernels ----------------

__global__ void k_order(const int* __restrict__ caption_len,
                        const int* __restrict__ captions,
                        int* __restrict__ order_i, int* __restrict__ declen_i,
                        int* __restrict__ caps_s,
                        float* __restrict__ out_caps, float* __restrict__ out_declen,
                        float* __restrict__ out_order)
{
  __shared__ int lens[Bn];
  int b = threadIdx.x;
  lens[b] = caption_len[b];
  __syncthreads();
  int lb = lens[b];
  int r = 0;
  for (int j = 0; j < Bn; ++j) {
    int lj = lens[j];
    r += (int)((lj > lb) || (lj == lb && j < b));
  }
  order_i[r] = b;
  declen_i[r] = lb - 1;
  out_order[r] = (float)b;
  out_declen[r] = (float)(lb - 1);
  for (int t = 0; t < Ln; ++t) {
    int cv = captions[b*Ln + t];
    caps_s[r*Ln + t] = cv;
    out_caps[r*Ln + t] = (float)cv;
  }
}

// bsum reordered to (d*4+g); dg_b / hc_b plain concat
__global__ void k_setup_bias(const float* __restrict__ bih, const float* __restrict__ bhh,
                             const float* __restrict__ da_b, const float* __restrict__ gate_b,
                             const float* __restrict__ h0_b, const float* __restrict__ c0_b,
                             float* __restrict__ bsum_r, float* __restrict__ dg_b,
                             float* __restrict__ hc_b)
{
  int i = blockIdx.x*256 + threadIdx.x;
  if (i < 2048) {
    int d = i >> 2, g = i & 3;
    bsum_r[i] = bih[g*512+d] + bhh[g*512+d];
  }
  if (i < 2560) dg_b[i] = (i < 512) ? da_b[i] : gate_b[i-512];
  if (i < 1024) hc_b[i] = (i < 512) ? h0_b[i] : c0_b[i-512];
}

// merged f32->bf16 conversion of all 6 weight matrices, one dispatch
#define C_EA  (512*2048)
#define C_LIN (10000*512)
#define C_H0  (512*2048)
#define C_C0  (512*2048)
#define C_DA  (512*512)
#define C_GW  (2048*512)
#define CUM1  (C_EA)
#define CUM2  (CUM1 + C_LIN)
#define CUM3  (CUM2 + C_H0)
#define CUM4  (CUM3 + C_C0)
#define CUM5  (CUM4 + C_DA)
#define CUM6  (CUM5 + C_GW)          // 9576448 total, = 9352 blocks * 1024

__global__ void k_cvt6(const float* __restrict__ ea_w, const float* __restrict__ lin_w,
                       const float* __restrict__ h0_w, const float* __restrict__ c0_w,
                       const float* __restrict__ da_w, const float* __restrict__ gate_w,
                       unsigned short* __restrict__ ea_bf, unsigned short* __restrict__ lin_bf,
                       unsigned short* __restrict__ h0c0_bf, unsigned short* __restrict__ dg_bf)
{
  int i = (blockIdx.x*256 + threadIdx.x)*4;
  const float* src; unsigned short* dst; int off;
  if      (i < CUM1) { src = ea_w;   dst = ea_bf;                    off = i; }
  else if (i < CUM2) { src = lin_w;  dst = lin_bf;                   off = i - CUM1; }
  else if (i < CUM3) { src = h0_w;   dst = h0c0_bf;                  off = i - CUM2; }
  else if (i < CUM4) { src = c0_w;   dst = h0c0_bf + (size_t)C_H0;   off = i - CUM3; }
  else if (i < CUM5) { src = da_w;   dst = dg_bf;                    off = i - CUM4; }
  else               { src = gate_w; dst = dg_bf + (size_t)C_DA;     off = i - CUM5; }
  float4 v = *(const float4*)(src + off);
  dst[off+0]=f2bf(v.x); dst[off+1]=f2bf(v.y); dst[off+2]=f2bf(v.z); dst[off+3]=f2bf(v.w);
}

// wcat_r[d*4+g][3072] = [Wih | Whh][g*512+d][:] in bf16 (gate-interleaved rows)
__global__ void k_wcat(const float* __restrict__ Wih, const float* __restrict__ Whh,
                       unsigned short* __restrict__ dst)
{
  int i = (blockIdx.x*256 + threadIdx.x)*4;
  if (i >= 2048*3072) return;
  int rp = i/3072, j = i - rp*3072;
  int d = rp >> 2, g = rp & 3;
  int r = g*512 + d;
  const float* s = (j < 2560) ? (Wih + (size_t)r*2560 + j) : (Whh + (size_t)r*512 + (j-2560));
  float4 v = *(const float4*)s;
  dst[i+0]=f2bf(v.x); dst[i+1]=f2bf(v.y); dst[i+2]=f2bf(v.z); dst[i+3]=f2bf(v.w);
}

__global__ void k_cvt_enc(const float* __restrict__ enc, const int* __restrict__ order_i,
                          unsigned short* __restrict__ dst)
{
  int id = blockIdx.x;               // b*196+p
  int b = id / Pn, p = id - b*Pn;
  const float* src = enc + ((size_t)order_i[b]*Pn + p)*ENCn;
  unsigned short* d = dst + (size_t)id*ENCn;
  int i = threadIdx.x*8;
  float4 v0 = *(const float4*)(src+i), v1 = *(const float4*)(src+i+4);
  d[i+0]=f2bf(v0.x); d[i+1]=f2bf(v0.y); d[i+2]=f2bf(v0.z); d[i+3]=f2bf(v0.w);
  d[i+4]=f2bf(v1.x); d[i+5]=f2bf(v1.y); d[i+6]=f2bf(v1.z); d[i+7]=f2bf(v1.w);
}

__global__ void k_mean(const unsigned short* __restrict__ enc_bf,
                       unsigned short* __restrict__ mean_bf)
{
  int b = blockIdx.x;
  const unsigned short* eb = enc_bf + (size_t)b*Pn*ENCn;
  for (int e = threadIdx.x; e < ENCn; e += 256) {
    float s = 0.f;
    for (int p = 0; p < Pn; ++p) s += bf2f(eb[(size_t)p*ENCn + e]);
    mean_bf[b*ENCn + e] = f2bf(s * (1.f/196.f));
  }
}

__global__ void k_emb_all(const int* __restrict__ caps_s, const float* __restrict__ emb_w,
                          unsigned short* __restrict__ xh_all)
{
  int id = blockIdx.x; int t = id >> 7, b = id & 127;
  int tok = caps_s[b*Ln + t];
  const float* src = emb_w + (size_t)tok*EDn;
  unsigned short* d = xh_all + ((size_t)t*Bn + b)*3072;
  int i = threadIdx.x*2;
  float2 v = *(const float2*)(src+i);
  d[i] = f2bf(v.x); d[i+1] = f2bf(v.y);
}

__global__ void k_h2bf(const float* __restrict__ hc, float* __restrict__ c,
                       unsigned short* __restrict__ h_bf, unsigned short* __restrict__ xh_all)
{
  int b = blockIdx.x, d = threadIdx.x;
  float hv = hc[b*1024 + d];
  float cv = hc[b*1024 + 512 + d];
  c[b*Dn + d] = cv;
  unsigned short hb = f2bf(hv);
  h_bf[b*Dn + d] = hb;
  xh_all[(size_t)b*3072 + 2560 + d] = hb;
}

// ---------------- bf16 MFMA GEMM 64x64, BK=256: C = A @ B^T (+bias) ----------------
// grid (N/64, M/64); actlen tile-skip. K=512 -> 2 phases; K=2048 -> 8.
__global__ __launch_bounds__(256) void k_mfma_gemm(
    const unsigned short* __restrict__ Aw, const unsigned short* __restrict__ Bw,
    const float* __restrict__ bias, float* __restrict__ Cp,
    int N, int K, size_t ldc,
    const int* __restrict__ actlen, int t)
{
  __shared__ unsigned short smA[2][16384];   // 64 rows x 256 k
  __shared__ unsigned short smB[2][16384];
  const int tid = threadIdx.x;
  const int bm0 = blockIdx.y*64, bn0 = blockIdx.x*64;
  if (actlen && actlen[bm0] <= t) return;

  const int lane = tid & 63, w = tid >> 6;
  const int wr = w >> 1, wc = w & 1;
  const int lrow = lane & 15, kq = lane >> 4;

  v4f acc[2][2];
  #pragma unroll
  for (int i=0;i<2;++i)
    #pragma unroll
    for (int j=0;j<2;++j) acc[i][j] = (v4f)0.f;

  const int nt = K >> 8;

  auto stage = [&](int buf, int k0) {
    #pragma unroll
    for (int it = 0; it < 8; ++it) {
      int s = it*256 + tid;            // row = s>>5, kbl = s&31
      int row = s >> 5;
      int kbs = (s & 31) ^ (row & 7);  // swizzled source k-block
      *(v8s*)&smA[buf][s*8] = *(const v8s*)(Aw + (size_t)(bm0+row)*K + k0 + kbs*8);
      *(v8s*)&smB[buf][s*8] = *(const v8s*)(Bw + (size_t)(bn0+row)*K + k0 + kbs*8);
    }
  };
  auto compute = [&](int buf) {
    #pragma unroll
    for (int kc = 0; kc < 8; ++kc) {
      v8s aF[2], bF[2];
      #pragma unroll
      for (int mi = 0; mi < 2; ++mi) {
        int row = wr*32 + mi*16 + lrow;
        int kb = kc*4 + kq;
        aF[mi] = *(const v8s*)&smA[buf][row*256 + ((kb ^ (row&7))<<3)];
      }
      #pragma unroll
      for (int ni = 0; ni < 2; ++ni) {
        int row = wc*32 + ni*16 + lrow;
        int kb = kc*4 + kq;
        bF[ni] = *(const v8s*)&smB[buf][row*256 + ((kb ^ (row&7))<<3)];
      }
      #pragma unroll
      for (int mi = 0; mi < 2; ++mi)
        #pragma unroll
        for (int ni = 0; ni < 2; ++ni)
          acc[mi][ni] = __builtin_amdgcn_mfma_f32_16x16x32_bf16(aF[mi], bF[ni], acc[mi][ni], 0, 0, 0);
    }
  };

  stage(0, 0);
  __syncthreads();
  for (int tk = 0; tk < nt; ++tk) {
    if (tk + 1 < nt) stage((tk+1)&1, (tk+1)<<8);
    compute(tk&1);
    __syncthreads();
  }

  #pragma unroll
  for (int mi=0; mi<2; ++mi)
    #pragma unroll
    for (int ni=0; ni<2; ++ni)
      #pragma unroll
      for (int r=0; r<4; ++r) {
        int m = bm0 + wr*32 + mi*16 + kq*4 + r;
        int n = bn0 + wc*32 + ni*16 + lrow;
        Cp[(size_t)m*ldc + n] = acc[mi][ni][r] + bias[n];
      }
}

// ---------------- att1 GEMM: 128x64 tile, XCD-contiguous (BK=64) ----------------
__global__ __launch_bounds__(256) void k_att1(
    const unsigned short* __restrict__ Aw, const unsigned short* __restrict__ Bw,
    const float* __restrict__ bias, unsigned short* __restrict__ Cp)
{
  __shared__ unsigned short smA[2][8192];
  __shared__ unsigned short smB[2][4096];
  const int tid = threadIdx.x;
  const int id = blockIdx.x;
  const int g = (id & 7)*196 + (id >> 3);   // XCD-contiguous panel walk
  const int bm0 = (g >> 3) * 128, bn0 = (g & 7) * 64;
  const int K = ENCn;

  const int lane = tid & 63, w = tid >> 6;
  const int wr = w >> 1, wc = w & 1;
  const int lrow = lane & 15, kq = lane >> 4;

  v4f acc[4][2];
  #pragma unroll
  for (int i=0;i<4;++i)
    #pragma unroll
    for (int j=0;j<2;++j) acc[i][j] = (v4f)0.f;

  auto stage = [&](int buf, int k0) {
    #pragma unroll
    for (int it = 0; it < 4; ++it) {
      int s = it*256 + tid;
      int row = s >> 3;
      int kb  = (s & 7) ^ (row & 7);
      *(v8s*)&smA[buf][s*8] = *(const v8s*)(Aw + (size_t)(bm0+row)*K + k0 + kb*8);
    }
    #pragma unroll
    for (int it = 0; it < 2; ++it) {
      int s = it*256 + tid;
      int row = s >> 3;
      int kb  = (s & 7) ^ (row & 7);
      *(v8s*)&smB[buf][s*8] = *(const v8s*)(Bw + (size_t)(bn0+row)*K + k0 + kb*8);
    }
  };
  auto compute = [&](int buf) {
    #pragma unroll
    for (int kc = 0; kc < 2; ++kc) {
      v8s aF[4], bF[2];
      #pragma unroll
      for (int mi = 0; mi < 4; ++mi) {
        int row = wr*64 + mi*16 + lrow;
        int kb = kc*4 + kq;
        aF[mi] = *(const v8s*)&smA[buf][row*64 + ((kb ^ (row&7))<<3)];
      }
      #pragma unroll
      for (int ni = 0; ni < 2; ++ni) {
        int row = wc*32 + ni*16 + lrow;
        int kb = kc*4 + kq;
        bF[ni] = *(const v8s*)&smB[buf][row*64 + ((kb ^ (row&7))<<3)];
      }
      #pragma unroll
      for (int mi = 0; mi < 4; ++mi)
        #pragma unroll
        for (int ni = 0; ni < 2; ++ni)
          acc[mi][ni] = __builtin_amdgcn_mfma_f32_16x16x32_bf16(aF[mi], bF[ni], acc[mi][ni], 0, 0, 0);
    }
  };

  stage(0, 0);
  __syncthreads();
  const int nt = K >> 6;
  for (int tk = 0; tk < nt; ++tk) {
    if (tk + 1 < nt) stage((tk+1)&1, (tk+1)<<6);
    compute(tk&1);
    __syncthreads();
  }

  #pragma unroll
  for (int mi=0; mi<4; ++mi)
    #pragma unroll
    for (int ni=0; ni<2; ++ni)
      #pragma unroll
      for (int r=0; r<4; ++r) {
        int m = bm0 + wr*64 + mi*16 + kq*4 + r;
        int n = bn0 + wc*32 + ni*16 + lrow;
        Cp[(size_t)m*An + n] = f2bf(acc[mi][ni][r] + bias[n]);
      }
}

// ---------------- gates GEMM (BK=256) + LSTM epilogue ----------------
__global__ __launch_bounds__(256) void k_gates_lstm(
    const unsigned short* __restrict__ Aw, const unsigned short* __restrict__ Bw,
    const float* __restrict__ bias,
    float* __restrict__ c, unsigned short* __restrict__ h_bf,
    unsigned short* __restrict__ h_all, unsigned short* __restrict__ xh_all,
    const int* __restrict__ declen_i, int t)
{
  __shared__ __align__(16) char smraw[131072];
  unsigned short (*smA)[16384] = (unsigned short(*)[16384])smraw;            // 64KB
  unsigned short (*smB)[16384] = (unsigned short(*)[16384])(smraw + 65536);  // 64KB
  float (*smC)[65] = (float(*)[65])smraw;  // aliases smA after K-loop
  const int tid = threadIdx.x;
  const int bm0 = blockIdx.y*64, bn0 = blockIdx.x*64;
  if (declen_i[bm0] <= t) return;

  const int lane = tid & 63, w = tid >> 6;
  const int wr = w >> 1, wc = w & 1;
  const int lrow = lane & 15, kq = lane >> 4;
  const int K = 3072;

  v4f acc[2][2];
  #pragma unroll
  for (int i=0;i<2;++i)
    #pragma unroll
    for (int j=0;j<2;++j) acc[i][j] = (v4f)0.f;

  auto stage = [&](int buf, int k0) {
    #pragma unroll
    for (int it = 0; it < 8; ++it) {
      int s = it*256 + tid;
      int row = s >> 5;
      int kbs = (s & 31) ^ (row & 7);
      *(v8s*)&smA[buf][s*8] = *(const v8s*)(Aw + (size_t)(bm0+row)*K + k0 + kbs*8);
      *(v8s*)&smB[buf][s*8] = *(const v8s*)(Bw + (size_t)(bn0+row)*K + k0 + kbs*8);
    }
  };
  auto compute = [&](int buf) {
    #pragma unroll
    for (int kc = 0; kc < 8; ++kc) {
      v8s aF[2], bF[2];
      #pragma unroll
      for (int mi = 0; mi < 2; ++mi) {
        int row = wr*32 + mi*16 + lrow;
        int kb = kc*4 + kq;
        aF[mi] = *(const v8s*)&smA[buf][row*256 + ((kb ^ (row&7))<<3)];
      }
      #pragma unroll
      for (int ni = 0; ni < 2; ++ni) {
        int row = wc*32 + ni*16 + lrow;
        int kb = kc*4 + kq;
        bF[ni] = *(const v8s*)&smB[buf][row*256 + ((kb ^ (row&7))<<3)];
      }
      #pragma unroll
      for (int mi = 0; mi < 2; ++mi)
        #pragma unroll
        for (int ni = 0; ni < 2; ++ni)
          acc[mi][ni] = __builtin_amdgcn_mfma_f32_16x16x32_bf16(aF[mi], bF[ni], acc[mi][ni], 0, 0, 0);
    }
  };

  stage(0, 0);
  __syncthreads();
  const int nt = K >> 8;   // 12
  for (int tk = 0; tk < nt; ++tk) {
    if (tk + 1 < nt) stage((tk+1)&1, (tk+1)<<8);
    compute(tk&1);
    __syncthreads();
  }
  // loop ends with barrier: safe to overwrite smA region with smC

  #pragma unroll
  for (int mi=0; mi<2; ++mi)
    #pragma unroll
    for (int ni=0; ni<2; ++ni)
      #pragma unroll
      for (int r=0; r<4; ++r) {
        int ml = wr*32 + mi*16 + kq*4 + r;
        int nl = wc*32 + ni*16 + lrow;
        smC[ml][nl] = acc[mi][ni][r] + bias[bn0 + nl];
      }
  __syncthreads();

  for (int idx = tid; idx < 1024; idx += 256) {
    int ml = idx >> 4, dl = idx & 15;
    int b = bm0 + ml;
    if (t < declen_i[b]) {
      int dg = (bn0 >> 2) + dl;
      float gi = smC[ml][dl*4+0];
      float gf = smC[ml][dl*4+1];
      float gg = smC[ml][dl*4+2];
      float go = smC[ml][dl*4+3];
      float cv = c[b*Dn + dg];
      float cn = sigf(gf)*cv + sigf(gi)*tanhf(gg);
      float hn = sigf(go)*tanhf(cn);
      c[b*Dn + dg] = cn;
      unsigned short hb = f2bf(hn);
      h_bf[b*Dn + dg] = hb;
      h_all[((size_t)t*Bn + b)*Dn + dg] = hb;
      if (t + 1 < Tn)
        xh_all[((size_t)(t+1)*Bn + b)*3072 + 2560 + dg] = hb;
    }
  }
}

// ---------------- batched pred GEMM (all t, 64x64 tiles with inactive-tile skip) ----------------
__global__ __launch_bounds__(256) void k_pred(
    const unsigned short* __restrict__ Aw, const unsigned short* __restrict__ Bw,
    const float* __restrict__ bias, float* __restrict__ out_pred,
    const int* __restrict__ declen_i)
{
  __shared__ unsigned short smA[2][4096];
  __shared__ unsigned short smB[2][4096];
  const int tid = threadIdx.x;
  const int bm0 = blockIdx.y*64, bn0 = blockIdx.x*64;
  const int t0 = bm0 >> 7, b0 = bm0 & 127;

  if (declen_i[b0] <= t0) {
    for (int i = tid; i < 4096; i += 256) {
      int ml = i >> 6, nl = i & 63;
      int n = bn0 + nl;
      if (n < Vn) {
        int m = bm0 + ml;
        out_pred[((size_t)(m & 127)*Tn + (m >> 7))*Vn + n] = 0.f;
      }
    }
    return;
  }

  const int lane = tid & 63, w = tid >> 6;
  const int wr = w >> 1, wc = w & 1;
  const int lrow = lane & 15, kq = lane >> 4;
  const int K = 512;

  v4f acc[2][2];
  #pragma unroll
  for (int i=0;i<2;++i)
    #pragma unroll
    for (int j=0;j<2;++j) acc[i][j] = (v4f)0.f;

  auto stage = [&](int buf, int k0) {
    #pragma unroll
    for (int it = 0; it < 2; ++it) {
      int s = it*256 + tid;
      int row = s >> 3;
      int kb  = (s & 7) ^ (row & 7);
      *(v8s*)&smA[buf][s*8] = *(const v8s*)(Aw + (size_t)(bm0+row)*K + k0 + kb*8);
      {
        int gn = bn0 + row; if (gn >= Vn) gn = Vn-1;
        *(v8s*)&smB[buf][s*8] = *(const v8s*)(Bw + (size_t)gn*K + k0 + kb*8);
      }
    }
  };
  auto compute = [&](int buf) {
    #pragma unroll
    for (int kc = 0; kc < 2; ++kc) {
      v8s aF[2], bF[2];
      #pragma unroll
      for (int mi = 0; mi < 2; ++mi) {
        int row = wr*32 + mi*16 + lrow;
        int kb = kc*4 + kq;
        aF[mi] = *(const v8s*)&smA[buf][row*64 + ((kb ^ (row&7))<<3)];
      }
      #pragma unroll
      for (int ni = 0; ni < 2; ++ni) {
        int row = wc*32 + ni*16 + lrow;
        int kb = kc*4 + kq;
        bF[ni] = *(const v8s*)&smB[buf][row*64 + ((kb ^ (row&7))<<3)];
      }
      #pragma unroll
      for (int mi = 0; mi < 2; ++mi)
        #pragma unroll
        for (int ni = 0; ni < 2; ++ni)
          acc[mi][ni] = __builtin_amdgcn_mfma_f32_16x16x32_bf16(aF[mi], bF[ni], acc[mi][ni], 0, 0, 0);
    }
  };

  stage(0, 0);
  __syncthreads();
  const int nt = K >> 6;
  for (int tk = 0; tk < nt; ++tk) {
    if (tk + 1 < nt) stage((tk+1)&1, (tk+1)<<6);
    compute(tk&1);
    __syncthreads();
  }

  #pragma unroll
  for (int mi=0; mi<2; ++mi)
    #pragma unroll
    for (int ni=0; ni<2; ++ni)
      #pragma unroll
      for (int r=0; r<4; ++r) {
        int m = bm0 + wr*32 + mi*16 + kq*4 + r;
        int n = bn0 + wc*32 + ni*16 + lrow;
        if (n < Vn) {
          int b = m & 127, tt = m >> 7;
          float v = (tt < declen_i[b]) ? (acc[mi][ni][r] + bias[n]) : 0.f;
          out_pred[((size_t)b*Tn + tt)*Vn + n] = v;
        }
      }
}

// ---------------- e-dot + softmax (thread-per-p) ----------------
__global__ __launch_bounds__(256) void k_esm(
    const unsigned short* __restrict__ att1, const float* __restrict__ att2g,
    const float* __restrict__ fa_w, const float* __restrict__ fa_b,
    float* __restrict__ alpha, float* __restrict__ out_alph,
    const int* __restrict__ declen_i, int t)
{
  int b = blockIdx.x;
  int tid = threadIdx.x;
  if (t >= declen_i[b]) {
    if (tid < Pn)
      out_alph[(size_t)b*Tn*Pn + (size_t)t*Pn + tid] = 0.f;
    return;
  }
  __shared__ float a2s[An];
  __shared__ float fws[An];
  __shared__ float es[Pn];
  __shared__ float wred[4];
  __shared__ float wsum[4];
  for (int i = tid; i < An; i += 256) { a2s[i] = att2g[(size_t)b*2560 + i]; fws[i] = fa_w[i]; }
  __syncthreads();
  int lane = tid & 63, w = tid >> 6;
  if (tid < Pn) {
    const unsigned short* row = att1 + ((size_t)b*Pn + tid)*An;
    float s = 0.f;
    #pragma unroll 4
    for (int kb = 0; kb < 64; ++kb) {
      const v8s vv = *(const v8s*)(row + kb*8);
      #pragma unroll
      for (int j = 0; j < 8; ++j) {
        int a = kb*8 + j;
        float v = bf2f((unsigned short)vv[j]) + a2s[a];
        s += fmaxf(v, 0.f) * fws[a];
      }
    }
    es[tid] = s + fa_b[0];
  }
  __syncthreads();
  float m = -1e30f;
  for (int p = tid; p < Pn; p += 256) m = fmaxf(m, es[p]);
  for (int off = 32; off; off >>= 1) m = fmaxf(m, __shfl_down(m, off));
  if (lane == 0) wred[w] = m;
  __syncthreads();
  m = fmaxf(fmaxf(wred[0], wred[1]), fmaxf(wred[2], wred[3]));
  float s = 0.f;
  for (int p = tid; p < Pn; p += 256) { float ev = __expf(es[p] - m); es[p] = ev; s += ev; }
  for (int off = 32; off; off >>= 1) s += __shfl_down(s, off);
  if (lane == 0) wsum[w] = s;
  __syncthreads();
  s = wsum[0] + wsum[1] + wsum[2] + wsum[3];
  float inv = 1.f / s;
  for (int p = tid; p < Pn; p += 256) {
    float al = es[p] * inv;
    alpha[b*Pn + p] = al;
    out_alph[(size_t)b*Tn*Pn + (size_t)t*Pn + p] = al;
  }
}

// ---------------- awe + gate ----------------
// grid (8, 128): block (ei, b) handles 256-e slice.
__global__ __launch_bounds__(256) void k_awe_gate(
    const unsigned short* __restrict__ enc_bf,
    const float* __restrict__ alpha, const float* __restrict__ att2g,
    unsigned short* __restrict__ xh_t, const int* __restrict__ declen_i, int t)
{
  int b = blockIdx.y;
  if (t >= declen_i[b]) return;
  __shared__ float als[Pn];
  __shared__ float red[8][256];
  int tid = threadIdx.x;
  if (tid < Pn) als[tid] = alpha[b*Pn + tid];
  __syncthreads();
  int e0 = blockIdx.x*256;
  int ec = tid & 31, ps = tid >> 5;
  const unsigned short* eb = enc_bf + (size_t)b*Pn*ENCn + e0 + ec*8;
  float s[8] = {};
  for (int p = ps; p < Pn; p += 8) {
    v8s v = *(const v8s*)(eb + (size_t)p*ENCn);
    float a = als[p];
    #pragma unroll
    for (int j = 0; j < 8; ++j) s[j] += a * bf2f((unsigned short)v[j]);
  }
  #pragma unroll
  for (int j = 0; j < 8; ++j) red[ps][ec*8+j] = s[j];
  __syncthreads();
  {
    int e = tid;
    float tsum = 0.f;
    #pragma unroll
    for (int k = 0; k < 8; ++k) tsum += red[k][e];
    int eg = e0 + e;
    float g = sigf(att2g[(size_t)b*2560 + 512 + eg]);
    xh_t[(size_t)b*3072 + 512 + eg] = f2bf(g*tsum);
  }
}

// ---------------- launch ----------------

extern "C" void kernel_launch(void* const* d_in, const int* in_sizes, int n_in,
                              void* d_out, int out_size, void* d_ws, size_t ws_size,
                              hipStream_t stream)
{
  const float* enc     = (const float*)d_in[0];
  const int*   captions= (const int*)d_in[1];
  const int*   cap_len = (const int*)d_in[2];
  const float* emb_w   = (const float*)d_in[3];
  const float* Wih     = (const float*)d_in[4];
  const float* Whh     = (const float*)d_in[5];
  const float* bih     = (const float*)d_in[6];
  const float* bhh     = (const float*)d_in[7];
  const float* h0_w    = (const float*)d_in[8];
  const float* h0_b    = (const float*)d_in[9];
  const float* c0_w    = (const float*)d_in[10];
  const float* c0_b    = (const float*)d_in[11];
  const float* gate_w  = (const float*)d_in[12];
  const float* gate_b  = (const float*)d_in[13];
  const float* lin_w   = (const float*)d_in[14];
  const float* lin_b   = (const float*)d_in[15];
  const float* ea_w    = (const float*)d_in[16];
  const float* ea_b    = (const float*)d_in[17];
  const float* da_w    = (const float*)d_in[18];
  const float* da_b    = (const float*)d_in[19];
  const float* fa_w    = (const float*)d_in[20];
  const float* fa_b    = (const float*)d_in[21];

  float* out = (float*)d_out;
  float* out_pred   = out;                               // [128][19][10000]
  float* out_caps   = out + (size_t)Bn*Tn*Vn;            // [128][20]
  float* out_declen = out_caps + Bn*Ln;                  // [128]
  float* out_alph   = out_declen + Bn;                   // [128][19][196]
  float* out_order  = out_alph + (size_t)Bn*Tn*Pn;       // [128]

  char* wp = (char*)d_ws;
  auto alloc = [&](size_t bytes)->void* {
    void* p = (void*)wp; wp += (bytes + 255) & ~(size_t)255; return p;
  };
  int*   order_i  = (int*)alloc(Bn*4);
  int*   declen_i = (int*)alloc(Bn*4);
  int*   caps_s   = (int*)alloc(Bn*Ln*4);
  unsigned short* enc_bf  = (unsigned short*)alloc((size_t)Bn*Pn*ENCn*2);  // 102.8 MB
  unsigned short* mean_bf = (unsigned short*)alloc((size_t)Bn*ENCn*2);
  float* hc       = (float*)alloc((size_t)Bn*1024*4);
  float* c        = (float*)alloc((size_t)Bn*Dn*4);
  unsigned short* h_bf   = (unsigned short*)alloc((size_t)Bn*Dn*2);
  unsigned short* h_all  = (unsigned short*)alloc((size_t)Tn*Bn*Dn*2);     // 2.5 MB
  unsigned short* xh_all = (unsigned short*)alloc((size_t)Tn*Bn*3072*2);   // 14.9 MB
  unsigned short* att1   = (unsigned short*)alloc((size_t)Bn*Pn*An*2);     // 25.7 MB
  float* att2g    = (float*)alloc((size_t)Bn*2560*4);
  float* alpha    = (float*)alloc((size_t)Bn*Pn*4);
  unsigned short* ea_bf   = (unsigned short*)alloc((size_t)An*ENCn*2);
  unsigned short* lin_bf  = (unsigned short*)alloc((size_t)Vn*Dn*2);
  unsigned short* h0c0_bf = (unsigned short*)alloc((size_t)1024*ENCn*2);
  unsigned short* dg_bf   = (unsigned short*)alloc((size_t)2560*Dn*2);
  unsigned short* wcat_bf = (unsigned short*)alloc((size_t)2048*3072*2);
  float* bsum = (float*)alloc(2048*4);
  float* dg_b = (float*)alloc(2560*4);
  float* hc_b = (float*)alloc(1024*4);

  // ---- setup ----
  k_order<<<1,128,0,stream>>>(cap_len, captions, order_i, declen_i, caps_s,
                              out_caps, out_declen, out_order);
  k_setup_bias<<<10,256,0,stream>>>(bih, bhh, da_b, gate_b, h0_b, c0_b, bsum, dg_b, hc_b);
  k_cvt6<<<9352,256,0,stream>>>(ea_w, lin_w, h0_w, c0_w, da_w, gate_w,
                                ea_bf, lin_bf, h0c0_bf, dg_bf);
  k_wcat<<<(2048*3072/4+255)/256,256,0,stream>>>(Wih, Whh, wcat_bf);
  k_cvt_enc<<<Bn*Pn,256,0,stream>>>(enc, order_i, enc_bf);
  k_mean<<<Bn,256,0,stream>>>(enc_bf, mean_bf);
  k_emb_all<<<Tn*Bn,256,0,stream>>>(caps_s, emb_w, xh_all);

  // h0/c0 (K=2048, BK=256 -> 8 phases)
  k_mfma_gemm<<<dim3(16,2),256,0,stream>>>(
      mean_bf, h0c0_bf, hc_b, hc, 1024, ENCn, 1024, nullptr, 0);
  k_h2bf<<<Bn,512,0,stream>>>(hc, c, h_bf, xh_all);

  // att1 = enc_bf @ ea_w^T (bf16 out), 128x64 tiles, XCD-contiguous
  k_att1<<<dim3(196*8),256,0,stream>>>(enc_bf, ea_bf, ea_b, att1);

  for (int t = 0; t < Tn; ++t) {
    unsigned short* xh_t = xh_all + (size_t)t*Bn*3072;
    // att2|gpre = h @ [da_w;gate_w]^T : [128,2560], K=512 -> 2 phases
    k_mfma_gemm<<<dim3(40,2),256,0,stream>>>(
        h_bf, dg_bf, dg_b, att2g, 2560, Dn, 2560, declen_i, t);
    // e-dot + softmax (thread-per-p)
    k_esm<<<Bn,256,0,stream>>>(att1, att2g, fa_w, fa_b, alpha, out_alph, declen_i, t);
    // awe + gate (1024 blocks)
    k_awe_gate<<<dim3(8,Bn),256,0,stream>>>(enc_bf, alpha, att2g, xh_t, declen_i, t);
    // gates GEMM (BK=256, 12 phases) + LSTM epilogue
    k_gates_lstm<<<dim3(32,2),256,0,stream>>>(
        xh_t, wcat_bf, bsum, c, h_bf, h_all, xh_all, declen_i, t);
  }

  // batched pred over all t: 64x64 tiles with inactive-tile skip
  k_pred<<<dim3((Vn+63)/64, (Tn*Bn)/64),256,0,stream>>>(
      h_all, lin_bf, lin_b, out_pred, declen_i);
}

// Round 14
// 1379.854 us; speedup vs baseline: 1.3145x; 1.0032x over previous
//
#include <hip/hip_runtime.h>
#include <hip/hip_bf16.h>
#include <math.h>

#define Bn 128
#define Pn 196
#define ENCn 2048
#define Dn 512
#define An 512
#define EDn 512
#define Vn 10000
#define Ln 20
#define Tn 19

typedef short v8s __attribute__((ext_vector_type(8)));
typedef float v4f __attribute__((ext_vector_type(4)));

__device__ __forceinline__ float sigf(float x){ return 1.f/(1.f+__expf(-x)); }
__device__ __forceinline__ unsigned short f2bf(float f){
  unsigned u = __float_as_uint(f);
  return (unsigned short)((u + 0x7FFFu + ((u>>16)&1u)) >> 16);
}
__device__ __forceinline__ float bf2f(unsigned short h){
  return __uint_as_float(((unsigned)h)<<16);
}

// ---------------- setup kernels ----------------

__global__ void k_order(const int* __restrict__ caption_len,
                        const int* __restrict__ captions,
                        int* __restrict__ order_i, int* __restrict__ declen_i,
                        int* __restrict__ caps_s,
                        float* __restrict__ out_caps, float* __restrict__ out_declen,
                        float* __restrict__ out_order)
{
  __shared__ int lens[Bn];
  int b = threadIdx.x;
  lens[b] = caption_len[b];
  __syncthreads();
  int lb = lens[b];
  int r = 0;
  for (int j = 0; j < Bn; ++j) {
    int lj = lens[j];
    r += (int)((lj > lb) || (lj == lb && j < b));
  }
  order_i[r] = b;
  declen_i[r] = lb - 1;
  out_order[r] = (float)b;
  out_declen[r] = (float)(lb - 1);
  for (int t = 0; t < Ln; ++t) {
    int cv = captions[b*Ln + t];
    caps_s[r*Ln + t] = cv;
    out_caps[r*Ln + t] = (float)cv;
  }
}

// bsum reordered to (d*4+g); dg_b / hc_b plain concat
__global__ void k_setup_bias(const float* __restrict__ bih, const float* __restrict__ bhh,
                             const float* __restrict__ da_b, const float* __restrict__ gate_b,
                             const float* __restrict__ h0_b, const float* __restrict__ c0_b,
                             float* __restrict__ bsum_r, float* __restrict__ dg_b,
                             float* __restrict__ hc_b)
{
  int i = blockIdx.x*256 + threadIdx.x;
  if (i < 2048) {
    int d = i >> 2, g = i & 3;
    bsum_r[i] = bih[g*512+d] + bhh[g*512+d];
  }
  if (i < 2560) dg_b[i] = (i < 512) ? da_b[i] : gate_b[i-512];
  if (i < 1024) hc_b[i] = (i < 512) ? h0_b[i] : c0_b[i-512];
}

// merged f32->bf16 conversion of all 6 weight matrices, one dispatch
#define C_EA  (512*2048)
#define C_LIN (10000*512)
#define C_H0  (512*2048)
#define C_C0  (512*2048)
#define C_DA  (512*512)
#define C_GW  (2048*512)
#define CUM1  (C_EA)
#define CUM2  (CUM1 + C_LIN)
#define CUM3  (CUM2 + C_H0)
#define CUM4  (CUM3 + C_C0)
#define CUM5  (CUM4 + C_DA)
#define CUM6  (CUM5 + C_GW)          // 9576448 total, = 9352 blocks * 1024

__global__ void k_cvt6(const float* __restrict__ ea_w, const float* __restrict__ lin_w,
                       const float* __restrict__ h0_w, const float* __restrict__ c0_w,
                       const float* __restrict__ da_w, const float* __restrict__ gate_w,
                       unsigned short* __restrict__ ea_bf, unsigned short* __restrict__ lin_bf,
                       unsigned short* __restrict__ h0c0_bf, unsigned short* __restrict__ dg_bf)
{
  int i = (blockIdx.x*256 + threadIdx.x)*4;
  const float* src; unsigned short* dst; int off;
  if      (i < CUM1) { src = ea_w;   dst = ea_bf;                    off = i; }
  else if (i < CUM2) { src = lin_w;  dst = lin_bf;                   off = i - CUM1; }
  else if (i < CUM3) { src = h0_w;   dst = h0c0_bf;                  off = i - CUM2; }
  else if (i < CUM4) { src = c0_w;   dst = h0c0_bf + (size_t)C_H0;   off = i - CUM3; }
  else if (i < CUM5) { src = da_w;   dst = dg_bf;                    off = i - CUM4; }
  else               { src = gate_w; dst = dg_bf + (size_t)C_DA;     off = i - CUM5; }
  float4 v = *(const float4*)(src + off);
  dst[off+0]=f2bf(v.x); dst[off+1]=f2bf(v.y); dst[off+2]=f2bf(v.z); dst[off+3]=f2bf(v.w);
}

// wcat_r[d*4+g][3072] = [Wih | Whh][g*512+d][:] in bf16 (gate-interleaved rows)
__global__ void k_wcat(const float* __restrict__ Wih, const float* __restrict__ Whh,
                       unsigned short* __restrict__ dst)
{
  int i = (blockIdx.x*256 + threadIdx.x)*4;
  if (i >= 2048*3072) return;
  int rp = i/3072, j = i - rp*3072;
  int d = rp >> 2, g = rp & 3;
  int r = g*512 + d;
  const float* s = (j < 2560) ? (Wih + (size_t)r*2560 + j) : (Whh + (size_t)r*512 + (j-2560));
  float4 v = *(const float4*)s;
  dst[i+0]=f2bf(v.x); dst[i+1]=f2bf(v.y); dst[i+2]=f2bf(v.z); dst[i+3]=f2bf(v.w);
}

__global__ void k_cvt_enc(const float* __restrict__ enc, const int* __restrict__ order_i,
                          unsigned short* __restrict__ dst)
{
  int id = blockIdx.x;               // b*196+p
  int b = id / Pn, p = id - b*Pn;
  const float* src = enc + ((size_t)order_i[b]*Pn + p)*ENCn;
  unsigned short* d = dst + (size_t)id*ENCn;
  int i = threadIdx.x*8;
  float4 v0 = *(const float4*)(src+i), v1 = *(const float4*)(src+i+4);
  d[i+0]=f2bf(v0.x); d[i+1]=f2bf(v0.y); d[i+2]=f2bf(v0.z); d[i+3]=f2bf(v0.w);
  d[i+4]=f2bf(v1.x); d[i+5]=f2bf(v1.y); d[i+6]=f2bf(v1.z); d[i+7]=f2bf(v1.w);
}

__global__ void k_mean(const unsigned short* __restrict__ enc_bf,
                       unsigned short* __restrict__ mean_bf)
{
  int b = blockIdx.x;
  const unsigned short* eb = enc_bf + (size_t)b*Pn*ENCn;
  for (int e = threadIdx.x; e < ENCn; e += 256) {
    float s = 0.f;
    for (int p = 0; p < Pn; ++p) s += bf2f(eb[(size_t)p*ENCn + e]);
    mean_bf[b*ENCn + e] = f2bf(s * (1.f/196.f));
  }
}

__global__ void k_emb_all(const int* __restrict__ caps_s, const float* __restrict__ emb_w,
                          unsigned short* __restrict__ xh_all)
{
  int id = blockIdx.x; int t = id >> 7, b = id & 127;
  int tok = caps_s[b*Ln + t];
  const float* src = emb_w + (size_t)tok*EDn;
  unsigned short* d = xh_all + ((size_t)t*Bn + b)*3072;
  int i = threadIdx.x*2;
  float2 v = *(const float2*)(src+i);
  d[i] = f2bf(v.x); d[i+1] = f2bf(v.y);
}

__global__ void k_h2bf(const float* __restrict__ hc, float* __restrict__ c,
                       unsigned short* __restrict__ h_bf, unsigned short* __restrict__ xh_all)
{
  int b = blockIdx.x, d = threadIdx.x;
  float hv = hc[b*1024 + d];
  float cv = hc[b*1024 + 512 + d];
  c[b*Dn + d] = cv;
  unsigned short hb = f2bf(hv);
  h_bf[b*Dn + d] = hb;
  xh_all[(size_t)b*3072 + 2560 + d] = hb;
}

// ---------------- bf16 MFMA GEMM 64x64, BK=256 (h0c0 only) ----------------
__global__ __launch_bounds__(256) void k_mfma_gemm(
    const unsigned short* __restrict__ Aw, const unsigned short* __restrict__ Bw,
    const float* __restrict__ bias, float* __restrict__ Cp,
    int N, int K, size_t ldc,
    const int* __restrict__ actlen, int t)
{
  __shared__ unsigned short smA[2][16384];   // 64 rows x 256 k
  __shared__ unsigned short smB[2][16384];
  const int tid = threadIdx.x;
  const int bm0 = blockIdx.y*64, bn0 = blockIdx.x*64;
  if (actlen && actlen[bm0] <= t) return;

  const int lane = tid & 63, w = tid >> 6;
  const int wr = w >> 1, wc = w & 1;
  const int lrow = lane & 15, kq = lane >> 4;

  v4f acc[2][2];
  #pragma unroll
  for (int i=0;i<2;++i)
    #pragma unroll
    for (int j=0;j<2;++j) acc[i][j] = (v4f)0.f;

  const int nt = K >> 8;

  auto stage = [&](int buf, int k0) {
    #pragma unroll
    for (int it = 0; it < 8; ++it) {
      int s = it*256 + tid;            // row = s>>5, kbl = s&31
      int row = s >> 5;
      int kbs = (s & 31) ^ (row & 7);  // swizzled source k-block
      *(v8s*)&smA[buf][s*8] = *(const v8s*)(Aw + (size_t)(bm0+row)*K + k0 + kbs*8);
      *(v8s*)&smB[buf][s*8] = *(const v8s*)(Bw + (size_t)(bn0+row)*K + k0 + kbs*8);
    }
  };
  auto compute = [&](int buf) {
    #pragma unroll
    for (int kc = 0; kc < 8; ++kc) {
      v8s aF[2], bF[2];
      #pragma unroll
      for (int mi = 0; mi < 2; ++mi) {
        int row = wr*32 + mi*16 + lrow;
        int kb = kc*4 + kq;
        aF[mi] = *(const v8s*)&smA[buf][row*256 + ((kb ^ (row&7))<<3)];
      }
      #pragma unroll
      for (int ni = 0; ni < 2; ++ni) {
        int row = wc*32 + ni*16 + lrow;
        int kb = kc*4 + kq;
        bF[ni] = *(const v8s*)&smB[buf][row*256 + ((kb ^ (row&7))<<3)];
      }
      #pragma unroll
      for (int mi = 0; mi < 2; ++mi)
        #pragma unroll
        for (int ni = 0; ni < 2; ++ni)
          acc[mi][ni] = __builtin_amdgcn_mfma_f32_16x16x32_bf16(aF[mi], bF[ni], acc[mi][ni], 0, 0, 0);
    }
  };

  stage(0, 0);
  __syncthreads();
  for (int tk = 0; tk < nt; ++tk) {
    if (tk + 1 < nt) stage((tk+1)&1, (tk+1)<<8);
    compute(tk&1);
    __syncthreads();
  }

  #pragma unroll
  for (int mi=0; mi<2; ++mi)
    #pragma unroll
    for (int ni=0; ni<2; ++ni)
      #pragma unroll
      for (int r=0; r<4; ++r) {
        int m = bm0 + wr*32 + mi*16 + kq*4 + r;
        int n = bn0 + wc*32 + ni*16 + lrow;
        Cp[(size_t)m*ldc + n] = acc[mi][ni][r] + bias[n];
      }
}

// ---------------- att2g GEMM: single-phase, K=512 fully staged ----------------
// grid (40, 2): C[128,2560] = h_bf[128,512] @ dg_bf[2560,512]^T + dg_b
__global__ __launch_bounds__(256) void k_att2g(
    const unsigned short* __restrict__ Aw, const unsigned short* __restrict__ Bw,
    const float* __restrict__ bias, float* __restrict__ Cp,
    const int* __restrict__ declen_i, int t)
{
  __shared__ unsigned short smA[64*512];   // 64 KB
  __shared__ unsigned short smB[64*512];   // 64 KB
  const int tid = threadIdx.x;
  const int bm0 = blockIdx.y*64, bn0 = blockIdx.x*64;
  if (declen_i[bm0] <= t) return;

  const int lane = tid & 63, w = tid >> 6;
  const int wr = w >> 1, wc = w & 1;
  const int lrow = lane & 15, kq = lane >> 4;

  v4f acc[2][2];
  #pragma unroll
  for (int i=0;i<2;++i)
    #pragma unroll
    for (int j=0;j<2;++j) acc[i][j] = (v4f)0.f;

  // stage whole K=512: 64 rows x 64 k-blocks per matrix
  #pragma unroll
  for (int it = 0; it < 16; ++it) {
    int s = it*256 + tid;            // row = s>>6, kbl = s&63
    int row = s >> 6;
    int kbs = (s & 63) ^ (row & 7);
    *(v8s*)&smA[s*8] = *(const v8s*)(Aw + (size_t)(bm0+row)*Dn + kbs*8);
    *(v8s*)&smB[s*8] = *(const v8s*)(Bw + (size_t)(bn0+row)*Dn + kbs*8);
  }
  __syncthreads();

  #pragma unroll
  for (int kc = 0; kc < 16; ++kc) {
    v8s aF[2], bF[2];
    #pragma unroll
    for (int mi = 0; mi < 2; ++mi) {
      int row = wr*32 + mi*16 + lrow;
      int kb = kc*4 + kq;
      aF[mi] = *(const v8s*)&smA[row*512 + ((kb ^ (row&7))<<3)];
    }
    #pragma unroll
    for (int ni = 0; ni < 2; ++ni) {
      int row = wc*32 + ni*16 + lrow;
      int kb = kc*4 + kq;
      bF[ni] = *(const v8s*)&smB[row*512 + ((kb ^ (row&7))<<3)];
    }
    #pragma unroll
    for (int mi = 0; mi < 2; ++mi)
      #pragma unroll
      for (int ni = 0; ni < 2; ++ni)
        acc[mi][ni] = __builtin_amdgcn_mfma_f32_16x16x32_bf16(aF[mi], bF[ni], acc[mi][ni], 0, 0, 0);
  }

  #pragma unroll
  for (int mi=0; mi<2; ++mi)
    #pragma unroll
    for (int ni=0; ni<2; ++ni)
      #pragma unroll
      for (int r=0; r<4; ++r) {
        int m = bm0 + wr*32 + mi*16 + kq*4 + r;
        int n = bn0 + wc*32 + ni*16 + lrow;
        Cp[(size_t)m*2560 + n] = acc[mi][ni][r] + bias[n];
      }
}

// ---------------- att1 GEMM: 128x64 tile, XCD-contiguous (BK=64) ----------------
__global__ __launch_bounds__(256) void k_att1(
    const unsigned short* __restrict__ Aw, const unsigned short* __restrict__ Bw,
    const float* __restrict__ bias, unsigned short* __restrict__ Cp)
{
  __shared__ unsigned short smA[2][8192];
  __shared__ unsigned short smB[2][4096];
  const int tid = threadIdx.x;
  const int id = blockIdx.x;
  const int g = (id & 7)*196 + (id >> 3);   // XCD-contiguous panel walk
  const int bm0 = (g >> 3) * 128, bn0 = (g & 7) * 64;
  const int K = ENCn;

  const int lane = tid & 63, w = tid >> 6;
  const int wr = w >> 1, wc = w & 1;
  const int lrow = lane & 15, kq = lane >> 4;

  v4f acc[4][2];
  #pragma unroll
  for (int i=0;i<4;++i)
    #pragma unroll
    for (int j=0;j<2;++j) acc[i][j] = (v4f)0.f;

  auto stage = [&](int buf, int k0) {
    #pragma unroll
    for (int it = 0; it < 4; ++it) {
      int s = it*256 + tid;
      int row = s >> 3;
      int kb  = (s & 7) ^ (row & 7);
      *(v8s*)&smA[buf][s*8] = *(const v8s*)(Aw + (size_t)(bm0+row)*K + k0 + kb*8);
    }
    #pragma unroll
    for (int it = 0; it < 2; ++it) {
      int s = it*256 + tid;
      int row = s >> 3;
      int kb  = (s & 7) ^ (row & 7);
      *(v8s*)&smB[buf][s*8] = *(const v8s*)(Bw + (size_t)(bn0+row)*K + k0 + kb*8);
    }
  };
  auto compute = [&](int buf) {
    #pragma unroll
    for (int kc = 0; kc < 2; ++kc) {
      v8s aF[4], bF[2];
      #pragma unroll
      for (int mi = 0; mi < 4; ++mi) {
        int row = wr*64 + mi*16 + lrow;
        int kb = kc*4 + kq;
        aF[mi] = *(const v8s*)&smA[buf][row*64 + ((kb ^ (row&7))<<3)];
      }
      #pragma unroll
      for (int ni = 0; ni < 2; ++ni) {
        int row = wc*32 + ni*16 + lrow;
        int kb = kc*4 + kq;
        bF[ni] = *(const v8s*)&smB[buf][row*64 + ((kb ^ (row&7))<<3)];
      }
      #pragma unroll
      for (int mi = 0; mi < 4; ++mi)
        #pragma unroll
        for (int ni = 0; ni < 2; ++ni)
          acc[mi][ni] = __builtin_amdgcn_mfma_f32_16x16x32_bf16(aF[mi], bF[ni], acc[mi][ni], 0, 0, 0);
    }
  };

  stage(0, 0);
  __syncthreads();
  const int nt = K >> 6;
  for (int tk = 0; tk < nt; ++tk) {
    if (tk + 1 < nt) stage((tk+1)&1, (tk+1)<<6);
    compute(tk&1);
    __syncthreads();
  }

  #pragma unroll
  for (int mi=0; mi<4; ++mi)
    #pragma unroll
    for (int ni=0; ni<2; ++ni)
      #pragma unroll
      for (int r=0; r<4; ++r) {
        int m = bm0 + wr*64 + mi*16 + kq*4 + r;
        int n = bn0 + wc*32 + ni*16 + lrow;
        Cp[(size_t)m*An + n] = f2bf(acc[mi][ni][r] + bias[n]);
      }
}

// ---------------- gates GEMM (BK=256) + LSTM epilogue ----------------
__global__ __launch_bounds__(256) void k_gates_lstm(
    const unsigned short* __restrict__ Aw, const unsigned short* __restrict__ Bw,
    const float* __restrict__ bias,
    float* __restrict__ c, unsigned short* __restrict__ h_bf,
    unsigned short* __restrict__ h_all, unsigned short* __restrict__ xh_all,
    const int* __restrict__ declen_i, int t)
{
  __shared__ __align__(16) char smraw[131072];
  unsigned short (*smA)[16384] = (unsigned short(*)[16384])smraw;            // 64KB
  unsigned short (*smB)[16384] = (unsigned short(*)[16384])(smraw + 65536);  // 64KB
  float (*smC)[65] = (float(*)[65])smraw;  // aliases smA after K-loop
  const int tid = threadIdx.x;
  const int bm0 = blockIdx.y*64, bn0 = blockIdx.x*64;
  if (declen_i[bm0] <= t) return;

  const int lane = tid & 63, w = tid >> 6;
  const int wr = w >> 1, wc = w & 1;
  const int lrow = lane & 15, kq = lane >> 4;
  const int K = 3072;

  v4f acc[2][2];
  #pragma unroll
  for (int i=0;i<2;++i)
    #pragma unroll
    for (int j=0;j<2;++j) acc[i][j] = (v4f)0.f;

  auto stage = [&](int buf, int k0) {
    #pragma unroll
    for (int it = 0; it < 8; ++it) {
      int s = it*256 + tid;
      int row = s >> 5;
      int kbs = (s & 31) ^ (row & 7);
      *(v8s*)&smA[buf][s*8] = *(const v8s*)(Aw + (size_t)(bm0+row)*K + k0 + kbs*8);
      *(v8s*)&smB[buf][s*8] = *(const v8s*)(Bw + (size_t)(bn0+row)*K + k0 + kbs*8);
    }
  };
  auto compute = [&](int buf) {
    #pragma unroll
    for (int kc = 0; kc < 8; ++kc) {
      v8s aF[2], bF[2];
      #pragma unroll
      for (int mi = 0; mi < 2; ++mi) {
        int row = wr*32 + mi*16 + lrow;
        int kb = kc*4 + kq;
        aF[mi] = *(const v8s*)&smA[buf][row*256 + ((kb ^ (row&7))<<3)];
      }
      #pragma unroll
      for (int ni = 0; ni < 2; ++ni) {
        int row = wc*32 + ni*16 + lrow;
        int kb = kc*4 + kq;
        bF[ni] = *(const v8s*)&smB[buf][row*256 + ((kb ^ (row&7))<<3)];
      }
      #pragma unroll
      for (int mi = 0; mi < 2; ++mi)
        #pragma unroll
        for (int ni = 0; ni < 2; ++ni)
          acc[mi][ni] = __builtin_amdgcn_mfma_f32_16x16x32_bf16(aF[mi], bF[ni], acc[mi][ni], 0, 0, 0);
    }
  };

  stage(0, 0);
  __syncthreads();
  const int nt = K >> 8;   // 12
  for (int tk = 0; tk < nt; ++tk) {
    if (tk + 1 < nt) stage((tk+1)&1, (tk+1)<<8);
    compute(tk&1);
    __syncthreads();
  }
  // loop ends with barrier: safe to overwrite smA region with smC

  #pragma unroll
  for (int mi=0; mi<2; ++mi)
    #pragma unroll
    for (int ni=0; ni<2; ++ni)
      #pragma unroll
      for (int r=0; r<4; ++r) {
        int ml = wr*32 + mi*16 + kq*4 + r;
        int nl = wc*32 + ni*16 + lrow;
        smC[ml][nl] = acc[mi][ni][r] + bias[bn0 + nl];
      }
  __syncthreads();

  for (int idx = tid; idx < 1024; idx += 256) {
    int ml = idx >> 4, dl = idx & 15;
    int b = bm0 + ml;
    if (t < declen_i[b]) {
      int dg = (bn0 >> 2) + dl;
      float gi = smC[ml][dl*4+0];
      float gf = smC[ml][dl*4+1];
      float gg = smC[ml][dl*4+2];
      float go = smC[ml][dl*4+3];
      float cv = c[b*Dn + dg];
      float cn = sigf(gf)*cv + sigf(gi)*tanhf(gg);
      float hn = sigf(go)*tanhf(cn);
      c[b*Dn + dg] = cn;
      unsigned short hb = f2bf(hn);
      h_bf[b*Dn + dg] = hb;
      h_all[((size_t)t*Bn + b)*Dn + dg] = hb;
      if (t + 1 < Tn)
        xh_all[((size_t)(t+1)*Bn + b)*3072 + 2560 + dg] = hb;
    }
  }
}

// ---------------- batched pred GEMM (all t, 64x64 tiles with inactive-tile skip) ----------------
__global__ __launch_bounds__(256) void k_pred(
    const unsigned short* __restrict__ Aw, const unsigned short* __restrict__ Bw,
    const float* __restrict__ bias, float* __restrict__ out_pred,
    const int* __restrict__ declen_i)
{
  __shared__ unsigned short smA[2][4096];
  __shared__ unsigned short smB[2][4096];
  const int tid = threadIdx.x;
  const int bm0 = blockIdx.y*64, bn0 = blockIdx.x*64;
  const int t0 = bm0 >> 7, b0 = bm0 & 127;

  if (declen_i[b0] <= t0) {
    for (int i = tid; i < 4096; i += 256) {
      int ml = i >> 6, nl = i & 63;
      int n = bn0 + nl;
      if (n < Vn) {
        int m = bm0 + ml;
        out_pred[((size_t)(m & 127)*Tn + (m >> 7))*Vn + n] = 0.f;
      }
    }
    return;
  }

  const int lane = tid & 63, w = tid >> 6;
  const int wr = w >> 1, wc = w & 1;
  const int lrow = lane & 15, kq = lane >> 4;
  const int K = 512;

  v4f acc[2][2];
  #pragma unroll
  for (int i=0;i<2;++i)
    #pragma unroll
    for (int j=0;j<2;++j) acc[i][j] = (v4f)0.f;

  auto stage = [&](int buf, int k0) {
    #pragma unroll
    for (int it = 0; it < 2; ++it) {
      int s = it*256 + tid;
      int row = s >> 3;
      int kb  = (s & 7) ^ (row & 7);
      *(v8s*)&smA[buf][s*8] = *(const v8s*)(Aw + (size_t)(bm0+row)*K + k0 + kb*8);
      {
        int gn = bn0 + row; if (gn >= Vn) gn = Vn-1;
        *(v8s*)&smB[buf][s*8] = *(const v8s*)(Bw + (size_t)gn*K + k0 + kb*8);
      }
    }
  };
  auto compute = [&](int buf) {
    #pragma unroll
    for (int kc = 0; kc < 2; ++kc) {
      v8s aF[2], bF[2];
      #pragma unroll
      for (int mi = 0; mi < 2; ++mi) {
        int row = wr*32 + mi*16 + lrow;
        int kb = kc*4 + kq;
        aF[mi] = *(const v8s*)&smA[buf][row*64 + ((kb ^ (row&7))<<3)];
      }
      #pragma unroll
      for (int ni = 0; ni < 2; ++ni) {
        int row = wc*32 + ni*16 + lrow;
        int kb = kc*4 + kq;
        bF[ni] = *(const v8s*)&smB[buf][row*64 + ((kb ^ (row&7))<<3)];
      }
      #pragma unroll
      for (int mi = 0; mi < 2; ++mi)
        #pragma unroll
        for (int ni = 0; ni < 2; ++ni)
          acc[mi][ni] = __builtin_amdgcn_mfma_f32_16x16x32_bf16(aF[mi], bF[ni], acc[mi][ni], 0, 0, 0);
    }
  };

  stage(0, 0);
  __syncthreads();
  const int nt = K >> 6;
  for (int tk = 0; tk < nt; ++tk) {
    if (tk + 1 < nt) stage((tk+1)&1, (tk+1)<<6);
    compute(tk&1);
    __syncthreads();
  }

  #pragma unroll
  for (int mi=0; mi<2; ++mi)
    #pragma unroll
    for (int ni=0; ni<2; ++ni)
      #pragma unroll
      for (int r=0; r<4; ++r) {
        int m = bm0 + wr*32 + mi*16 + kq*4 + r;
        int n = bn0 + wc*32 + ni*16 + lrow;
        if (n < Vn) {
          int b = m & 127, tt = m >> 7;
          float v = (tt < declen_i[b]) ? (acc[mi][ni][r] + bias[n]) : 0.f;
          out_pred[((size_t)b*Tn + tt)*Vn + n] = v;
        }
      }
}

// ---------------- e-dot + softmax (thread-per-p) ----------------
__global__ __launch_bounds__(256) void k_esm(
    const unsigned short* __restrict__ att1, const float* __restrict__ att2g,
    const float* __restrict__ fa_w, const float* __restrict__ fa_b,
    float* __restrict__ alpha, float* __restrict__ out_alph,
    const int* __restrict__ declen_i, int t)
{
  int b = blockIdx.x;
  int tid = threadIdx.x;
  if (t >= declen_i[b]) {
    if (tid < Pn)
      out_alph[(size_t)b*Tn*Pn + (size_t)t*Pn + tid] = 0.f;
    return;
  }
  __shared__ float a2s[An];
  __shared__ float fws[An];
  __shared__ float es[Pn];
  __shared__ float wred[4];
  __shared__ float wsum[4];
  for (int i = tid; i < An; i += 256) { a2s[i] = att2g[(size_t)b*2560 + i]; fws[i] = fa_w[i]; }
  __syncthreads();
  int lane = tid & 63, w = tid >> 6;
  if (tid < Pn) {
    const unsigned short* row = att1 + ((size_t)b*Pn + tid)*An;
    float s = 0.f;
    #pragma unroll 4
    for (int kb = 0; kb < 64; ++kb) {
      const v8s vv = *(const v8s*)(row + kb*8);
      #pragma unroll
      for (int j = 0; j < 8; ++j) {
        int a = kb*8 + j;
        float v = bf2f((unsigned short)vv[j]) + a2s[a];
        s += fmaxf(v, 0.f) * fws[a];
      }
    }
    es[tid] = s + fa_b[0];
  }
  __syncthreads();
  float m = -1e30f;
  for (int p = tid; p < Pn; p += 256) m = fmaxf(m, es[p]);
  for (int off = 32; off; off >>= 1) m = fmaxf(m, __shfl_down(m, off));
  if (lane == 0) wred[w] = m;
  __syncthreads();
  m = fmaxf(fmaxf(wred[0], wred[1]), fmaxf(wred[2], wred[3]));
  float s = 0.f;
  for (int p = tid; p < Pn; p += 256) { float ev = __expf(es[p] - m); es[p] = ev; s += ev; }
  for (int off = 32; off; off >>= 1) s += __shfl_down(s, off);
  if (lane == 0) wsum[w] = s;
  __syncthreads();
  s = wsum[0] + wsum[1] + wsum[2] + wsum[3];
  float inv = 1.f / s;
  for (int p = tid; p < Pn; p += 256) {
    float al = es[p] * inv;
    alpha[b*Pn + p] = al;
    out_alph[(size_t)b*Tn*Pn + (size_t)t*Pn + p] = al;
  }
}

// ---------------- awe + gate ----------------
// grid (8, 128): block (ei, b) handles 256-e slice.
__global__ __launch_bounds__(256) void k_awe_gate(
    const unsigned short* __restrict__ enc_bf,
    const float* __restrict__ alpha, const float* __restrict__ att2g,
    unsigned short* __restrict__ xh_t, const int* __restrict__ declen_i, int t)
{
  int b = blockIdx.y;
  if (t >= declen_i[b]) return;
  __shared__ float als[Pn];
  __shared__ float red[8][256];
  int tid = threadIdx.x;
  if (tid < Pn) als[tid] = alpha[b*Pn + tid];
  __syncthreads();
  int e0 = blockIdx.x*256;
  int ec = tid & 31, ps = tid >> 5;
  const unsigned short* eb = enc_bf + (size_t)b*Pn*ENCn + e0 + ec*8;
  float s[8] = {};
  for (int p = ps; p < Pn; p += 8) {
    v8s v = *(const v8s*)(eb + (size_t)p*ENCn);
    float a = als[p];
    #pragma unroll
    for (int j = 0; j < 8; ++j) s[j] += a * bf2f((unsigned short)v[j]);
  }
  #pragma unroll
  for (int j = 0; j < 8; ++j) red[ps][ec*8+j] = s[j];
  __syncthreads();
  {
    int e = tid;
    float tsum = 0.f;
    #pragma unroll
    for (int k = 0; k < 8; ++k) tsum += red[k][e];
    int eg = e0 + e;
    float g = sigf(att2g[(size_t)b*2560 + 512 + eg]);
    xh_t[(size_t)b*3072 + 512 + eg] = f2bf(g*tsum);
  }
}

// ---------------- launch ----------------

extern "C" void kernel_launch(void* const* d_in, const int* in_sizes, int n_in,
                              void* d_out, int out_size, void* d_ws, size_t ws_size,
                              hipStream_t stream)
{
  const float* enc     = (const float*)d_in[0];
  const int*   captions= (const int*)d_in[1];
  const int*   cap_len = (const int*)d_in[2];
  const float* emb_w   = (const float*)d_in[3];
  const float* Wih     = (const float*)d_in[4];
  const float* Whh     = (const float*)d_in[5];
  const float* bih     = (const float*)d_in[6];
  const float* bhh     = (const float*)d_in[7];
  const float* h0_w    = (const float*)d_in[8];
  const float* h0_b    = (const float*)d_in[9];
  const float* c0_w    = (const float*)d_in[10];
  const float* c0_b    = (const float*)d_in[11];
  const float* gate_w  = (const float*)d_in[12];
  const float* gate_b  = (const float*)d_in[13];
  const float* lin_w   = (const float*)d_in[14];
  const float* lin_b   = (const float*)d_in[15];
  const float* ea_w    = (const float*)d_in[16];
  const float* ea_b    = (const float*)d_in[17];
  const float* da_w    = (const float*)d_in[18];
  const float* da_b    = (const float*)d_in[19];
  const float* fa_w    = (const float*)d_in[20];
  const float* fa_b    = (const float*)d_in[21];

  float* out = (float*)d_out;
  float* out_pred   = out;                               // [128][19][10000]
  float* out_caps   = out + (size_t)Bn*Tn*Vn;            // [128][20]
  float* out_declen = out_caps + Bn*Ln;                  // [128]
  float* out_alph   = out_declen + Bn;                   // [128][19][196]
  float* out_order  = out_alph + (size_t)Bn*Tn*Pn;       // [128]

  char* wp = (char*)d_ws;
  auto alloc = [&](size_t bytes)->void* {
    void* p = (void*)wp; wp += (bytes + 255) & ~(size_t)255; return p;
  };
  int*   order_i  = (int*)alloc(Bn*4);
  int*   declen_i = (int*)alloc(Bn*4);
  int*   caps_s   = (int*)alloc(Bn*Ln*4);
  unsigned short* enc_bf  = (unsigned short*)alloc((size_t)Bn*Pn*ENCn*2);  // 102.8 MB
  unsigned short* mean_bf = (unsigned short*)alloc((size_t)Bn*ENCn*2);
  float* hc       = (float*)alloc((size_t)Bn*1024*4);
  float* c        = (float*)alloc((size_t)Bn*Dn*4);
  unsigned short* h_bf   = (unsigned short*)alloc((size_t)Bn*Dn*2);
  unsigned short* h_all  = (unsigned short*)alloc((size_t)Tn*Bn*Dn*2);     // 2.5 MB
  unsigned short* xh_all = (unsigned short*)alloc((size_t)Tn*Bn*3072*2);   // 14.9 MB
  unsigned short* att1   = (unsigned short*)alloc((size_t)Bn*Pn*An*2);     // 25.7 MB
  float* att2g    = (float*)alloc((size_t)Bn*2560*4);
  float* alpha    = (float*)alloc((size_t)Bn*Pn*4);
  unsigned short* ea_bf   = (unsigned short*)alloc((size_t)An*ENCn*2);
  unsigned short* lin_bf  = (unsigned short*)alloc((size_t)Vn*Dn*2);
  unsigned short* h0c0_bf = (unsigned short*)alloc((size_t)1024*ENCn*2);
  unsigned short* dg_bf   = (unsigned short*)alloc((size_t)2560*Dn*2);
  unsigned short* wcat_bf = (unsigned short*)alloc((size_t)2048*3072*2);
  float* bsum = (float*)alloc(2048*4);
  float* dg_b = (float*)alloc(2560*4);
  float* hc_b = (float*)alloc(1024*4);

  // ---- setup ----
  k_order<<<1,128,0,stream>>>(cap_len, captions, order_i, declen_i, caps_s,
                              out_caps, out_declen, out_order);
  k_setup_bias<<<10,256,0,stream>>>(bih, bhh, da_b, gate_b, h0_b, c0_b, bsum, dg_b, hc_b);
  k_cvt6<<<9352,256,0,stream>>>(ea_w, lin_w, h0_w, c0_w, da_w, gate_w,
                                ea_bf, lin_bf, h0c0_bf, dg_bf);
  k_wcat<<<(2048*3072/4+255)/256,256,0,stream>>>(Wih, Whh, wcat_bf);
  k_cvt_enc<<<Bn*Pn,256,0,stream>>>(enc, order_i, enc_bf);
  k_mean<<<Bn,256,0,stream>>>(enc_bf, mean_bf);
  k_emb_all<<<Tn*Bn,256,0,stream>>>(caps_s, emb_w, xh_all);

  // h0/c0 (K=2048, BK=256 -> 8 phases)
  k_mfma_gemm<<<dim3(16,2),256,0,stream>>>(
      mean_bf, h0c0_bf, hc_b, hc, 1024, ENCn, 1024, nullptr, 0);
  k_h2bf<<<Bn,512,0,stream>>>(hc, c, h_bf, xh_all);

  // att1 = enc_bf @ ea_w^T (bf16 out), 128x64 tiles, XCD-contiguous
  k_att1<<<dim3(196*8),256,0,stream>>>(enc_bf, ea_bf, ea_b, att1);

  for (int t = 0; t < Tn; ++t) {
    unsigned short* xh_t = xh_all + (size_t)t*Bn*3072;
    // att2|gpre = h @ [da_w;gate_w]^T : [128,2560], single-phase K=512
    k_att2g<<<dim3(40,2),256,0,stream>>>(
        h_bf, dg_bf, dg_b, att2g, declen_i, t);
    // e-dot + softmax (thread-per-p)
    k_esm<<<Bn,256,0,stream>>>(att1, att2g, fa_w, fa_b, alpha, out_alph, declen_i, t);
    // awe + gate (1024 blocks)
    k_awe_gate<<<dim3(8,Bn),256,0,stream>>>(enc_bf, alpha, att2g, xh_t, declen_i, t);
    // gates GEMM (BK=256, 12 phases) + LSTM epilogue
    k_gates_lstm<<<dim3(32,2),256,0,stream>>>(
        xh_t, wcat_bf, bsum, c, h_bf, h_all, xh_all, declen_i, t);
  }

  // batched pred over all t: 64x64 tiles with inactive-tile skip
  k_pred<<<dim3((Vn+63)/64, (Tn*Bn)/64),256,0,stream>>>(
      h_all, lin_bf, lin_b, out_pred, declen_i);
}